// Round 3
// baseline (445.588 us; speedup 1.0000x reference)
//
#include <hip/hip_runtime.h>
#include <hip/hip_bf16.h>
#include <cstddef>

#define H 200
#define NA 48
#define NBB 96
#define BATCH 128
#define AFD 39
#define BFD 50          // 39+11
#define LP 1000
#define CATD (AFD + H)  // 239
#define BPB 4           // bonds per block in message kernel (APB/BPB=8 spilled in R3)
#define APB 2           // atoms per block in atom kernel
#define BIPB 4          // bonds per block in bond-input kernel

typedef unsigned short ushort_t;
typedef __bf16 bf16x8 __attribute__((ext_vector_type(8)));
typedef float f32x16 __attribute__((ext_vector_type(16)));

union U16B { uint4 u; bf16x8 b; };
static __device__ __forceinline__ bf16x8 as_bf16x8(uint4 u) { U16B x; x.u = u; return x.b; }

// float -> bf16 (RNE)
static __device__ __forceinline__ ushort_t f2bf(float f) {
    union { float f; unsigned u; } a; a.f = f;
    unsigned r = (a.u + 0x7FFFu + ((a.u >> 16) & 1u)) >> 16;
    return (ushort_t)r;
}

// ---------------- fused prep: 3 weight swizzles (32x32x16 A-frag order) + zero x ----------------
// Wb[((tile*NS + s)*64 + lane)*8 + j] = bf16(w[co][ci][t])
//   co = tile*32 + (lane&31), t = s/NC, cc = s%NC, ci = cc*16 + (lane>>5)*8 + j
template <int COUT, int CIN, int CP, int K>
static __device__ __forceinline__ void prep_one(int t, const float* __restrict__ w,
                                                ushort_t* __restrict__ Wb) {
    constexpr int NC = CP / 16;
    constexpr int NS = K * NC;
    int j = t & 7;
    int lane = (t >> 3) & 63;
    int s = (t >> 9) % NS;
    int ct = (t >> 9) / NS;
    int co = ct * 32 + (lane & 31);
    int tt = s / NC, cc = s % NC;
    int ci = cc * 16 + ((lane >> 5) & 1) * 8 + j;
    float v = 0.f;
    if (co < COUT && ci < CIN) v = w[((size_t)co * CIN + ci) * K + tt];
    Wb[t] = f2bf(v);
}

#define PREP_T0 (4 * 12 * 512)            // conv0: 4 tiles x NS=12
#define PREP_T1 (PREP_T0 + 4 * 30 * 512)  // conv1: 4 tiles x NS=30
#define PREP_T2 (PREP_T1 + 8 * 56 * 512)  // conv2: 8 tiles x NS=56
#define PREP_T3 (PREP_T2 + 51200)         // zero x

__global__ __launch_bounds__(256) void k_prep_all(
        const float* __restrict__ c0w, const float* __restrict__ c1w,
        const float* __restrict__ c2w, float* __restrict__ x,
        ushort_t* __restrict__ Wb0, ushort_t* __restrict__ Wb1,
        ushort_t* __restrict__ Wb2) {
    int tid = blockIdx.x * 256 + threadIdx.x;
    if (tid < PREP_T0) prep_one<96, 50, 64, 3>(tid, c0w, Wb0);
    else if (tid < PREP_T1) prep_one<128, 96, 96, 5>(tid - PREP_T0, c1w, Wb1);
    else if (tid < PREP_T2) prep_one<200, 128, 128, 7>(tid - PREP_T1, c2w, Wb2);
    else if (tid < PREP_T3) x[tid - PREP_T2] = 0.f;
}

// ---------------- MFMA conv1d body, 32x32x16 ----------------
// R6: per-step wall is latency-pinned (~1200cy; R4 reg-ring + R5 DMA-pipeline both failed
// to hide it). Amortize instead: LT=4 l-subtiles per wave (acc[2][4]=128 regs, 8 MFMA/step).
// A-loads per step unchanged, total A-traffic halved (half the blocks). 2 blocks/CU.
// Wave = 64co(ct=2) x 32*LT l. Block = CO_WAVES x L_WAVES waves.
// EMB: build X tile directly from seq+emb (conv0). FMAX: relu + global max -> atomicMax.
template <int CP, int K, int COUT, int CO_WAVES, int L_WAVES, int LT, bool FMAX, bool EMB>
static __device__ __forceinline__ void conv_body(
        const ushort_t* __restrict__ act, const int* __restrict__ seq,
        const float* __restrict__ emb, const ushort_t* __restrict__ Wb,
        const float* __restrict__ bias, void* __restrict__ outv,
        ushort_t* __restrict__ Xs) {
    constexpr int NC = CP / 16;
    constexpr int NS = K * NC;
    constexpr int P = K / 2;
    constexpr int PITCH = CP + 8;     // ushorts; 16B-aligned rows, non-pow2 bank stride
    constexpr int LSPAN = 32 * LT;            // l rows per wave
    constexpr int LTILE = LSPAN * L_WAVES;    // l rows per block
    constexpr int ROWS = LTILE + K - 1;
    constexpr int CPR = CP / 8;

    int b = blockIdx.z, lb = blockIdx.x;
    int l0 = lb * LTILE;
    int tid = threadIdx.x;

    // ---- stage X tile (halo, zero-padded at edges) ----
    if (EMB) {
        const int* seqb = seq + (size_t)b * LP;
        for (int idx = tid; idx < ROWS * CPR; idx += 256) {
            int r = idx / CPR, c = idx % CPR;
            int l = l0 - P + r;
            uint4 v = {0u, 0u, 0u, 0u};
            if ((unsigned)l < (unsigned)LP) {
                int s = seqb[l];
                const float* e = emb + (size_t)s * 50;
                ushort_t h[8];
#pragma unroll
                for (int j = 0; j < 8; ++j) {
                    int cc = c * 8 + j;
                    h[j] = (cc < 50) ? f2bf(e[cc]) : (ushort_t)0;
                }
                v.x = (unsigned)h[0] | ((unsigned)h[1] << 16);
                v.y = (unsigned)h[2] | ((unsigned)h[3] << 16);
                v.z = (unsigned)h[4] | ((unsigned)h[5] << 16);
                v.w = (unsigned)h[6] | ((unsigned)h[7] << 16);
            }
            *(uint4*)(Xs + r * PITCH + c * 8) = v;
        }
    } else {
        const ushort_t* actb = act + (size_t)b * LP * CP;
        for (int idx = tid; idx < ROWS * CPR; idx += 256) {
            int r = idx / CPR, c = idx % CPR;
            int l = l0 - P + r;
            uint4 v = {0u, 0u, 0u, 0u};
            if ((unsigned)l < (unsigned)LP) v = *(const uint4*)(actb + (size_t)l * CP + c * 8);
            *(uint4*)(Xs + r * PITCH + c * 8) = v;
        }
    }

    int lane = tid & 63, wv = tid >> 6;
    int cw = wv % CO_WAVES, lw = wv / CO_WAVES;
    int ln31 = lane & 31, half = lane >> 5;

    // A stream: fragment (tile, s) at Wb + ((tile*NS + s)*64 + lane) uint4s
    const uint4* A0 = (const uint4*)Wb + ((size_t)(cw * 2) * NS) * 64 + lane;
    // B base (ushort idx): row = lw*LSPAN + lt*32 + ln31 + t, col = cc*16 + half*8
    int bbase = (lw * LSPAN + ln31) * PITCH + half * 8;

    f32x16 acc[2][LT];
#pragma unroll
    for (int ct = 0; ct < 2; ++ct)
#pragma unroll
        for (int lt = 0; lt < LT; ++lt)
#pragma unroll
            for (int r = 0; r < 16; ++r) acc[ct][lt][r] = 0.f;

    __syncthreads();

    uint4 aC0 = A0[0];
    uint4 aC1 = A0[(size_t)NS * 64];
    uint4 bC[LT];
#pragma unroll
    for (int lt = 0; lt < LT; ++lt)
        bC[lt] = *(const uint4*)(Xs + bbase + lt * 32 * PITCH);

#pragma unroll
    for (int s = 0; s < NS; ++s) {
        int sn = (s + 1 < NS) ? s + 1 : NS - 1;   // folds at compile time (full unroll)
        int tn = sn / NC, ccn = sn % NC;
        uint4 aN0 = A0[(size_t)sn * 64];
        uint4 aN1 = A0[(size_t)(NS + sn) * 64];
        int off = bbase + tn * PITCH + ccn * 16;
        uint4 bN[LT];
#pragma unroll
        for (int lt = 0; lt < LT; ++lt)
            bN[lt] = *(const uint4*)(Xs + off + lt * 32 * PITCH);

#pragma unroll
        for (int lt = 0; lt < LT; ++lt) {
            acc[0][lt] = __builtin_amdgcn_mfma_f32_32x32x16_bf16(
                as_bf16x8(aC0), as_bf16x8(bC[lt]), acc[0][lt], 0, 0, 0);
            acc[1][lt] = __builtin_amdgcn_mfma_f32_32x32x16_bf16(
                as_bf16x8(aC1), as_bf16x8(bC[lt]), acc[1][lt], 0, 0, 0);
        }

        aC0 = aN0; aC1 = aN1;
#pragma unroll
        for (int lt = 0; lt < LT; ++lt) bC[lt] = bN[lt];
    }

    // C/D layout: col(l) = lane&31, row(co within tile) = (r&3) + 8*(r>>2) + 4*half
    if (!FMAX) {
        ushort_t* out = (ushort_t*)outv + (size_t)b * LP * COUT;
#pragma unroll
        for (int ct = 0; ct < 2; ++ct) {
            int cbase = (cw * 2 + ct) * 32 + 4 * half;
#pragma unroll
            for (int g = 0; g < 4; ++g) {
                int co = cbase + 8 * g;
                if (co >= COUT) continue;
                float4 bv = *(const float4*)(bias + co);
#pragma unroll
                for (int lt = 0; lt < LT; ++lt) {
                    int l = l0 + lw * LSPAN + lt * 32 + ln31;
                    if (l < LP) {
                        ushort_t h0 = f2bf(fmaxf(acc[ct][lt][4 * g + 0] + bv.x, 0.f));
                        ushort_t h1 = f2bf(fmaxf(acc[ct][lt][4 * g + 1] + bv.y, 0.f));
                        ushort_t h2 = f2bf(fmaxf(acc[ct][lt][4 * g + 2] + bv.z, 0.f));
                        ushort_t h3 = f2bf(fmaxf(acc[ct][lt][4 * g + 3] + bv.w, 0.f));
                        uint2 o;
                        o.x = (unsigned)h0 | ((unsigned)h1 << 16);
                        o.y = (unsigned)h2 | ((unsigned)h3 << 16);
                        *(uint2*)(out + (size_t)l * COUT + co) = o;
                    }
                }
            }
        }
    } else {
        float* xout = (float*)outv;
#pragma unroll
        for (int ct = 0; ct < 2; ++ct) {
            float mx[16];
#pragma unroll
            for (int r = 0; r < 16; ++r) mx[r] = -3.0e38f;
#pragma unroll
            for (int lt = 0; lt < LT; ++lt) {
                int l = l0 + lw * LSPAN + lt * 32 + ln31;
                if (l < LP) {
#pragma unroll
                    for (int r = 0; r < 16; ++r) mx[r] = fmaxf(mx[r], acc[ct][lt][r]);
                }
            }
#pragma unroll
            for (int r = 0; r < 16; ++r) {
#pragma unroll
                for (int off = 1; off < 32; off <<= 1)
                    mx[r] = fmaxf(mx[r], __shfl_xor(mx[r], off, 64));
            }
            if (ln31 == 0) {
                int cbase = (cw * 2 + ct) * 32 + 4 * half;
#pragma unroll
                for (int r = 0; r < 16; ++r) {
                    int co = cbase + (r & 3) + 8 * (r >> 2);
                    if (co < COUT) {
                        float v = fmaxf(mx[r] + bias[co], 0.f);
                        atomicMax((int*)&xout[(size_t)b * 400 + 200 + co], __float_as_int(v));
                    }
                }
            }
        }
    }
}

// Distinct names so rocprof disambiguates the tower.
__global__ __launch_bounds__(256, 2) void k_conv0(
        const int* __restrict__ seq, const float* __restrict__ emb,
        const ushort_t* __restrict__ Wb, const float* __restrict__ bias,
        ushort_t* __restrict__ out) {
    __shared__ __align__(16) ushort_t Xs[(256 + 2) * (64 + 8)];
    conv_body<64, 3, 96, 2, 2, 4, false, true>(nullptr, seq, emb, Wb, bias, out, Xs);
}
__global__ __launch_bounds__(256, 2) void k_conv1(
        const ushort_t* __restrict__ act, const ushort_t* __restrict__ Wb,
        const float* __restrict__ bias, ushort_t* __restrict__ out) {
    __shared__ __align__(16) ushort_t Xs[(256 + 4) * (96 + 8)];
    conv_body<96, 5, 128, 2, 2, 4, false, false>(act, nullptr, nullptr, Wb, bias, out, Xs);
}
__global__ __launch_bounds__(256, 2) void k_conv2(
        const ushort_t* __restrict__ act, const ushort_t* __restrict__ Wb,
        const float* __restrict__ bias, float* __restrict__ x) {
    __shared__ __align__(16) ushort_t Xs[(128 + 6) * (128 + 8)];
    conv_body<128, 7, 200, 4, 1, 4, true, false>(act, nullptr, nullptr, Wb, bias, x, Xs);
}

// ---------------- binput = fbonds @ W_i ; msg = relu(binput) ----------------
__global__ __launch_bounds__(256) void k_bond_input(
        const float* __restrict__ fbonds, const float* __restrict__ Wi,
        float* __restrict__ binput, float* __restrict__ msg) {
    int bond0 = blockIdx.x * BIPB;
    __shared__ float fb[BIPB][BFD];
    int tid = threadIdx.x;
    if (tid < BIPB * BFD) fb[tid / BFD][tid % BFD] = fbonds[(size_t)bond0 * BFD + tid];
    __syncthreads();
    if (tid < H) {
        float acc[BIPB];
#pragma unroll
        for (int q = 0; q < BIPB; ++q) acc[q] = 0.f;
#pragma unroll 5
        for (int k = 0; k < BFD; ++k) {
            float w = Wi[k * H + tid];
#pragma unroll
            for (int q = 0; q < BIPB; ++q) acc[q] += fb[q][k] * w;
        }
#pragma unroll
        for (int q = 0; q < BIPB; ++q) {
            size_t o = (size_t)(bond0 + q) * H + tid;
            binput[o] = acc[q];
            msg[o] = fmaxf(acc[q], 0.f);
        }
    }
}

// ---------------- message update: msgOut = relu(binput + (sum nei) @ W_h) ----------------
__global__ __launch_bounds__(256) void k_msg(
        const float* __restrict__ msgIn, const float* __restrict__ binput,
        const int* __restrict__ bgraph, const float* __restrict__ Wh,
        float* __restrict__ msgOut) {
    const int grpPerMol = NBB / BPB;
    int b = blockIdx.x / grpPerMol;
    int grp = blockIdx.x % grpPerMol;
    int bond0 = grp * BPB;
    __shared__ int idxs[BPB * 6];
    __shared__ float nei[BPB][H];
    int tid = threadIdx.x;
    if (tid < BPB * 6) idxs[tid] = bgraph[((size_t)(b * NBB + bond0)) * 6 + tid];
    __syncthreads();
    if (tid < H) {
        const float* base = msgIn + (size_t)b * NBB * H;
#pragma unroll
        for (int q = 0; q < BPB; ++q) {
            float s = 0.f;
#pragma unroll
            for (int j = 0; j < 6; ++j) s += base[(size_t)idxs[q * 6 + j] * H + tid];
            nei[q][tid] = s;
        }
    }
    __syncthreads();
    if (tid < H) {
        float acc[BPB];
#pragma unroll
        for (int q = 0; q < BPB; ++q)
            acc[q] = binput[((size_t)(b * NBB + bond0 + q)) * H + tid];
#pragma unroll 4
        for (int hi = 0; hi < H; ++hi) {
            float w = Wh[hi * H + tid];
#pragma unroll
            for (int q = 0; q < BPB; ++q) acc[q] += nei[q][hi] * w;
        }
#pragma unroll
        for (int q = 0; q < BPB; ++q)
            msgOut[((size_t)(b * NBB + bond0 + q)) * H + tid] = fmaxf(acc[q], 0.f);
    }
}

// ---------------- atom head: relu(cat(fa, nei) @ W_o + b), mean -> x[:, :200] ----------------
__global__ __launch_bounds__(256) void k_atom(
        const float* __restrict__ msg, const float* __restrict__ fatoms,
        const int* __restrict__ agraph, const float* __restrict__ Wo,
        const float* __restrict__ Wob, float* __restrict__ x) {
    const int grpPerMol = NA / APB;
    int b = blockIdx.x / grpPerMol;
    int grp = blockIdx.x % grpPerMol;
    int atom0 = grp * APB;
    __shared__ int idxs[APB * 6];
    __shared__ float cat[APB][CATD];
    int tid = threadIdx.x;
    if (tid < APB * 6) idxs[tid] = agraph[((size_t)(b * NA + atom0)) * 6 + tid];
    if (tid >= 64 && tid < 64 + APB * AFD) {
        int t = tid - 64;
        int q = t / AFD, c = t % AFD;
        cat[q][c] = fatoms[((size_t)(b * NA + atom0 + q)) * AFD + c];
    }
    __syncthreads();
    if (tid < H) {
        const float* base = msg + (size_t)b * NBB * H;
#pragma unroll
        for (int q = 0; q < APB; ++q) {
            float s = 0.f;
#pragma unroll
            for (int j = 0; j < 6; ++j) s += base[(size_t)idxs[q * 6 + j] * H + tid];
            cat[q][AFD + tid] = s;
        }
    }
    __syncthreads();
    if (tid < H) {
        float bb = Wob[tid];
        float acc0 = bb, acc1 = bb;
#pragma unroll 4
        for (int k = 0; k < CATD; ++k) {
            float w = Wo[k * H + tid];
            acc0 += cat[0][k] * w;
            acc1 += cat[1][k] * w;
        }
        atomicAdd(&x[(size_t)b * 400 + tid],
                  (fmaxf(acc0, 0.f) + fmaxf(acc1, 0.f)) * (1.f / NA));
    }
}

// ---------------- fused FC head: 400 -> 200 -> 100 -> 1 ----------------
__global__ __launch_bounds__(256) void k_fc(
        const float* __restrict__ x,
        const float* __restrict__ w0, const float* __restrict__ b0,
        const float* __restrict__ w1, const float* __restrict__ b1,
        const float* __restrict__ w2, const float* __restrict__ b2,
        float* __restrict__ out) {
    int b = blockIdx.x, tid = threadIdx.x;
    __shared__ float xr[400];
    __shared__ float h1[200];
    __shared__ float h2[100];
    for (int i = tid; i < 400; i += 256) xr[i] = x[(size_t)b * 400 + i];
    __syncthreads();
    if (tid < 200) {
        float a = b0[tid];
#pragma unroll 4
        for (int k = 0; k < 400; ++k) a += xr[k] * w0[k * 200 + tid];
        h1[tid] = fmaxf(a, 0.f);
    }
    __syncthreads();
    if (tid < 100) {
        float a = b1[tid];
#pragma unroll 4
        for (int k = 0; k < 200; ++k) a += h1[k] * w1[k * 100 + tid];
        h2[tid] = fmaxf(a, 0.f);
    }
    __syncthreads();
    if (tid == 0) {
        float a = b2[0];
#pragma unroll 4
        for (int k = 0; k < 100; ++k) a += h2[k] * w2[k];
        out[b] = a;
    }
}

extern "C" void kernel_launch(void* const* d_in, const int* in_sizes, int n_in,
                              void* d_out, int out_size, void* d_ws, size_t ws_size,
                              hipStream_t stream) {
    const float* fatoms = (const float*)d_in[0];
    const float* fbonds = (const float*)d_in[1];
    const int* agraph = (const int*)d_in[2];
    const int* bgraph = (const int*)d_in[3];
    const int* seq = (const int*)d_in[4];
    const float* Wi = (const float*)d_in[5];
    const float* Wh = (const float*)d_in[6];
    const float* Wo = (const float*)d_in[7];
    const float* Wob = (const float*)d_in[8];
    const float* embp = (const float*)d_in[9];
    const float* c0w = (const float*)d_in[10];
    const float* c0b = (const float*)d_in[11];
    const float* c1w = (const float*)d_in[12];
    const float* c1b = (const float*)d_in[13];
    const float* c2w = (const float*)d_in[14];
    const float* c2b = (const float*)d_in[15];
    const float* fc0w = (const float*)d_in[16];
    const float* fc0b = (const float*)d_in[17];
    const float* fc1w = (const float*)d_in[18];
    const float* fc1b = (const float*)d_in[19];
    const float* fc2w = (const float*)d_in[20];
    const float* fc2b = (const float*)d_in[21];

    float* ws = (float*)d_ws;
    float* binput = ws;                    // 2457600
    float* msgA = binput + 2457600;        // 2457600
    float* msgB = msgA + 2457600;          // 2457600
    float* x = msgB + 2457600;             // 51200
    ushort_t* u = (ushort_t*)(x + 51200);  // bf16 region
    ushort_t* act1 = u;                    // 128000*96  = 12288000
    ushort_t* act2 = act1 + 12288000;      // 128000*128 = 16384000
    ushort_t* Wb0 = act2 + 16384000;       // 4*12*512  = 24576
    ushort_t* Wb1 = Wb0 + 24576;           // 4*30*512  = 61440
    ushort_t* Wb2 = Wb1 + 61440;           // 8*56*512  = 229376

    // fused: weight swizzles + zero x (k_atom atomicAdd / conv2 atomicMax need zeros)
    k_prep_all<<<(PREP_T3 + 255) / 256, 256, 0, stream>>>(c0w, c1w, c2w, x, Wb0, Wb1, Wb2);

    // ---- MPNN ----
    k_bond_input<<<BATCH * NBB / BIPB, 256, 0, stream>>>(fbonds, Wi, binput, msgA);
    k_msg<<<BATCH * NBB / BPB, 256, 0, stream>>>(msgA, binput, bgraph, Wh, msgB);
    k_msg<<<BATCH * NBB / BPB, 256, 0, stream>>>(msgB, binput, bgraph, Wh, msgA);
    k_atom<<<BATCH * NA / APB, 256, 0, stream>>>(msgA, fatoms, agraph, Wo, Wob, x);

    // ---- protein tower (bf16 MFMA, 32x32x16; conv0 fuses embedding) ----
    // LTILE: conv0/conv1 = 256 (4 l-blocks), conv2 = 128 (8 l-blocks)
    k_conv0<<<dim3(4, 1, BATCH), 256, 0, stream>>>(seq, embp, Wb0, c0b, act1);
    k_conv1<<<dim3(4, 1, BATCH), 256, 0, stream>>>(act1, Wb1, c1b, act2);
    k_conv2<<<dim3(8, 1, BATCH), 256, 0, stream>>>(act2, Wb2, c2b, x);

    // ---- fused FC head ----
    k_fc<<<BATCH, 256, 0, stream>>>(x, fc0w, fc0b, fc1w, fc1b, fc2w, fc2b, (float*)d_out);
}

// Round 5
// 396.597 us; speedup vs baseline: 1.1235x; 1.1235x over previous
//
#include <hip/hip_runtime.h>
#include <hip/hip_bf16.h>
#include <cstddef>

#define H 200
#define NA 48
#define NBB 96
#define BATCH 128
#define AFD 39
#define BFD 50          // 39+11
#define LP 1000
#define CATD (AFD + H)  // 239
#define BPB 4           // bonds per block in message kernel (APB/BPB=8 spilled in R3)
#define APB 2           // atoms per block in atom kernel
#define BIPB 4          // bonds per block in bond-input kernel

typedef unsigned short ushort_t;
typedef __bf16 bf16x8 __attribute__((ext_vector_type(8)));
typedef float f32x16 __attribute__((ext_vector_type(16)));
typedef unsigned uint32x4 __attribute__((ext_vector_type(4)));

union U16B { uint4 u; bf16x8 b; };
static __device__ __forceinline__ bf16x8 as_bf16x8(uint4 u) { U16B x; x.u = u; return x.b; }
union U16B2 { uint32x4 u; bf16x8 b; };
static __device__ __forceinline__ bf16x8 as_bf16x8v(uint32x4 u) { U16B2 x; x.u = u; return x.b; }

// float -> bf16 (RNE)
static __device__ __forceinline__ ushort_t f2bf(float f) {
    union { float f; unsigned u; } a; a.f = f;
    unsigned r = (a.u + 0x7FFFu + ((a.u >> 16) & 1u)) >> 16;
    return (ushort_t)r;
}

// raw asm global load: 16B at sgpr-base + 32-bit voffset. asm volatile pins issue
// order -> counted vmcnt discipline stays valid. "=&v" early-clobber: dest quad
// must not alias inputs (load result lands asynchronously).
static __device__ __forceinline__ uint32x4 gload16(const ushort_t* base, unsigned voff) {
    uint32x4 r;
    asm volatile("global_load_dwordx4 %0, %1, %2"
                 : "=&v"(r) : "v"(voff), "s"(base));
    return r;
}

// ---------------- fused prep: 3 weight swizzles (32x32x16 A-frag order) + zero x ----------------
// Wb[((tile*NS + s)*64 + lane)*8 + j] = bf16(w[co][ci][t])
//   co = tile*32 + (lane&31), t = s/NC, cc = s%NC, ci = cc*16 + (lane>>5)*8 + j
template <int COUT, int CIN, int CP, int K>
static __device__ __forceinline__ void prep_one(int t, const float* __restrict__ w,
                                                ushort_t* __restrict__ Wb) {
    constexpr int NC = CP / 16;
    constexpr int NS = K * NC;
    int j = t & 7;
    int lane = (t >> 3) & 63;
    int s = (t >> 9) % NS;
    int ct = (t >> 9) / NS;
    int co = ct * 32 + (lane & 31);
    int tt = s / NC, cc = s % NC;
    int ci = cc * 16 + ((lane >> 5) & 1) * 8 + j;
    float v = 0.f;
    if (co < COUT && ci < CIN) v = w[((size_t)co * CIN + ci) * K + tt];
    Wb[t] = f2bf(v);
}

#define PREP_T0 (4 * 12 * 512)            // conv0: 4 tiles x NS=12
#define PREP_T1 (PREP_T0 + 4 * 30 * 512)  // conv1: 4 tiles x NS=30
#define PREP_T2 (PREP_T1 + 8 * 56 * 512)  // conv2: 8 tiles x NS=56
#define PREP_T3 (PREP_T2 + 51200)         // zero x

__global__ __launch_bounds__(256) void k_prep_all(
        const float* __restrict__ c0w, const float* __restrict__ c1w,
        const float* __restrict__ c2w, float* __restrict__ x,
        ushort_t* __restrict__ Wb0, ushort_t* __restrict__ Wb1,
        ushort_t* __restrict__ Wb2) {
    int tid = blockIdx.x * 256 + threadIdx.x;
    if (tid < PREP_T0) prep_one<96, 50, 64, 3>(tid, c0w, Wb0);
    else if (tid < PREP_T1) prep_one<128, 96, 96, 5>(tid - PREP_T0, c1w, Wb1);
    else if (tid < PREP_T2) prep_one<200, 128, 128, 7>(tid - PREP_T1, c2w, Wb2);
    else if (tid < PREP_T3) x[tid - PREP_T2] = 0.f;
}

// ---------------- MFMA conv1d body, 32x32x16 ----------------
// R8 = R7 resubmit (R4 bench was an infra failure, no data). Wall model from R0/R6:
// wall = 723 + 158*work -> fixed 723cy = exposed A-load latency (compiler keeps only
// ~1-step prefetch; flattened R4's source-level ring). Fix: inline-asm A ring (depth
// D=4, asm volatile -> unflattenable), counted s_waitcnt vmcnt(2*(D-1)) per step
// (never 0 until tail) + sched_barrier(0) so MFMAs can't hoist above the wait
// (rule #18). AITER-style MFMA<->load 1:1. No barriers in loop; 3 blk/CU unchanged.
template <int CP, int K, int COUT, int CO_WAVES, int L_WAVES, bool FMAX, bool EMB>
static __device__ __forceinline__ void conv_body(
        const ushort_t* __restrict__ act, const int* __restrict__ seq,
        const float* __restrict__ emb, const ushort_t* __restrict__ Wb,
        const float* __restrict__ bias, void* __restrict__ outv,
        ushort_t* __restrict__ Xs) {
    constexpr int NC = CP / 16;
    constexpr int NS = K * NC;
    constexpr int P = K / 2;
    constexpr int PITCH = CP + 8;     // ushorts; 16B-aligned rows, non-pow2 bank stride
    constexpr int LTILE = 64 * L_WAVES;
    constexpr int ROWS = LTILE + K - 1;
    constexpr int CPR = CP / 8;
    constexpr int D = 4;              // A-ring depth (asm-pinned)

    int b = blockIdx.z, lb = blockIdx.x;
    int l0 = lb * LTILE;
    int tid = threadIdx.x;

    // ---- stage X tile (halo, zero-padded at edges) ----
    if (EMB) {
        const int* seqb = seq + (size_t)b * LP;
        for (int idx = tid; idx < ROWS * CPR; idx += 256) {
            int r = idx / CPR, c = idx % CPR;
            int l = l0 - P + r;
            uint4 v = {0u, 0u, 0u, 0u};
            if ((unsigned)l < (unsigned)LP) {
                int s = seqb[l];
                const float* e = emb + (size_t)s * 50;
                ushort_t h[8];
#pragma unroll
                for (int j = 0; j < 8; ++j) {
                    int cc = c * 8 + j;
                    h[j] = (cc < 50) ? f2bf(e[cc]) : (ushort_t)0;
                }
                v.x = (unsigned)h[0] | ((unsigned)h[1] << 16);
                v.y = (unsigned)h[2] | ((unsigned)h[3] << 16);
                v.z = (unsigned)h[4] | ((unsigned)h[5] << 16);
                v.w = (unsigned)h[6] | ((unsigned)h[7] << 16);
            }
            *(uint4*)(Xs + r * PITCH + c * 8) = v;
        }
    } else {
        const ushort_t* actb = act + (size_t)b * LP * CP;
        for (int idx = tid; idx < ROWS * CPR; idx += 256) {
            int r = idx / CPR, c = idx % CPR;
            int l = l0 - P + r;
            uint4 v = {0u, 0u, 0u, 0u};
            if ((unsigned)l < (unsigned)LP) v = *(const uint4*)(actb + (size_t)l * CP + c * 8);
            *(uint4*)(Xs + r * PITCH + c * 8) = v;
        }
    }

    int lane = tid & 63, wv = tid >> 6;
    int cw = wv % CO_WAVES, lw = wv / CO_WAVES;
    int ln31 = lane & 31, half = lane >> 5;

    // A byte offsets: fragment (tile, s) at byte (tile*NS + s)*1024 + lane*16
    unsigned abase0 = (unsigned)(cw * 2) * (unsigned)NS * 1024u + (unsigned)lane * 16u;
    unsigned abase1 = abase0 + (unsigned)NS * 1024u;
    // B base (ushort idx): row = lw*64 + lt*32 + ln31 + t, col = cc*16 + half*8
    int bbase = (lw * 64 + ln31) * PITCH + half * 8;

    f32x16 acc[2][2];
#pragma unroll
    for (int ct = 0; ct < 2; ++ct)
#pragma unroll
        for (int lt = 0; lt < 2; ++lt)
#pragma unroll
            for (int r = 0; r < 16; ++r) acc[ct][lt][r] = 0.f;

    __syncthreads();   // drains staging vmem -> vmcnt below counts ONLY ring loads

    // ---- A ring prologue: D slots (2 loads each) in flight, slot-major order ----
    uint32x4 ra0[D], ra1[D];
#pragma unroll
    for (int d = 0; d < D; ++d) {
        ra0[d] = gload16(Wb, abase0 + (unsigned)(d * 1024));
        ra1[d] = gload16(Wb, abase1 + (unsigned)(d * 1024));
    }

    uint4 bC0 = *(const uint4*)(Xs + bbase);
    uint4 bC1 = *(const uint4*)(Xs + bbase + 32 * PITCH);

#pragma unroll
    for (int s = 0; s < NS; ++s) {
        // B next (LDS; lgkmcnt is compiler-scheduled, 1-ahead is enough)
        int sn = (s + 1 < NS) ? s + 1 : NS - 1;   // folds at compile time (full unroll)
        int tn = sn / NC, ccn = sn % NC;
        int off = bbase + tn * PITCH + ccn * 16;
        uint4 bN0 = *(const uint4*)(Xs + off);
        uint4 bN1 = *(const uint4*)(Xs + off + 32 * PITCH);

        // counted wait: slot-s loads landed when <= 2*min(D-1, NS-1-s) remain outstanding
        {
            const int rem = NS - 1 - s;
            const int allow = 2 * ((D - 1) < rem ? (D - 1) : rem);
            asm volatile("s_waitcnt vmcnt(%0)" :: "i"(allow) : "memory");
            __builtin_amdgcn_sched_barrier(0);
        }

        uint32x4 a0 = ra0[s % D];
        uint32x4 a1 = ra1[s % D];

        acc[0][0] = __builtin_amdgcn_mfma_f32_32x32x16_bf16(
            as_bf16x8v(a0), as_bf16x8(bC0), acc[0][0], 0, 0, 0);
        acc[1][0] = __builtin_amdgcn_mfma_f32_32x32x16_bf16(
            as_bf16x8v(a1), as_bf16x8(bC0), acc[1][0], 0, 0, 0);
        acc[0][1] = __builtin_amdgcn_mfma_f32_32x32x16_bf16(
            as_bf16x8v(a0), as_bf16x8(bC1), acc[0][1], 0, 0, 0);
        acc[1][1] = __builtin_amdgcn_mfma_f32_32x32x16_bf16(
            as_bf16x8v(a1), as_bf16x8(bC1), acc[1][1], 0, 0, 0);

        // refill slot s%D with step s+D (WAR on ra[] orders vs MFMAs; HW pattern = AITER)
        if (s + D < NS) {
            ra0[s % D] = gload16(Wb, abase0 + (unsigned)((s + D) * 1024));
            ra1[s % D] = gload16(Wb, abase1 + (unsigned)((s + D) * 1024));
        }

        bC0 = bN0; bC1 = bN1;
    }

    // C/D layout: col(l) = lane&31, row(co within tile) = (r&3) + 8*(r>>2) + 4*half
    if (!FMAX) {
        ushort_t* out = (ushort_t*)outv + (size_t)b * LP * COUT;
#pragma unroll
        for (int ct = 0; ct < 2; ++ct) {
            int cbase = (cw * 2 + ct) * 32 + 4 * half;
#pragma unroll
            for (int g = 0; g < 4; ++g) {
                int co = cbase + 8 * g;
                if (co >= COUT) continue;
                float4 bv = *(const float4*)(bias + co);
#pragma unroll
                for (int lt = 0; lt < 2; ++lt) {
                    int l = l0 + lw * 64 + lt * 32 + ln31;
                    if (l < LP) {
                        ushort_t h0 = f2bf(fmaxf(acc[ct][lt][4 * g + 0] + bv.x, 0.f));
                        ushort_t h1 = f2bf(fmaxf(acc[ct][lt][4 * g + 1] + bv.y, 0.f));
                        ushort_t h2 = f2bf(fmaxf(acc[ct][lt][4 * g + 2] + bv.z, 0.f));
                        ushort_t h3 = f2bf(fmaxf(acc[ct][lt][4 * g + 3] + bv.w, 0.f));
                        uint2 o;
                        o.x = (unsigned)h0 | ((unsigned)h1 << 16);
                        o.y = (unsigned)h2 | ((unsigned)h3 << 16);
                        *(uint2*)(out + (size_t)l * COUT + co) = o;
                    }
                }
            }
        }
    } else {
        float* xout = (float*)outv;
#pragma unroll
        for (int ct = 0; ct < 2; ++ct) {
            float mx[16];
#pragma unroll
            for (int r = 0; r < 16; ++r) mx[r] = -3.0e38f;
#pragma unroll
            for (int lt = 0; lt < 2; ++lt) {
                int l = l0 + lw * 64 + lt * 32 + ln31;
                if (l < LP) {
#pragma unroll
                    for (int r = 0; r < 16; ++r) mx[r] = fmaxf(mx[r], acc[ct][lt][r]);
                }
            }
#pragma unroll
            for (int r = 0; r < 16; ++r) {
#pragma unroll
                for (int off = 1; off < 32; off <<= 1)
                    mx[r] = fmaxf(mx[r], __shfl_xor(mx[r], off, 64));
            }
            if (ln31 == 0) {
                int cbase = (cw * 2 + ct) * 32 + 4 * half;
#pragma unroll
                for (int r = 0; r < 16; ++r) {
                    int co = cbase + (r & 3) + 8 * (r >> 2);
                    if (co < COUT) {
                        float v = fmaxf(mx[r] + bias[co], 0.f);
                        atomicMax((int*)&xout[(size_t)b * 400 + 200 + co], __float_as_int(v));
                    }
                }
            }
        }
    }
}

// Distinct names so rocprof disambiguates the tower.
__global__ __launch_bounds__(256, 3) void k_conv0(
        const int* __restrict__ seq, const float* __restrict__ emb,
        const ushort_t* __restrict__ Wb, const float* __restrict__ bias,
        ushort_t* __restrict__ out) {
    __shared__ __align__(16) ushort_t Xs[(128 + 2) * (64 + 8)];
    conv_body<64, 3, 96, 2, 2, false, true>(nullptr, seq, emb, Wb, bias, out, Xs);
}
__global__ __launch_bounds__(256, 3) void k_conv1(
        const ushort_t* __restrict__ act, const ushort_t* __restrict__ Wb,
        const float* __restrict__ bias, ushort_t* __restrict__ out) {
    __shared__ __align__(16) ushort_t Xs[(128 + 4) * (96 + 8)];
    conv_body<96, 5, 128, 2, 2, false, false>(act, nullptr, nullptr, Wb, bias, out, Xs);
}
__global__ __launch_bounds__(256, 3) void k_conv2(
        const ushort_t* __restrict__ act, const ushort_t* __restrict__ Wb,
        const float* __restrict__ bias, float* __restrict__ x) {
    __shared__ __align__(16) ushort_t Xs[(64 + 6) * (128 + 8)];
    conv_body<128, 7, 200, 4, 1, true, false>(act, nullptr, nullptr, Wb, bias, x, Xs);
}

// ---------------- binput = fbonds @ W_i ; msg = relu(binput) ----------------
__global__ __launch_bounds__(256) void k_bond_input(
        const float* __restrict__ fbonds, const float* __restrict__ Wi,
        float* __restrict__ binput, float* __restrict__ msg) {
    int bond0 = blockIdx.x * BIPB;
    __shared__ float fb[BIPB][BFD];
    int tid = threadIdx.x;
    if (tid < BIPB * BFD) fb[tid / BFD][tid % BFD] = fbonds[(size_t)bond0 * BFD + tid];
    __syncthreads();
    if (tid < H) {
        float acc[BIPB];
#pragma unroll
        for (int q = 0; q < BIPB; ++q) acc[q] = 0.f;
#pragma unroll 5
        for (int k = 0; k < BFD; ++k) {
            float w = Wi[k * H + tid];
#pragma unroll
            for (int q = 0; q < BIPB; ++q) acc[q] += fb[q][k] * w;
        }
#pragma unroll
        for (int q = 0; q < BIPB; ++q) {
            size_t o = (size_t)(bond0 + q) * H + tid;
            binput[o] = acc[q];
            msg[o] = fmaxf(acc[q], 0.f);
        }
    }
}

// ---------------- message update: msgOut = relu(binput + (sum nei) @ W_h) ----------------
__global__ __launch_bounds__(256) void k_msg(
        const float* __restrict__ msgIn, const float* __restrict__ binput,
        const int* __restrict__ bgraph, const float* __restrict__ Wh,
        float* __restrict__ msgOut) {
    const int grpPerMol = NBB / BPB;
    int b = blockIdx.x / grpPerMol;
    int grp = blockIdx.x % grpPerMol;
    int bond0 = grp * BPB;
    __shared__ int idxs[BPB * 6];
    __shared__ float nei[BPB][H];
    int tid = threadIdx.x;
    if (tid < BPB * 6) idxs[tid] = bgraph[((size_t)(b * NBB + bond0)) * 6 + tid];
    __syncthreads();
    if (tid < H) {
        const float* base = msgIn + (size_t)b * NBB * H;
#pragma unroll
        for (int q = 0; q < BPB; ++q) {
            float s = 0.f;
#pragma unroll
            for (int j = 0; j < 6; ++j) s += base[(size_t)idxs[q * 6 + j] * H + tid];
            nei[q][tid] = s;
        }
    }
    __syncthreads();
    if (tid < H) {
        float acc[BPB];
#pragma unroll
        for (int q = 0; q < BPB; ++q)
            acc[q] = binput[((size_t)(b * NBB + bond0 + q)) * H + tid];
#pragma unroll 4
        for (int hi = 0; hi < H; ++hi) {
            float w = Wh[hi * H + tid];
#pragma unroll
            for (int q = 0; q < BPB; ++q) acc[q] += nei[q][hi] * w;
        }
#pragma unroll
        for (int q = 0; q < BPB; ++q)
            msgOut[((size_t)(b * NBB + bond0 + q)) * H + tid] = fmaxf(acc[q], 0.f);
    }
}

// ---------------- atom head: relu(cat(fa, nei) @ W_o + b), mean -> x[:, :200] ----------------
__global__ __launch_bounds__(256) void k_atom(
        const float* __restrict__ msg, const float* __restrict__ fatoms,
        const int* __restrict__ agraph, const float* __restrict__ Wo,
        const float* __restrict__ Wob, float* __restrict__ x) {
    const int grpPerMol = NA / APB;
    int b = blockIdx.x / grpPerMol;
    int grp = blockIdx.x % grpPerMol;
    int atom0 = grp * APB;
    __shared__ int idxs[APB * 6];
    __shared__ float cat[APB][CATD];
    int tid = threadIdx.x;
    if (tid < APB * 6) idxs[tid] = agraph[((size_t)(b * NA + atom0)) * 6 + tid];
    if (tid >= 64 && tid < 64 + APB * AFD) {
        int t = tid - 64;
        int q = t / AFD, c = t % AFD;
        cat[q][c] = fatoms[((size_t)(b * NA + atom0 + q)) * AFD + c];
    }
    __syncthreads();
    if (tid < H) {
        const float* base = msg + (size_t)b * NBB * H;
#pragma unroll
        for (int q = 0; q < APB; ++q) {
            float s = 0.f;
#pragma unroll
            for (int j = 0; j < 6; ++j) s += base[(size_t)idxs[q * 6 + j] * H + tid];
            cat[q][AFD + tid] = s;
        }
    }
    __syncthreads();
    if (tid < H) {
        float bb = Wob[tid];
        float acc0 = bb, acc1 = bb;
#pragma unroll 4
        for (int k = 0; k < CATD; ++k) {
            float w = Wo[k * H + tid];
            acc0 += cat[0][k] * w;
            acc1 += cat[1][k] * w;
        }
        atomicAdd(&x[(size_t)b * 400 + tid],
                  (fmaxf(acc0, 0.f) + fmaxf(acc1, 0.f)) * (1.f / NA));
    }
}

// ---------------- fused FC head: 400 -> 200 -> 100 -> 1 ----------------
__global__ __launch_bounds__(256) void k_fc(
        const float* __restrict__ x,
        const float* __restrict__ w0, const float* __restrict__ b0,
        const float* __restrict__ w1, const float* __restrict__ b1,
        const float* __restrict__ w2, const float* __restrict__ b2,
        float* __restrict__ out) {
    int b = blockIdx.x, tid = threadIdx.x;
    __shared__ float xr[400];
    __shared__ float h1[200];
    __shared__ float h2[100];
    for (int i = tid; i < 400; i += 256) xr[i] = x[(size_t)b * 400 + i];
    __syncthreads();
    if (tid < 200) {
        float a = b0[tid];
#pragma unroll 4
        for (int k = 0; k < 400; ++k) a += xr[k] * w0[k * 200 + tid];
        h1[tid] = fmaxf(a, 0.f);
    }
    __syncthreads();
    if (tid < 100) {
        float a = b1[tid];
#pragma unroll 4
        for (int k = 0; k < 200; ++k) a += h1[k] * w1[k * 100 + tid];
        h2[tid] = fmaxf(a, 0.f);
    }
    __syncthreads();
    if (tid == 0) {
        float a = b2[0];
#pragma unroll 4
        for (int k = 0; k < 100; ++k) a += h2[k] * w2[k];
        out[b] = a;
    }
}

extern "C" void kernel_launch(void* const* d_in, const int* in_sizes, int n_in,
                              void* d_out, int out_size, void* d_ws, size_t ws_size,
                              hipStream_t stream) {
    const float* fatoms = (const float*)d_in[0];
    const float* fbonds = (const float*)d_in[1];
    const int* agraph = (const int*)d_in[2];
    const int* bgraph = (const int*)d_in[3];
    const int* seq = (const int*)d_in[4];
    const float* Wi = (const float*)d_in[5];
    const float* Wh = (const float*)d_in[6];
    const float* Wo = (const float*)d_in[7];
    const float* Wob = (const float*)d_in[8];
    const float* embp = (const float*)d_in[9];
    const float* c0w = (const float*)d_in[10];
    const float* c0b = (const float*)d_in[11];
    const float* c1w = (const float*)d_in[12];
    const float* c1b = (const float*)d_in[13];
    const float* c2w = (const float*)d_in[14];
    const float* c2b = (const float*)d_in[15];
    const float* fc0w = (const float*)d_in[16];
    const float* fc0b = (const float*)d_in[17];
    const float* fc1w = (const float*)d_in[18];
    const float* fc1b = (const float*)d_in[19];
    const float* fc2w = (const float*)d_in[20];
    const float* fc2b = (const float*)d_in[21];

    float* ws = (float*)d_ws;
    float* binput = ws;                    // 2457600
    float* msgA = binput + 2457600;        // 2457600
    float* msgB = msgA + 2457600;          // 2457600
    float* x = msgB + 2457600;             // 51200
    ushort_t* u = (ushort_t*)(x + 51200);  // bf16 region
    ushort_t* act1 = u;                    // 128000*96  = 12288000
    ushort_t* act2 = act1 + 12288000;      // 128000*128 = 16384000
    ushort_t* Wb0 = act2 + 16384000;       // 4*12*512  = 24576
    ushort_t* Wb1 = Wb0 + 24576;           // 4*30*512  = 61440
    ushort_t* Wb2 = Wb1 + 61440;           // 8*56*512  = 229376

    // fused: weight swizzles + zero x (k_atom atomicAdd / conv2 atomicMax need zeros)
    k_prep_all<<<(PREP_T3 + 255) / 256, 256, 0, stream>>>(c0w, c1w, c2w, x, Wb0, Wb1, Wb2);

    // ---- MPNN ----
    k_bond_input<<<BATCH * NBB / BIPB, 256, 0, stream>>>(fbonds, Wi, binput, msgA);
    k_msg<<<BATCH * NBB / BPB, 256, 0, stream>>>(msgA, binput, bgraph, Wh, msgB);
    k_msg<<<BATCH * NBB / BPB, 256, 0, stream>>>(msgB, binput, bgraph, Wh, msgA);
    k_atom<<<BATCH * NA / APB, 256, 0, stream>>>(msgA, fatoms, agraph, Wo, Wob, x);

    // ---- protein tower (bf16 MFMA, 32x32x16; conv0 fuses embedding) ----
    k_conv0<<<dim3(8, 1, BATCH), 256, 0, stream>>>(seq, embp, Wb0, c0b, act1);
    k_conv1<<<dim3(8, 1, BATCH), 256, 0, stream>>>(act1, Wb1, c1b, act2);
    k_conv2<<<dim3(16, 1, BATCH), 256, 0, stream>>>(act2, Wb2, c2b, x);

    // ---- fused FC head ----
    k_fc<<<BATCH, 256, 0, stream>>>(x, fc0w, fc0b, fc1w, fc1b, fc2w, fc2b, (float*)d_out);
}

// Round 6
// 392.438 us; speedup vs baseline: 1.1354x; 1.0106x over previous
//
#include <hip/hip_runtime.h>
#include <hip/hip_bf16.h>
#include <cstddef>

#define H 200
#define NA 48
#define NBB 96
#define BATCH 128
#define AFD 39
#define BFD 50          // 39+11
#define LP 1000
#define CATD (AFD + H)  // 239
#define BPB 16          // bonds per block in message kernel (R9: 4->16, amortize Wh reads)
#define APB 8           // atoms per block in atom kernel (R9: 2->8, amortize Wo reads)
#define BIPB 16         // bonds per block in bond-input kernel (R9: 4->16)

typedef unsigned short ushort_t;
typedef __bf16 bf16x8 __attribute__((ext_vector_type(8)));
typedef float f32x16 __attribute__((ext_vector_type(16)));
typedef unsigned uint32x4 __attribute__((ext_vector_type(4)));

union U16B { uint4 u; bf16x8 b; };
static __device__ __forceinline__ bf16x8 as_bf16x8(uint4 u) { U16B x; x.u = u; return x.b; }
union U16B2 { uint32x4 u; bf16x8 b; };
static __device__ __forceinline__ bf16x8 as_bf16x8v(uint32x4 u) { U16B2 x; x.u = u; return x.b; }

// float -> bf16 (RNE)
static __device__ __forceinline__ ushort_t f2bf(float f) {
    union { float f; unsigned u; } a; a.f = f;
    unsigned r = (a.u + 0x7FFFu + ((a.u >> 16) & 1u)) >> 16;
    return (ushort_t)r;
}

// raw asm global load: 16B at sgpr-base + 32-bit voffset. asm volatile pins issue
// order -> counted vmcnt discipline stays valid. "=&v" early-clobber: dest quad
// must not alias inputs (load result lands asynchronously).
static __device__ __forceinline__ uint32x4 gload16(const ushort_t* base, unsigned voff) {
    uint32x4 r;
    asm volatile("global_load_dwordx4 %0, %1, %2"
                 : "=&v"(r) : "v"(voff), "s"(base));
    return r;
}

// ---------------- fused prep: 3 weight swizzles (32x32x16 A-frag order) + zero x ----------------
// Wb[((tile*NS + s)*64 + lane)*8 + j] = bf16(w[co][ci][t])
//   co = tile*32 + (lane&31), t = s/NC, cc = s%NC, ci = cc*16 + (lane>>5)*8 + j
template <int COUT, int CIN, int CP, int K>
static __device__ __forceinline__ void prep_one(int t, const float* __restrict__ w,
                                                ushort_t* __restrict__ Wb) {
    constexpr int NC = CP / 16;
    constexpr int NS = K * NC;
    int j = t & 7;
    int lane = (t >> 3) & 63;
    int s = (t >> 9) % NS;
    int ct = (t >> 9) / NS;
    int co = ct * 32 + (lane & 31);
    int tt = s / NC, cc = s % NC;
    int ci = cc * 16 + ((lane >> 5) & 1) * 8 + j;
    float v = 0.f;
    if (co < COUT && ci < CIN) v = w[((size_t)co * CIN + ci) * K + tt];
    Wb[t] = f2bf(v);
}

#define PREP_T0 (4 * 12 * 512)            // conv0: 4 tiles x NS=12
#define PREP_T1 (PREP_T0 + 4 * 30 * 512)  // conv1: 4 tiles x NS=30
#define PREP_T2 (PREP_T1 + 8 * 56 * 512)  // conv2: 8 tiles x NS=56
#define PREP_T3 (PREP_T2 + 51200)         // zero x

__global__ __launch_bounds__(256) void k_prep_all(
        const float* __restrict__ c0w, const float* __restrict__ c1w,
        const float* __restrict__ c2w, float* __restrict__ x,
        ushort_t* __restrict__ Wb0, ushort_t* __restrict__ Wb1,
        ushort_t* __restrict__ Wb2) {
    int tid = blockIdx.x * 256 + threadIdx.x;
    if (tid < PREP_T0) prep_one<96, 50, 64, 3>(tid, c0w, Wb0);
    else if (tid < PREP_T1) prep_one<128, 96, 96, 5>(tid - PREP_T0, c1w, Wb1);
    else if (tid < PREP_T2) prep_one<200, 128, 128, 7>(tid - PREP_T1, c2w, Wb2);
    else if (tid < PREP_T3) x[tid - PREP_T2] = 0.f;
}

// ---------------- MFMA conv1d body, 32x32x16 ----------------
// R8 WIN: inline-asm A ring (depth D=4, asm volatile -> unflattenable), counted
// s_waitcnt vmcnt(2*(D-1)) per step (never 0 until tail) + sched_barrier(0)
// (rule #18). conv2 84.4 -> 72.4 us, MfmaUtil 29 -> 35.6%. Do not touch.
template <int CP, int K, int COUT, int CO_WAVES, int L_WAVES, bool FMAX, bool EMB>
static __device__ __forceinline__ void conv_body(
        const ushort_t* __restrict__ act, const int* __restrict__ seq,
        const float* __restrict__ emb, const ushort_t* __restrict__ Wb,
        const float* __restrict__ bias, void* __restrict__ outv,
        ushort_t* __restrict__ Xs) {
    constexpr int NC = CP / 16;
    constexpr int NS = K * NC;
    constexpr int P = K / 2;
    constexpr int PITCH = CP + 8;     // ushorts; 16B-aligned rows, non-pow2 bank stride
    constexpr int LTILE = 64 * L_WAVES;
    constexpr int ROWS = LTILE + K - 1;
    constexpr int CPR = CP / 8;
    constexpr int D = 4;              // A-ring depth (asm-pinned)

    int b = blockIdx.z, lb = blockIdx.x;
    int l0 = lb * LTILE;
    int tid = threadIdx.x;

    // ---- stage X tile (halo, zero-padded at edges) ----
    if (EMB) {
        const int* seqb = seq + (size_t)b * LP;
        for (int idx = tid; idx < ROWS * CPR; idx += 256) {
            int r = idx / CPR, c = idx % CPR;
            int l = l0 - P + r;
            uint4 v = {0u, 0u, 0u, 0u};
            if ((unsigned)l < (unsigned)LP) {
                int s = seqb[l];
                const float* e = emb + (size_t)s * 50;
                ushort_t h[8];
#pragma unroll
                for (int j = 0; j < 8; ++j) {
                    int cc = c * 8 + j;
                    h[j] = (cc < 50) ? f2bf(e[cc]) : (ushort_t)0;
                }
                v.x = (unsigned)h[0] | ((unsigned)h[1] << 16);
                v.y = (unsigned)h[2] | ((unsigned)h[3] << 16);
                v.z = (unsigned)h[4] | ((unsigned)h[5] << 16);
                v.w = (unsigned)h[6] | ((unsigned)h[7] << 16);
            }
            *(uint4*)(Xs + r * PITCH + c * 8) = v;
        }
    } else {
        const ushort_t* actb = act + (size_t)b * LP * CP;
        for (int idx = tid; idx < ROWS * CPR; idx += 256) {
            int r = idx / CPR, c = idx % CPR;
            int l = l0 - P + r;
            uint4 v = {0u, 0u, 0u, 0u};
            if ((unsigned)l < (unsigned)LP) v = *(const uint4*)(actb + (size_t)l * CP + c * 8);
            *(uint4*)(Xs + r * PITCH + c * 8) = v;
        }
    }

    int lane = tid & 63, wv = tid >> 6;
    int cw = wv % CO_WAVES, lw = wv / CO_WAVES;
    int ln31 = lane & 31, half = lane >> 5;

    // A byte offsets: fragment (tile, s) at byte (tile*NS + s)*1024 + lane*16
    unsigned abase0 = (unsigned)(cw * 2) * (unsigned)NS * 1024u + (unsigned)lane * 16u;
    unsigned abase1 = abase0 + (unsigned)NS * 1024u;
    // B base (ushort idx): row = lw*64 + lt*32 + ln31 + t, col = cc*16 + half*8
    int bbase = (lw * 64 + ln31) * PITCH + half * 8;

    f32x16 acc[2][2];
#pragma unroll
    for (int ct = 0; ct < 2; ++ct)
#pragma unroll
        for (int lt = 0; lt < 2; ++lt)
#pragma unroll
            for (int r = 0; r < 16; ++r) acc[ct][lt][r] = 0.f;

    __syncthreads();   // drains staging vmem -> vmcnt below counts ONLY ring loads

    // ---- A ring prologue: D slots (2 loads each) in flight, slot-major order ----
    uint32x4 ra0[D], ra1[D];
#pragma unroll
    for (int d = 0; d < D; ++d) {
        ra0[d] = gload16(Wb, abase0 + (unsigned)(d * 1024));
        ra1[d] = gload16(Wb, abase1 + (unsigned)(d * 1024));
    }

    uint4 bC0 = *(const uint4*)(Xs + bbase);
    uint4 bC1 = *(const uint4*)(Xs + bbase + 32 * PITCH);

#pragma unroll
    for (int s = 0; s < NS; ++s) {
        // B next (LDS; lgkmcnt is compiler-scheduled, 1-ahead is enough)
        int sn = (s + 1 < NS) ? s + 1 : NS - 1;   // folds at compile time (full unroll)
        int tn = sn / NC, ccn = sn % NC;
        int off = bbase + tn * PITCH + ccn * 16;
        uint4 bN0 = *(const uint4*)(Xs + off);
        uint4 bN1 = *(const uint4*)(Xs + off + 32 * PITCH);

        // counted wait: slot-s loads landed when <= 2*min(D-1, NS-1-s) remain outstanding
        {
            const int rem = NS - 1 - s;
            const int allow = 2 * ((D - 1) < rem ? (D - 1) : rem);
            asm volatile("s_waitcnt vmcnt(%0)" :: "i"(allow) : "memory");
            __builtin_amdgcn_sched_barrier(0);
        }

        uint32x4 a0 = ra0[s % D];
        uint32x4 a1 = ra1[s % D];

        acc[0][0] = __builtin_amdgcn_mfma_f32_32x32x16_bf16(
            as_bf16x8v(a0), as_bf16x8(bC0), acc[0][0], 0, 0, 0);
        acc[1][0] = __builtin_amdgcn_mfma_f32_32x32x16_bf16(
            as_bf16x8v(a1), as_bf16x8(bC0), acc[1][0], 0, 0, 0);
        acc[0][1] = __builtin_amdgcn_mfma_f32_32x32x16_bf16(
            as_bf16x8v(a0), as_bf16x8(bC1), acc[0][1], 0, 0, 0);
        acc[1][1] = __builtin_amdgcn_mfma_f32_32x32x16_bf16(
            as_bf16x8v(a1), as_bf16x8(bC1), acc[1][1], 0, 0, 0);

        // refill slot s%D with step s+D (WAR on ra[] orders vs MFMAs; HW pattern = AITER)
        if (s + D < NS) {
            ra0[s % D] = gload16(Wb, abase0 + (unsigned)((s + D) * 1024));
            ra1[s % D] = gload16(Wb, abase1 + (unsigned)((s + D) * 1024));
        }

        bC0 = bN0; bC1 = bN1;
    }

    // C/D layout: col(l) = lane&31, row(co within tile) = (r&3) + 8*(r>>2) + 4*half
    if (!FMAX) {
        ushort_t* out = (ushort_t*)outv + (size_t)b * LP * COUT;
#pragma unroll
        for (int ct = 0; ct < 2; ++ct) {
            int cbase = (cw * 2 + ct) * 32 + 4 * half;
#pragma unroll
            for (int g = 0; g < 4; ++g) {
                int co = cbase + 8 * g;
                if (co >= COUT) continue;
                float4 bv = *(const float4*)(bias + co);
#pragma unroll
                for (int lt = 0; lt < 2; ++lt) {
                    int l = l0 + lw * 64 + lt * 32 + ln31;
                    if (l < LP) {
                        ushort_t h0 = f2bf(fmaxf(acc[ct][lt][4 * g + 0] + bv.x, 0.f));
                        ushort_t h1 = f2bf(fmaxf(acc[ct][lt][4 * g + 1] + bv.y, 0.f));
                        ushort_t h2 = f2bf(fmaxf(acc[ct][lt][4 * g + 2] + bv.z, 0.f));
                        ushort_t h3 = f2bf(fmaxf(acc[ct][lt][4 * g + 3] + bv.w, 0.f));
                        uint2 o;
                        o.x = (unsigned)h0 | ((unsigned)h1 << 16);
                        o.y = (unsigned)h2 | ((unsigned)h3 << 16);
                        *(uint2*)(out + (size_t)l * COUT + co) = o;
                    }
                }
            }
        }
    } else {
        float* xout = (float*)outv;
#pragma unroll
        for (int ct = 0; ct < 2; ++ct) {
            float mx[16];
#pragma unroll
            for (int r = 0; r < 16; ++r) mx[r] = -3.0e38f;
#pragma unroll
            for (int lt = 0; lt < 2; ++lt) {
                int l = l0 + lw * 64 + lt * 32 + ln31;
                if (l < LP) {
#pragma unroll
                    for (int r = 0; r < 16; ++r) mx[r] = fmaxf(mx[r], acc[ct][lt][r]);
                }
            }
#pragma unroll
            for (int r = 0; r < 16; ++r) {
#pragma unroll
                for (int off = 1; off < 32; off <<= 1)
                    mx[r] = fmaxf(mx[r], __shfl_xor(mx[r], off, 64));
            }
            if (ln31 == 0) {
                int cbase = (cw * 2 + ct) * 32 + 4 * half;
#pragma unroll
                for (int r = 0; r < 16; ++r) {
                    int co = cbase + (r & 3) + 8 * (r >> 2);
                    if (co < COUT) {
                        float v = fmaxf(mx[r] + bias[co], 0.f);
                        atomicMax((int*)&xout[(size_t)b * 400 + 200 + co], __float_as_int(v));
                    }
                }
            }
        }
    }
}

// Distinct names so rocprof disambiguates the tower.
__global__ __launch_bounds__(256, 3) void k_conv0(
        const int* __restrict__ seq, const float* __restrict__ emb,
        const ushort_t* __restrict__ Wb, const float* __restrict__ bias,
        ushort_t* __restrict__ out) {
    __shared__ __align__(16) ushort_t Xs[(128 + 2) * (64 + 8)];
    conv_body<64, 3, 96, 2, 2, false, true>(nullptr, seq, emb, Wb, bias, out, Xs);
}
__global__ __launch_bounds__(256, 3) void k_conv1(
        const ushort_t* __restrict__ act, const ushort_t* __restrict__ Wb,
        const float* __restrict__ bias, ushort_t* __restrict__ out) {
    __shared__ __align__(16) ushort_t Xs[(128 + 4) * (96 + 8)];
    conv_body<96, 5, 128, 2, 2, false, false>(act, nullptr, nullptr, Wb, bias, out, Xs);
}
__global__ __launch_bounds__(256, 3) void k_conv2(
        const ushort_t* __restrict__ act, const ushort_t* __restrict__ Wb,
        const float* __restrict__ bias, float* __restrict__ x) {
    __shared__ __align__(16) ushort_t Xs[(64 + 6) * (128 + 8)];
    conv_body<128, 7, 200, 4, 1, true, false>(act, nullptr, nullptr, Wb, bias, x, Xs);
}

// ---------------- binput = fbonds @ W_i ; msg = relu(binput) ----------------
// R9: BIPB 4->16 — 16 FMAs per Wi load (was 4), grid 3072->768, Wi re-reads /4.
__global__ __launch_bounds__(256) void k_bond_input(
        const float* __restrict__ fbonds, const float* __restrict__ Wi,
        float* __restrict__ binput, float* __restrict__ msg) {
    int bond0 = blockIdx.x * BIPB;
    __shared__ float fb[BIPB][BFD];
    int tid = threadIdx.x;
    for (int idx = tid; idx < BIPB * BFD; idx += 256)
        fb[idx / BFD][idx % BFD] = fbonds[(size_t)bond0 * BFD + idx];
    __syncthreads();
    if (tid < H) {
        float acc[BIPB];
#pragma unroll
        for (int q = 0; q < BIPB; ++q) acc[q] = 0.f;
#pragma unroll 5
        for (int k = 0; k < BFD; ++k) {
            float w = Wi[k * H + tid];
#pragma unroll
            for (int q = 0; q < BIPB; ++q) acc[q] += fb[q][k] * w;
        }
#pragma unroll
        for (int q = 0; q < BIPB; ++q) {
            size_t o = (size_t)(bond0 + q) * H + tid;
            binput[o] = acc[q];
            msg[o] = fmaxf(acc[q], 0.f);
        }
    }
}

// ---------------- message update: msgOut = relu(binput + (sum nei) @ W_h) ----------------
// R9: BPB 4->16 — k_msg was latency-bound with 3072 blocks each re-reading 160KB Wh
// (492 MB L2 traffic); now 768 blocks, 16 FMAs of slack per Wh load.
__global__ __launch_bounds__(256) void k_msg(
        const float* __restrict__ msgIn, const float* __restrict__ binput,
        const int* __restrict__ bgraph, const float* __restrict__ Wh,
        float* __restrict__ msgOut) {
    const int grpPerMol = NBB / BPB;
    int b = blockIdx.x / grpPerMol;
    int grp = blockIdx.x % grpPerMol;
    int bond0 = grp * BPB;
    __shared__ int idxs[BPB * 6];
    __shared__ float nei[BPB][H];
    int tid = threadIdx.x;
    if (tid < BPB * 6) idxs[tid] = bgraph[((size_t)(b * NBB + bond0)) * 6 + tid];
    __syncthreads();
    if (tid < H) {
        const float* base = msgIn + (size_t)b * NBB * H;
#pragma unroll
        for (int q = 0; q < BPB; ++q) {
            float s = 0.f;
#pragma unroll
            for (int j = 0; j < 6; ++j) s += base[(size_t)idxs[q * 6 + j] * H + tid];
            nei[q][tid] = s;
        }
    }
    __syncthreads();
    if (tid < H) {
        float acc[BPB];
#pragma unroll
        for (int q = 0; q < BPB; ++q)
            acc[q] = binput[((size_t)(b * NBB + bond0 + q)) * H + tid];
#pragma unroll 4
        for (int hi = 0; hi < H; ++hi) {
            float w = Wh[hi * H + tid];
#pragma unroll
            for (int q = 0; q < BPB; ++q) acc[q] += nei[q][hi] * w;
        }
#pragma unroll
        for (int q = 0; q < BPB; ++q)
            msgOut[((size_t)(b * NBB + bond0 + q)) * H + tid] = fmaxf(acc[q], 0.f);
    }
}

// ---------------- atom head: relu(cat(fa, nei) @ W_o + b), mean -> x[:, :200] ----------------
// R9: APB 2->8 — k_atom was 72.8us co-leader: 3072 blocks x 191KB Wo = 587MB L2 traffic,
// MfmaUtil 0 / VALUBusy 21 / HBM 3% = latency-bound. Now 768 blocks, 8 FMAs/load.
__global__ __launch_bounds__(256) void k_atom(
        const float* __restrict__ msg, const float* __restrict__ fatoms,
        const int* __restrict__ agraph, const float* __restrict__ Wo,
        const float* __restrict__ Wob, float* __restrict__ x) {
    const int grpPerMol = NA / APB;
    int b = blockIdx.x / grpPerMol;
    int grp = blockIdx.x % grpPerMol;
    int atom0 = grp * APB;
    __shared__ int idxs[APB * 6];
    __shared__ float cat[APB][CATD];
    int tid = threadIdx.x;
    if (tid < APB * 6) idxs[tid] = agraph[((size_t)(b * NA + atom0)) * 6 + tid];
    for (int idx = tid; idx < APB * AFD; idx += 256) {
        int q = idx / AFD, c = idx % AFD;
        cat[q][c] = fatoms[((size_t)(b * NA + atom0 + q)) * AFD + c];
    }
    __syncthreads();
    if (tid < H) {
        const float* base = msg + (size_t)b * NBB * H;
#pragma unroll
        for (int q = 0; q < APB; ++q) {
            float s = 0.f;
#pragma unroll
            for (int j = 0; j < 6; ++j) s += base[(size_t)idxs[q * 6 + j] * H + tid];
            cat[q][AFD + tid] = s;
        }
    }
    __syncthreads();
    if (tid < H) {
        float bb = Wob[tid];
        float acc[APB];
#pragma unroll
        for (int q = 0; q < APB; ++q) acc[q] = bb;
#pragma unroll 4
        for (int k = 0; k < CATD; ++k) {
            float w = Wo[k * H + tid];
#pragma unroll
            for (int q = 0; q < APB; ++q) acc[q] += cat[q][k] * w;
        }
        float s = 0.f;
#pragma unroll
        for (int q = 0; q < APB; ++q) s += fmaxf(acc[q], 0.f);
        atomicAdd(&x[(size_t)b * 400 + tid], s * (1.f / NA));
    }
}

// ---------------- fused FC head: 400 -> 200 -> 100 -> 1 ----------------
__global__ __launch_bounds__(256) void k_fc(
        const float* __restrict__ x,
        const float* __restrict__ w0, const float* __restrict__ b0,
        const float* __restrict__ w1, const float* __restrict__ b1,
        const float* __restrict__ w2, const float* __restrict__ b2,
        float* __restrict__ out) {
    int b = blockIdx.x, tid = threadIdx.x;
    __shared__ float xr[400];
    __shared__ float h1[200];
    __shared__ float h2[100];
    for (int i = tid; i < 400; i += 256) xr[i] = x[(size_t)b * 400 + i];
    __syncthreads();
    if (tid < 200) {
        float a = b0[tid];
#pragma unroll 4
        for (int k = 0; k < 400; ++k) a += xr[k] * w0[k * 200 + tid];
        h1[tid] = fmaxf(a, 0.f);
    }
    __syncthreads();
    if (tid < 100) {
        float a = b1[tid];
#pragma unroll 4
        for (int k = 0; k < 200; ++k) a += h1[k] * w1[k * 100 + tid];
        h2[tid] = fmaxf(a, 0.f);
    }
    __syncthreads();
    if (tid == 0) {
        float a = b2[0];
#pragma unroll 4
        for (int k = 0; k < 100; ++k) a += h2[k] * w2[k];
        out[b] = a;
    }
}

extern "C" void kernel_launch(void* const* d_in, const int* in_sizes, int n_in,
                              void* d_out, int out_size, void* d_ws, size_t ws_size,
                              hipStream_t stream) {
    const float* fatoms = (const float*)d_in[0];
    const float* fbonds = (const float*)d_in[1];
    const int* agraph = (const int*)d_in[2];
    const int* bgraph = (const int*)d_in[3];
    const int* seq = (const int*)d_in[4];
    const float* Wi = (const float*)d_in[5];
    const float* Wh = (const float*)d_in[6];
    const float* Wo = (const float*)d_in[7];
    const float* Wob = (const float*)d_in[8];
    const float* embp = (const float*)d_in[9];
    const float* c0w = (const float*)d_in[10];
    const float* c0b = (const float*)d_in[11];
    const float* c1w = (const float*)d_in[12];
    const float* c1b = (const float*)d_in[13];
    const float* c2w = (const float*)d_in[14];
    const float* c2b = (const float*)d_in[15];
    const float* fc0w = (const float*)d_in[16];
    const float* fc0b = (const float*)d_in[17];
    const float* fc1w = (const float*)d_in[18];
    const float* fc1b = (const float*)d_in[19];
    const float* fc2w = (const float*)d_in[20];
    const float* fc2b = (const float*)d_in[21];

    float* ws = (float*)d_ws;
    float* binput = ws;                    // 2457600
    float* msgA = binput + 2457600;        // 2457600
    float* msgB = msgA + 2457600;          // 2457600
    float* x = msgB + 2457600;             // 51200
    ushort_t* u = (ushort_t*)(x + 51200);  // bf16 region
    ushort_t* act1 = u;                    // 128000*96  = 12288000
    ushort_t* act2 = act1 + 12288000;      // 128000*128 = 16384000
    ushort_t* Wb0 = act2 + 16384000;       // 4*12*512  = 24576
    ushort_t* Wb1 = Wb0 + 24576;           // 4*30*512  = 61440
    ushort_t* Wb2 = Wb1 + 61440;           // 8*56*512  = 229376

    // fused: weight swizzles + zero x (k_atom atomicAdd / conv2 atomicMax need zeros)
    k_prep_all<<<(PREP_T3 + 255) / 256, 256, 0, stream>>>(c0w, c1w, c2w, x, Wb0, Wb1, Wb2);

    // ---- MPNN ----
    k_bond_input<<<BATCH * NBB / BIPB, 256, 0, stream>>>(fbonds, Wi, binput, msgA);
    k_msg<<<BATCH * NBB / BPB, 256, 0, stream>>>(msgA, binput, bgraph, Wh, msgB);
    k_msg<<<BATCH * NBB / BPB, 256, 0, stream>>>(msgB, binput, bgraph, Wh, msgA);
    k_atom<<<BATCH * NA / APB, 256, 0, stream>>>(msgA, fatoms, agraph, Wo, Wob, x);

    // ---- protein tower (bf16 MFMA, 32x32x16; conv0 fuses embedding) ----
    k_conv0<<<dim3(8, 1, BATCH), 256, 0, stream>>>(seq, embp, Wb0, c0b, act1);
    k_conv1<<<dim3(8, 1, BATCH), 256, 0, stream>>>(act1, Wb1, c1b, act2);
    k_conv2<<<dim3(16, 1, BATCH), 256, 0, stream>>>(act2, Wb2, c2b, x);

    // ---- fused FC head ----
    k_fc<<<BATCH, 256, 0, stream>>>(x, fc0w, fc0b, fc1w, fc1b, fc2w, fc2b, (float*)d_out);
}

// Round 7
// 345.184 us; speedup vs baseline: 1.2909x; 1.1369x over previous
//
#include <hip/hip_runtime.h>
#include <hip/hip_bf16.h>
#include <cstddef>

#define H 200
#define NA 48
#define NBB 96
#define BATCH 128
#define AFD 39
#define BFD 50          // 39+11
#define LP 1000
#define CATD (AFD + H)  // 239
#define APB 8           // atoms per block in atom kernel
#define BIPB 16         // bonds per block in bond-input kernel

typedef unsigned short ushort_t;
typedef __bf16 bf16x8 __attribute__((ext_vector_type(8)));
typedef float f32x16 __attribute__((ext_vector_type(16)));
typedef unsigned uint32x4 __attribute__((ext_vector_type(4)));

union U16B { uint4 u; bf16x8 b; };
static __device__ __forceinline__ bf16x8 as_bf16x8(uint4 u) { U16B x; x.u = u; return x.b; }
union U16B2 { uint32x4 u; bf16x8 b; };
static __device__ __forceinline__ bf16x8 as_bf16x8v(uint32x4 u) { U16B2 x; x.u = u; return x.b; }

// float -> bf16 (RNE)
static __device__ __forceinline__ ushort_t f2bf(float f) {
    union { float f; unsigned u; } a; a.f = f;
    unsigned r = (a.u + 0x7FFFu + ((a.u >> 16) & 1u)) >> 16;
    return (ushort_t)r;
}

// raw asm global load: 16B at sgpr-base + 32-bit voffset. asm volatile pins issue
// order -> counted vmcnt discipline stays valid. "=&v" early-clobber.
static __device__ __forceinline__ uint32x4 gload16(const ushort_t* base, unsigned voff) {
    uint32x4 r;
    asm volatile("global_load_dwordx4 %0, %1, %2"
                 : "=&v"(r) : "v"(voff), "s"(base));
    return r;
}

// ---------------- fused prep: weight swizzles (32x32x16 A-frag order) + zero x ----------------
template <int COUT, int CIN, int CP, int K>
static __device__ __forceinline__ void prep_one(int t, const float* __restrict__ w,
                                                ushort_t* __restrict__ Wb) {
    constexpr int NC = CP / 16;
    constexpr int NS = K * NC;
    int j = t & 7;
    int lane = (t >> 3) & 63;
    int s = (t >> 9) % NS;
    int ct = (t >> 9) / NS;
    int co = ct * 32 + (lane & 31);
    int tt = s / NC, cc = s % NC;
    int ci = cc * 16 + ((lane >> 5) & 1) * 8 + j;
    float v = 0.f;
    if (co < COUT && ci < CIN) v = w[((size_t)co * CIN + ci) * K + tt];
    Wb[t] = f2bf(v);
}

#define MNS 13                            // K-steps for msg GEMM (208/16)
#define PREP_T0 (4 * 12 * 512)            // conv0: 4 tiles x NS=12
#define PREP_T1 (PREP_T0 + 4 * 30 * 512)  // conv1: 4 tiles x NS=30
#define PREP_T2 (PREP_T1 + 8 * 56 * 512)  // conv2: 8 tiles x NS=56
#define PREP_T3 (PREP_T2 + 51200)         // zero x
#define PREP_T4 (PREP_T3 + 8 * MNS * 512) // Wh swizzle: 8 tiles x 13 steps

__global__ __launch_bounds__(256) void k_prep_all(
        const float* __restrict__ c0w, const float* __restrict__ c1w,
        const float* __restrict__ c2w, const float* __restrict__ Wh,
        float* __restrict__ x,
        ushort_t* __restrict__ Wb0, ushort_t* __restrict__ Wb1,
        ushort_t* __restrict__ Wb2, ushort_t* __restrict__ Wbh) {
    int tid = blockIdx.x * 256 + threadIdx.x;
    if (tid < PREP_T0) prep_one<96, 50, 64, 3>(tid, c0w, Wb0);
    else if (tid < PREP_T1) prep_one<128, 96, 96, 5>(tid - PREP_T0, c1w, Wb1);
    else if (tid < PREP_T2) prep_one<200, 128, 128, 7>(tid - PREP_T1, c2w, Wb2);
    else if (tid < PREP_T3) x[tid - PREP_T2] = 0.f;
    else if (tid < PREP_T4) {
        // Wh stored (in,out): value for (co, ci) = Wh[ci*200 + co]
        int t = tid - PREP_T3;
        int j = t & 7;
        int lane = (t >> 3) & 63;
        int s = (t >> 9) % MNS;
        int tile = (t >> 9) / MNS;
        int co = tile * 32 + (lane & 31);
        int ci = s * 16 + ((lane >> 5) & 1) * 8 + j;
        float v = 0.f;
        if (co < H && ci < H) v = Wh[ci * H + co];
        Wbh[t] = f2bf(v);
    }
}

// ---------------- MFMA conv1d body, 32x32x16 ----------------
// R8 WIN: inline-asm A ring (depth D=4), counted s_waitcnt vmcnt + sched_barrier(0).
// conv2 84.4 -> 72.4 us, MfmaUtil 29 -> 35.6%. Do not touch.
template <int CP, int K, int COUT, int CO_WAVES, int L_WAVES, bool FMAX, bool EMB>
static __device__ __forceinline__ void conv_body(
        const ushort_t* __restrict__ act, const int* __restrict__ seq,
        const float* __restrict__ emb, const ushort_t* __restrict__ Wb,
        const float* __restrict__ bias, void* __restrict__ outv,
        ushort_t* __restrict__ Xs) {
    constexpr int NC = CP / 16;
    constexpr int NS = K * NC;
    constexpr int P = K / 2;
    constexpr int PITCH = CP + 8;
    constexpr int LTILE = 64 * L_WAVES;
    constexpr int ROWS = LTILE + K - 1;
    constexpr int CPR = CP / 8;
    constexpr int D = 4;

    int b = blockIdx.z, lb = blockIdx.x;
    int l0 = lb * LTILE;
    int tid = threadIdx.x;

    if (EMB) {
        const int* seqb = seq + (size_t)b * LP;
        for (int idx = tid; idx < ROWS * CPR; idx += 256) {
            int r = idx / CPR, c = idx % CPR;
            int l = l0 - P + r;
            uint4 v = {0u, 0u, 0u, 0u};
            if ((unsigned)l < (unsigned)LP) {
                int s = seqb[l];
                const float* e = emb + (size_t)s * 50;
                ushort_t h[8];
#pragma unroll
                for (int j = 0; j < 8; ++j) {
                    int cc = c * 8 + j;
                    h[j] = (cc < 50) ? f2bf(e[cc]) : (ushort_t)0;
                }
                v.x = (unsigned)h[0] | ((unsigned)h[1] << 16);
                v.y = (unsigned)h[2] | ((unsigned)h[3] << 16);
                v.z = (unsigned)h[4] | ((unsigned)h[5] << 16);
                v.w = (unsigned)h[6] | ((unsigned)h[7] << 16);
            }
            *(uint4*)(Xs + r * PITCH + c * 8) = v;
        }
    } else {
        const ushort_t* actb = act + (size_t)b * LP * CP;
        for (int idx = tid; idx < ROWS * CPR; idx += 256) {
            int r = idx / CPR, c = idx % CPR;
            int l = l0 - P + r;
            uint4 v = {0u, 0u, 0u, 0u};
            if ((unsigned)l < (unsigned)LP) v = *(const uint4*)(actb + (size_t)l * CP + c * 8);
            *(uint4*)(Xs + r * PITCH + c * 8) = v;
        }
    }

    int lane = tid & 63, wv = tid >> 6;
    int cw = wv % CO_WAVES, lw = wv / CO_WAVES;
    int ln31 = lane & 31, half = lane >> 5;

    unsigned abase0 = (unsigned)(cw * 2) * (unsigned)NS * 1024u + (unsigned)lane * 16u;
    unsigned abase1 = abase0 + (unsigned)NS * 1024u;
    int bbase = (lw * 64 + ln31) * PITCH + half * 8;

    f32x16 acc[2][2];
#pragma unroll
    for (int ct = 0; ct < 2; ++ct)
#pragma unroll
        for (int lt = 0; lt < 2; ++lt)
#pragma unroll
            for (int r = 0; r < 16; ++r) acc[ct][lt][r] = 0.f;

    __syncthreads();   // staging drained -> vmcnt counts ONLY ring loads

    uint32x4 ra0[D], ra1[D];
#pragma unroll
    for (int d = 0; d < D; ++d) {
        ra0[d] = gload16(Wb, abase0 + (unsigned)(d * 1024));
        ra1[d] = gload16(Wb, abase1 + (unsigned)(d * 1024));
    }

    uint4 bC0 = *(const uint4*)(Xs + bbase);
    uint4 bC1 = *(const uint4*)(Xs + bbase + 32 * PITCH);

#pragma unroll
    for (int s = 0; s < NS; ++s) {
        int sn = (s + 1 < NS) ? s + 1 : NS - 1;
        int tn = sn / NC, ccn = sn % NC;
        int off = bbase + tn * PITCH + ccn * 16;
        uint4 bN0 = *(const uint4*)(Xs + off);
        uint4 bN1 = *(const uint4*)(Xs + off + 32 * PITCH);

        {
            const int rem = NS - 1 - s;
            const int allow = 2 * ((D - 1) < rem ? (D - 1) : rem);
            asm volatile("s_waitcnt vmcnt(%0)" :: "i"(allow) : "memory");
            __builtin_amdgcn_sched_barrier(0);
        }

        uint32x4 a0 = ra0[s % D];
        uint32x4 a1 = ra1[s % D];

        acc[0][0] = __builtin_amdgcn_mfma_f32_32x32x16_bf16(
            as_bf16x8v(a0), as_bf16x8(bC0), acc[0][0], 0, 0, 0);
        acc[1][0] = __builtin_amdgcn_mfma_f32_32x32x16_bf16(
            as_bf16x8v(a1), as_bf16x8(bC0), acc[1][0], 0, 0, 0);
        acc[0][1] = __builtin_amdgcn_mfma_f32_32x32x16_bf16(
            as_bf16x8v(a0), as_bf16x8(bC1), acc[0][1], 0, 0, 0);
        acc[1][1] = __builtin_amdgcn_mfma_f32_32x32x16_bf16(
            as_bf16x8v(a1), as_bf16x8(bC1), acc[1][1], 0, 0, 0);

        if (s + D < NS) {
            ra0[s % D] = gload16(Wb, abase0 + (unsigned)((s + D) * 1024));
            ra1[s % D] = gload16(Wb, abase1 + (unsigned)((s + D) * 1024));
        }

        bC0 = bN0; bC1 = bN1;
    }

    if (!FMAX) {
        ushort_t* out = (ushort_t*)outv + (size_t)b * LP * COUT;
#pragma unroll
        for (int ct = 0; ct < 2; ++ct) {
            int cbase = (cw * 2 + ct) * 32 + 4 * half;
#pragma unroll
            for (int g = 0; g < 4; ++g) {
                int co = cbase + 8 * g;
                if (co >= COUT) continue;
                float4 bv = *(const float4*)(bias + co);
#pragma unroll
                for (int lt = 0; lt < 2; ++lt) {
                    int l = l0 + lw * 64 + lt * 32 + ln31;
                    if (l < LP) {
                        ushort_t h0 = f2bf(fmaxf(acc[ct][lt][4 * g + 0] + bv.x, 0.f));
                        ushort_t h1 = f2bf(fmaxf(acc[ct][lt][4 * g + 1] + bv.y, 0.f));
                        ushort_t h2 = f2bf(fmaxf(acc[ct][lt][4 * g + 2] + bv.z, 0.f));
                        ushort_t h3 = f2bf(fmaxf(acc[ct][lt][4 * g + 3] + bv.w, 0.f));
                        uint2 o;
                        o.x = (unsigned)h0 | ((unsigned)h1 << 16);
                        o.y = (unsigned)h2 | ((unsigned)h3 << 16);
                        *(uint2*)(out + (size_t)l * COUT + co) = o;
                    }
                }
            }
        }
    } else {
        float* xout = (float*)outv;
#pragma unroll
        for (int ct = 0; ct < 2; ++ct) {
            float mx[16];
#pragma unroll
            for (int r = 0; r < 16; ++r) mx[r] = -3.0e38f;
#pragma unroll
            for (int lt = 0; lt < 2; ++lt) {
                int l = l0 + lw * 64 + lt * 32 + ln31;
                if (l < LP) {
#pragma unroll
                    for (int r = 0; r < 16; ++r) mx[r] = fmaxf(mx[r], acc[ct][lt][r]);
                }
            }
#pragma unroll
            for (int r = 0; r < 16; ++r) {
#pragma unroll
                for (int off = 1; off < 32; off <<= 1)
                    mx[r] = fmaxf(mx[r], __shfl_xor(mx[r], off, 64));
            }
            if (ln31 == 0) {
                int cbase = (cw * 2 + ct) * 32 + 4 * half;
#pragma unroll
                for (int r = 0; r < 16; ++r) {
                    int co = cbase + (r & 3) + 8 * (r >> 2);
                    if (co < COUT) {
                        float v = fmaxf(mx[r] + bias[co], 0.f);
                        atomicMax((int*)&xout[(size_t)b * 400 + 200 + co], __float_as_int(v));
                    }
                }
            }
        }
    }
}

__global__ __launch_bounds__(256, 3) void k_conv0(
        const int* __restrict__ seq, const float* __restrict__ emb,
        const ushort_t* __restrict__ Wb, const float* __restrict__ bias,
        ushort_t* __restrict__ out) {
    __shared__ __align__(16) ushort_t Xs[(128 + 2) * (64 + 8)];
    conv_body<64, 3, 96, 2, 2, false, true>(nullptr, seq, emb, Wb, bias, out, Xs);
}
__global__ __launch_bounds__(256, 3) void k_conv1(
        const ushort_t* __restrict__ act, const ushort_t* __restrict__ Wb,
        const float* __restrict__ bias, ushort_t* __restrict__ out) {
    __shared__ __align__(16) ushort_t Xs[(128 + 4) * (96 + 8)];
    conv_body<96, 5, 128, 2, 2, false, false>(act, nullptr, nullptr, Wb, bias, out, Xs);
}
__global__ __launch_bounds__(256, 3) void k_conv2(
        const ushort_t* __restrict__ act, const ushort_t* __restrict__ Wb,
        const float* __restrict__ bias, float* __restrict__ x) {
    __shared__ __align__(16) ushort_t Xs[(64 + 6) * (128 + 8)];
    conv_body<128, 7, 200, 4, 1, true, false>(act, nullptr, nullptr, Wb, bias, x, Xs);
}

// ---------------- binput = fbonds @ W_i ; msg = relu(binput) ----------------
__global__ __launch_bounds__(256) void k_bond_input(
        const float* __restrict__ fbonds, const float* __restrict__ Wi,
        float* __restrict__ binput, float* __restrict__ msg) {
    int bond0 = blockIdx.x * BIPB;
    __shared__ float fb[BIPB][BFD];
    int tid = threadIdx.x;
    for (int idx = tid; idx < BIPB * BFD; idx += 256)
        fb[idx / BFD][idx % BFD] = fbonds[(size_t)bond0 * BFD + idx];
    __syncthreads();
    if (tid < H) {
        float acc[BIPB];
#pragma unroll
        for (int q = 0; q < BIPB; ++q) acc[q] = 0.f;
#pragma unroll 5
        for (int k = 0; k < BFD; ++k) {
            float w = Wi[k * H + tid];
#pragma unroll
            for (int q = 0; q < BIPB; ++q) acc[q] += fb[q][k] * w;
        }
#pragma unroll
        for (int q = 0; q < BIPB; ++q) {
            size_t o = (size_t)(bond0 + q) * H + tid;
            binput[o] = acc[q];
            msg[o] = fmaxf(acc[q], 0.f);
        }
    }
}

// ---------------- message update via MFMA GEMM ----------------
// R10: msgOut = relu(binput + (sum_nbr msgIn) @ Wh) as batched 12288x200 @ 200x200.
// Old k_msg was DS-pipe-bound (1 ds_read_b32 per FMA, ~18.5Kcy/thread on LDS vs 6.4K VALU).
// Per block: 32 rows. Gather-sum 6 neighbors in fp32, round ONCE to bf16 for the LDS
// B tile (msg buffers stay fp32 -> minimal extra rounding). A = pre-swizzled bf16 Wh
// (8 tiles x MNS=13 steps), streamed via the R8 asm ring. Epilogue relu(binput+acc) fp32.
#define MPITCH 216   // 208 + 8 ushorts
__global__ __launch_bounds__(256) void k_msg_mfma(
        const float* __restrict__ msgIn, const float* __restrict__ binput,
        const int* __restrict__ bgraph, const ushort_t* __restrict__ Wbh,
        float* __restrict__ msgOut) {
    __shared__ __align__(16) ushort_t Xs[32 * MPITCH];
    __shared__ int idxs[32 * 6];
    constexpr int D = 4;
    int m0 = blockIdx.x * 32;
    int tid = threadIdx.x;

    if (tid < 192) {
        int r = tid / 6, j = tid - r * 6;
        int m = m0 + r;
        int mol = m / NBB;
        idxs[tid] = mol * NBB + bgraph[(size_t)m * 6 + j];
    }
    __syncthreads();

    // stage B tile: 32 rows x 26 bf16x8 chunks (chunk 25 = pad, zeroed)
    for (int it = tid; it < 32 * 26; it += 256) {
        int r = it / 26, c = it - r * 26;
        uint4 v = {0u, 0u, 0u, 0u};
        if (c < 25) {
            float sv[8];
#pragma unroll
            for (int k = 0; k < 8; ++k) sv[k] = 0.f;
#pragma unroll
            for (int j = 0; j < 6; ++j) {
                const float* row = msgIn + (size_t)idxs[r * 6 + j] * H + c * 8;
                float4 a = *(const float4*)row;
                float4 b = *(const float4*)(row + 4);
                sv[0] += a.x; sv[1] += a.y; sv[2] += a.z; sv[3] += a.w;
                sv[4] += b.x; sv[5] += b.y; sv[6] += b.z; sv[7] += b.w;
            }
            v.x = (unsigned)f2bf(sv[0]) | ((unsigned)f2bf(sv[1]) << 16);
            v.y = (unsigned)f2bf(sv[2]) | ((unsigned)f2bf(sv[3]) << 16);
            v.z = (unsigned)f2bf(sv[4]) | ((unsigned)f2bf(sv[5]) << 16);
            v.w = (unsigned)f2bf(sv[6]) | ((unsigned)f2bf(sv[7]) << 16);
        }
        *(uint4*)(Xs + r * MPITCH + c * 8) = v;
    }

    int lane = tid & 63, wv = tid >> 6;      // wv = co-wave 0..3 (tiles 2wv, 2wv+1)
    int ln31 = lane & 31, half = lane >> 5;
    unsigned abase0 = (unsigned)(wv * 2) * (unsigned)MNS * 1024u + (unsigned)lane * 16u;
    unsigned abase1 = abase0 + (unsigned)MNS * 1024u;
    int bbase = ln31 * MPITCH + half * 8;

    f32x16 acc[2];
#pragma unroll
    for (int ct = 0; ct < 2; ++ct)
#pragma unroll
        for (int r = 0; r < 16; ++r) acc[ct][r] = 0.f;

    __syncthreads();   // staging drained -> vmcnt counts ONLY ring loads

    uint32x4 ra0[D], ra1[D];
#pragma unroll
    for (int d = 0; d < D; ++d) {
        ra0[d] = gload16(Wbh, abase0 + (unsigned)(d * 1024));
        ra1[d] = gload16(Wbh, abase1 + (unsigned)(d * 1024));
    }

    uint4 bC = *(const uint4*)(Xs + bbase);

#pragma unroll
    for (int s = 0; s < MNS; ++s) {
        int sn = (s + 1 < MNS) ? s + 1 : MNS - 1;
        uint4 bN = *(const uint4*)(Xs + bbase + sn * 16);

        {
            const int rem = MNS - 1 - s;
            const int allow = 2 * ((D - 1) < rem ? (D - 1) : rem);
            asm volatile("s_waitcnt vmcnt(%0)" :: "i"(allow) : "memory");
            __builtin_amdgcn_sched_barrier(0);
        }

        uint32x4 a0 = ra0[s % D];
        uint32x4 a1 = ra1[s % D];
        acc[0] = __builtin_amdgcn_mfma_f32_32x32x16_bf16(
            as_bf16x8v(a0), as_bf16x8(bC), acc[0], 0, 0, 0);
        acc[1] = __builtin_amdgcn_mfma_f32_32x32x16_bf16(
            as_bf16x8v(a1), as_bf16x8(bC), acc[1], 0, 0, 0);

        if (s + D < MNS) {
            ra0[s % D] = gload16(Wbh, abase0 + (unsigned)((s + D) * 1024));
            ra1[s % D] = gload16(Wbh, abase1 + (unsigned)((s + D) * 1024));
        }
        bC = bN;
    }

    // C/D: col(m) = ln31, row(co in tile) = (r&3) + 8*(r>>2) + 4*half
    int m = m0 + ln31;
    const float* bi = binput + (size_t)m * H;
    float* outp = msgOut + (size_t)m * H;
#pragma unroll
    for (int ct = 0; ct < 2; ++ct) {
        int cbase = (wv * 2 + ct) * 32 + 4 * half;
#pragma unroll
        for (int g = 0; g < 4; ++g) {
            int co = cbase + 8 * g;
            if (co >= H) continue;
            float4 b4 = *(const float4*)(bi + co);
            float4 o;
            o.x = fmaxf(acc[ct][4 * g + 0] + b4.x, 0.f);
            o.y = fmaxf(acc[ct][4 * g + 1] + b4.y, 0.f);
            o.z = fmaxf(acc[ct][4 * g + 2] + b4.z, 0.f);
            o.w = fmaxf(acc[ct][4 * g + 3] + b4.w, 0.f);
            *(float4*)(outp + co) = o;
        }
    }
}

// ---------------- atom head: relu(cat(fa, nei) @ W_o + b), mean -> x[:, :200] ----------------
__global__ __launch_bounds__(256) void k_atom(
        const float* __restrict__ msg, const float* __restrict__ fatoms,
        const int* __restrict__ agraph, const float* __restrict__ Wo,
        const float* __restrict__ Wob, float* __restrict__ x) {
    const int grpPerMol = NA / APB;
    int b = blockIdx.x / grpPerMol;
    int grp = blockIdx.x % grpPerMol;
    int atom0 = grp * APB;
    __shared__ int idxs[APB * 6];
    __shared__ float cat[APB][CATD];
    int tid = threadIdx.x;
    if (tid < APB * 6) idxs[tid] = agraph[((size_t)(b * NA + atom0)) * 6 + tid];
    for (int idx = tid; idx < APB * AFD; idx += 256) {
        int q = idx / AFD, c = idx % AFD;
        cat[q][c] = fatoms[((size_t)(b * NA + atom0 + q)) * AFD + c];
    }
    __syncthreads();
    if (tid < H) {
        const float* base = msg + (size_t)b * NBB * H;
#pragma unroll
        for (int q = 0; q < APB; ++q) {
            float s = 0.f;
#pragma unroll
            for (int j = 0; j < 6; ++j) s += base[(size_t)idxs[q * 6 + j] * H + tid];
            cat[q][AFD + tid] = s;
        }
    }
    __syncthreads();
    if (tid < H) {
        float bb = Wob[tid];
        float acc[APB];
#pragma unroll
        for (int q = 0; q < APB; ++q) acc[q] = bb;
#pragma unroll 4
        for (int k = 0; k < CATD; ++k) {
            float w = Wo[k * H + tid];
#pragma unroll
            for (int q = 0; q < APB; ++q) acc[q] += cat[q][k] * w;
        }
        float s = 0.f;
#pragma unroll
        for (int q = 0; q < APB; ++q) s += fmaxf(acc[q], 0.f);
        atomicAdd(&x[(size_t)b * 400 + tid], s * (1.f / NA));
    }
}

// ---------------- fused FC head: 400 -> 200 -> 100 -> 1 ----------------
__global__ __launch_bounds__(256) void k_fc(
        const float* __restrict__ x,
        const float* __restrict__ w0, const float* __restrict__ b0,
        const float* __restrict__ w1, const float* __restrict__ b1,
        const float* __restrict__ w2, const float* __restrict__ b2,
        float* __restrict__ out) {
    int b = blockIdx.x, tid = threadIdx.x;
    __shared__ float xr[400];
    __shared__ float h1[200];
    __shared__ float h2[100];
    for (int i = tid; i < 400; i += 256) xr[i] = x[(size_t)b * 400 + i];
    __syncthreads();
    if (tid < 200) {
        float a = b0[tid];
#pragma unroll 4
        for (int k = 0; k < 400; ++k) a += xr[k] * w0[k * 200 + tid];
        h1[tid] = fmaxf(a, 0.f);
    }
    __syncthreads();
    if (tid < 100) {
        float a = b1[tid];
#pragma unroll 4
        for (int k = 0; k < 200; ++k) a += h1[k] * w1[k * 100 + tid];
        h2[tid] = fmaxf(a, 0.f);
    }
    __syncthreads();
    if (tid == 0) {
        float a = b2[0];
#pragma unroll 4
        for (int k = 0; k < 100; ++k) a += h2[k] * w2[k];
        out[b] = a;
    }
}

extern "C" void kernel_launch(void* const* d_in, const int* in_sizes, int n_in,
                              void* d_out, int out_size, void* d_ws, size_t ws_size,
                              hipStream_t stream) {
    const float* fatoms = (const float*)d_in[0];
    const float* fbonds = (const float*)d_in[1];
    const int* agraph = (const int*)d_in[2];
    const int* bgraph = (const int*)d_in[3];
    const int* seq = (const int*)d_in[4];
    const float* Wi = (const float*)d_in[5];
    const float* Wh = (const float*)d_in[6];
    const float* Wo = (const float*)d_in[7];
    const float* Wob = (const float*)d_in[8];
    const float* embp = (const float*)d_in[9];
    const float* c0w = (const float*)d_in[10];
    const float* c0b = (const float*)d_in[11];
    const float* c1w = (const float*)d_in[12];
    const float* c1b = (const float*)d_in[13];
    const float* c2w = (const float*)d_in[14];
    const float* c2b = (const float*)d_in[15];
    const float* fc0w = (const float*)d_in[16];
    const float* fc0b = (const float*)d_in[17];
    const float* fc1w = (const float*)d_in[18];
    const float* fc1b = (const float*)d_in[19];
    const float* fc2w = (const float*)d_in[20];
    const float* fc2b = (const float*)d_in[21];

    float* ws = (float*)d_ws;
    float* binput = ws;                    // 2457600
    float* msgA = binput + 2457600;        // 2457600
    float* msgB = msgA + 2457600;          // 2457600
    float* x = msgB + 2457600;             // 51200
    ushort_t* u = (ushort_t*)(x + 51200);  // bf16 region
    ushort_t* act1 = u;                    // 128000*96  = 12288000
    ushort_t* act2 = act1 + 12288000;      // 128000*128 = 16384000
    ushort_t* Wb0 = act2 + 16384000;       // 4*12*512  = 24576
    ushort_t* Wb1 = Wb0 + 24576;           // 4*30*512  = 61440
    ushort_t* Wb2 = Wb1 + 61440;           // 8*56*512  = 229376
    ushort_t* Wbh = Wb2 + 229376;          // 8*13*512  = 53248

    // fused: weight swizzles (+Wh) + zero x
    k_prep_all<<<(PREP_T4 + 255) / 256, 256, 0, stream>>>(c0w, c1w, c2w, Wh, x,
                                                          Wb0, Wb1, Wb2, Wbh);

    // ---- MPNN ----
    k_bond_input<<<BATCH * NBB / BIPB, 256, 0, stream>>>(fbonds, Wi, binput, msgA);
    k_msg_mfma<<<BATCH * NBB / 32, 256, 0, stream>>>(msgA, binput, bgraph, Wbh, msgB);
    k_msg_mfma<<<BATCH * NBB / 32, 256, 0, stream>>>(msgB, binput, bgraph, Wbh, msgA);
    k_atom<<<BATCH * NA / APB, 256, 0, stream>>>(msgA, fatoms, agraph, Wo, Wob, x);

    // ---- protein tower (bf16 MFMA, 32x32x16; conv0 fuses embedding) ----
    k_conv0<<<dim3(8, 1, BATCH), 256, 0, stream>>>(seq, embp, Wb0, c0b, act1);
    k_conv1<<<dim3(8, 1, BATCH), 256, 0, stream>>>(act1, Wb1, c1b, act2);
    k_conv2<<<dim3(16, 1, BATCH), 256, 0, stream>>>(act2, Wb2, c2b, x);

    // ---- fused FC head ----
    k_fc<<<BATCH, 256, 0, stream>>>(x, fc0w, fc0b, fc1w, fc1b, fc2w, fc2b, (float*)d_out);
}

// Round 8
// 330.966 us; speedup vs baseline: 1.3463x; 1.0430x over previous
//
#include <hip/hip_runtime.h>
#include <hip/hip_bf16.h>
#include <cstddef>

#define H 200
#define NA 48
#define NBB 96
#define BATCH 128
#define AFD 39
#define BFD 50          // 39+11
#define LP 1000
#define CATD (AFD + H)  // 239
#define APB 8           // atoms per block in atom kernel
#define BIPB 16         // bonds per block in bond-input kernel

typedef unsigned short ushort_t;
typedef __bf16 bf16x8 __attribute__((ext_vector_type(8)));
typedef float f32x16 __attribute__((ext_vector_type(16)));
typedef unsigned uint32x4 __attribute__((ext_vector_type(4)));

union U16B { uint4 u; bf16x8 b; };
static __device__ __forceinline__ bf16x8 as_bf16x8(uint4 u) { U16B x; x.u = u; return x.b; }
union U16B2 { uint32x4 u; bf16x8 b; };
static __device__ __forceinline__ bf16x8 as_bf16x8v(uint32x4 u) { U16B2 x; x.u = u; return x.b; }

// float -> bf16 (RNE)
static __device__ __forceinline__ ushort_t f2bf(float f) {
    union { float f; unsigned u; } a; a.f = f;
    unsigned r = (a.u + 0x7FFFu + ((a.u >> 16) & 1u)) >> 16;
    return (ushort_t)r;
}

// raw asm global load: 16B at sgpr-base + 32-bit voffset. asm volatile pins issue
// order -> counted vmcnt discipline stays valid. "=&v" early-clobber.
static __device__ __forceinline__ uint32x4 gload16(const ushort_t* base, unsigned voff) {
    uint32x4 r;
    asm volatile("global_load_dwordx4 %0, %1, %2"
                 : "=&v"(r) : "v"(voff), "s"(base));
    return r;
}

// ---------------- prep: weight swizzles (32x32x16 A-frag order) ----------------
template <int COUT, int CIN, int CP, int K>
static __device__ __forceinline__ void prep_one(int t, const float* __restrict__ w,
                                                ushort_t* __restrict__ Wb) {
    constexpr int NC = CP / 16;
    constexpr int NS = K * NC;
    int j = t & 7;
    int lane = (t >> 3) & 63;
    int s = (t >> 9) % NS;
    int ct = (t >> 9) / NS;
    int co = ct * 32 + (lane & 31);
    int tt = s / NC, cc = s % NC;
    int ci = cc * 16 + ((lane >> 5) & 1) * 8 + j;
    float v = 0.f;
    if (co < COUT && ci < CIN) v = w[((size_t)co * CIN + ci) * K + tt];
    Wb[t] = f2bf(v);
}

#define MNS 13                            // K-steps for msg GEMM (208/16)
#define PREP_T0 (4 * 12 * 512)            // conv0: 4 tiles x NS=12
#define PREP_T1 (PREP_T0 + 4 * 30 * 512)  // conv1: 4 tiles x NS=30
#define PREP_T2 (PREP_T1 + 8 * 56 * 512)  // conv2: 8 tiles x NS=56
#define PREP_T3 (PREP_T2 + 51200)         // zero x
#define PREP_T4 (PREP_T3 + 8 * MNS * 512) // Wh swizzle: 8 tiles x 13 steps
#define PREP_BLKS (PREP_T4 / 256)         // 419840/256 = 1640 exactly

static __device__ __forceinline__ void prep_body(
        int tid, const float* __restrict__ c0w, const float* __restrict__ c1w,
        const float* __restrict__ c2w, const float* __restrict__ Wh,
        float* __restrict__ x, ushort_t* __restrict__ Wb0,
        ushort_t* __restrict__ Wb1, ushort_t* __restrict__ Wb2,
        ushort_t* __restrict__ Wbh) {
    if (tid < PREP_T0) prep_one<96, 50, 64, 3>(tid, c0w, Wb0);
    else if (tid < PREP_T1) prep_one<128, 96, 96, 5>(tid - PREP_T0, c1w, Wb1);
    else if (tid < PREP_T2) prep_one<200, 128, 128, 7>(tid - PREP_T1, c2w, Wb2);
    else if (tid < PREP_T3) x[tid - PREP_T2] = 0.f;
    else if (tid < PREP_T4) {
        // Wh stored (in,out): value for (co, ci) = Wh[ci*200 + co]
        int t = tid - PREP_T3;
        int j = t & 7;
        int lane = (t >> 3) & 63;
        int s = (t >> 9) % MNS;
        int tile = (t >> 9) / MNS;
        int co = tile * 32 + (lane & 31);
        int ci = s * 16 + ((lane >> 5) & 1) * 8 + j;
        float v = 0.f;
        if (co < H && ci < H) v = Wh[ci * H + co];
        Wbh[t] = f2bf(v);
    }
}

// ---------------- MFMA conv1d body, 32x32x16 ----------------
// R8 WIN: inline-asm A ring (depth D=4), counted s_waitcnt vmcnt + sched_barrier(0).
// conv2 84.4 -> 72.4 us, MfmaUtil 29 -> 35.6%. Do not touch.
template <int CP, int K, int COUT, int CO_WAVES, int L_WAVES, bool FMAX, bool EMB>
static __device__ __forceinline__ void conv_body(
        const ushort_t* __restrict__ act, const int* __restrict__ seq,
        const float* __restrict__ emb, const ushort_t* __restrict__ Wb,
        const float* __restrict__ bias, void* __restrict__ outv,
        ushort_t* __restrict__ Xs) {
    constexpr int NC = CP / 16;
    constexpr int NS = K * NC;
    constexpr int P = K / 2;
    constexpr int PITCH = CP + 8;
    constexpr int LTILE = 64 * L_WAVES;
    constexpr int ROWS = LTILE + K - 1;
    constexpr int CPR = CP / 8;
    constexpr int D = 4;

    int b = blockIdx.z, lb = blockIdx.x;
    int l0 = lb * LTILE;
    int tid = threadIdx.x;

    if (EMB) {
        const int* seqb = seq + (size_t)b * LP;
        for (int idx = tid; idx < ROWS * CPR; idx += 256) {
            int r = idx / CPR, c = idx % CPR;
            int l = l0 - P + r;
            uint4 v = {0u, 0u, 0u, 0u};
            if ((unsigned)l < (unsigned)LP) {
                int s = seqb[l];
                const float* e = emb + (size_t)s * 50;
                ushort_t h[8];
#pragma unroll
                for (int j = 0; j < 8; ++j) {
                    int cc = c * 8 + j;
                    h[j] = (cc < 50) ? f2bf(e[cc]) : (ushort_t)0;
                }
                v.x = (unsigned)h[0] | ((unsigned)h[1] << 16);
                v.y = (unsigned)h[2] | ((unsigned)h[3] << 16);
                v.z = (unsigned)h[4] | ((unsigned)h[5] << 16);
                v.w = (unsigned)h[6] | ((unsigned)h[7] << 16);
            }
            *(uint4*)(Xs + r * PITCH + c * 8) = v;
        }
    } else {
        const ushort_t* actb = act + (size_t)b * LP * CP;
        for (int idx = tid; idx < ROWS * CPR; idx += 256) {
            int r = idx / CPR, c = idx % CPR;
            int l = l0 - P + r;
            uint4 v = {0u, 0u, 0u, 0u};
            if ((unsigned)l < (unsigned)LP) v = *(const uint4*)(actb + (size_t)l * CP + c * 8);
            *(uint4*)(Xs + r * PITCH + c * 8) = v;
        }
    }

    int lane = tid & 63, wv = tid >> 6;
    int cw = wv % CO_WAVES, lw = wv / CO_WAVES;
    int ln31 = lane & 31, half = lane >> 5;

    unsigned abase0 = (unsigned)(cw * 2) * (unsigned)NS * 1024u + (unsigned)lane * 16u;
    unsigned abase1 = abase0 + (unsigned)NS * 1024u;
    int bbase = (lw * 64 + ln31) * PITCH + half * 8;

    f32x16 acc[2][2];
#pragma unroll
    for (int ct = 0; ct < 2; ++ct)
#pragma unroll
        for (int lt = 0; lt < 2; ++lt)
#pragma unroll
            for (int r = 0; r < 16; ++r) acc[ct][lt][r] = 0.f;

    __syncthreads();   // staging drained -> vmcnt counts ONLY ring loads

    uint32x4 ra0[D], ra1[D];
#pragma unroll
    for (int d = 0; d < D; ++d) {
        ra0[d] = gload16(Wb, abase0 + (unsigned)(d * 1024));
        ra1[d] = gload16(Wb, abase1 + (unsigned)(d * 1024));
    }

    uint4 bC0 = *(const uint4*)(Xs + bbase);
    uint4 bC1 = *(const uint4*)(Xs + bbase + 32 * PITCH);

#pragma unroll
    for (int s = 0; s < NS; ++s) {
        int sn = (s + 1 < NS) ? s + 1 : NS - 1;
        int tn = sn / NC, ccn = sn % NC;
        int off = bbase + tn * PITCH + ccn * 16;
        uint4 bN0 = *(const uint4*)(Xs + off);
        uint4 bN1 = *(const uint4*)(Xs + off + 32 * PITCH);

        {
            const int rem = NS - 1 - s;
            const int allow = 2 * ((D - 1) < rem ? (D - 1) : rem);
            asm volatile("s_waitcnt vmcnt(%0)" :: "i"(allow) : "memory");
            __builtin_amdgcn_sched_barrier(0);
        }

        uint32x4 a0 = ra0[s % D];
        uint32x4 a1 = ra1[s % D];

        acc[0][0] = __builtin_amdgcn_mfma_f32_32x32x16_bf16(
            as_bf16x8v(a0), as_bf16x8(bC0), acc[0][0], 0, 0, 0);
        acc[1][0] = __builtin_amdgcn_mfma_f32_32x32x16_bf16(
            as_bf16x8v(a1), as_bf16x8(bC0), acc[1][0], 0, 0, 0);
        acc[0][1] = __builtin_amdgcn_mfma_f32_32x32x16_bf16(
            as_bf16x8v(a0), as_bf16x8(bC1), acc[0][1], 0, 0, 0);
        acc[1][1] = __builtin_amdgcn_mfma_f32_32x32x16_bf16(
            as_bf16x8v(a1), as_bf16x8(bC1), acc[1][1], 0, 0, 0);

        if (s + D < NS) {
            ra0[s % D] = gload16(Wb, abase0 + (unsigned)((s + D) * 1024));
            ra1[s % D] = gload16(Wb, abase1 + (unsigned)((s + D) * 1024));
        }

        bC0 = bN0; bC1 = bN1;
    }

    if (!FMAX) {
        ushort_t* out = (ushort_t*)outv + (size_t)b * LP * COUT;
#pragma unroll
        for (int ct = 0; ct < 2; ++ct) {
            int cbase = (cw * 2 + ct) * 32 + 4 * half;
#pragma unroll
            for (int g = 0; g < 4; ++g) {
                int co = cbase + 8 * g;
                if (co >= COUT) continue;
                float4 bv = *(const float4*)(bias + co);
#pragma unroll
                for (int lt = 0; lt < 2; ++lt) {
                    int l = l0 + lw * 64 + lt * 32 + ln31;
                    if (l < LP) {
                        ushort_t h0 = f2bf(fmaxf(acc[ct][lt][4 * g + 0] + bv.x, 0.f));
                        ushort_t h1 = f2bf(fmaxf(acc[ct][lt][4 * g + 1] + bv.y, 0.f));
                        ushort_t h2 = f2bf(fmaxf(acc[ct][lt][4 * g + 2] + bv.z, 0.f));
                        ushort_t h3 = f2bf(fmaxf(acc[ct][lt][4 * g + 3] + bv.w, 0.f));
                        uint2 o;
                        o.x = (unsigned)h0 | ((unsigned)h1 << 16);
                        o.y = (unsigned)h2 | ((unsigned)h3 << 16);
                        *(uint2*)(out + (size_t)l * COUT + co) = o;
                    }
                }
            }
        }
    } else {
        float* xout = (float*)outv;
#pragma unroll
        for (int ct = 0; ct < 2; ++ct) {
            float mx[16];
#pragma unroll
            for (int r = 0; r < 16; ++r) mx[r] = -3.0e38f;
#pragma unroll
            for (int lt = 0; lt < 2; ++lt) {
                int l = l0 + lw * 64 + lt * 32 + ln31;
                if (l < LP) {
#pragma unroll
                    for (int r = 0; r < 16; ++r) mx[r] = fmaxf(mx[r], acc[ct][lt][r]);
                }
            }
#pragma unroll
            for (int r = 0; r < 16; ++r) {
#pragma unroll
                for (int off = 1; off < 32; off <<= 1)
                    mx[r] = fmaxf(mx[r], __shfl_xor(mx[r], off, 64));
            }
            if (ln31 == 0) {
                int cbase = (cw * 2 + ct) * 32 + 4 * half;
#pragma unroll
                for (int r = 0; r < 16; ++r) {
                    int co = cbase + (r & 3) + 8 * (r >> 2);
                    if (co < COUT) {
                        float v = fmaxf(mx[r] + bias[co], 0.f);
                        atomicMax((int*)&xout[(size_t)b * 400 + 200 + co], __float_as_int(v));
                    }
                }
            }
        }
    }
}

// ---------------- msg update via MFMA GEMM (R10 WIN, unchanged numerics) ----------------
#define MPITCH 216   // 208 + 8 ushorts
static __device__ __forceinline__ void msg_body(
        int blk, const float* __restrict__ msgIn, const float* __restrict__ binput,
        const int* __restrict__ bgraph, const ushort_t* __restrict__ Wbh,
        float* __restrict__ msgOut, ushort_t* __restrict__ Xs, int* __restrict__ idxs) {
    constexpr int D = 4;
    int m0 = blk * 32;
    int tid = threadIdx.x;

    if (tid < 192) {
        int r = tid / 6, j = tid - r * 6;
        int m = m0 + r;
        int mol = m / NBB;
        idxs[tid] = mol * NBB + bgraph[(size_t)m * 6 + j];
    }
    __syncthreads();

    for (int it = tid; it < 32 * 26; it += 256) {
        int r = it / 26, c = it - r * 26;
        uint4 v = {0u, 0u, 0u, 0u};
        if (c < 25) {
            float sv[8];
#pragma unroll
            for (int k = 0; k < 8; ++k) sv[k] = 0.f;
#pragma unroll
            for (int j = 0; j < 6; ++j) {
                const float* row = msgIn + (size_t)idxs[r * 6 + j] * H + c * 8;
                float4 a = *(const float4*)row;
                float4 b = *(const float4*)(row + 4);
                sv[0] += a.x; sv[1] += a.y; sv[2] += a.z; sv[3] += a.w;
                sv[4] += b.x; sv[5] += b.y; sv[6] += b.z; sv[7] += b.w;
            }
            v.x = (unsigned)f2bf(sv[0]) | ((unsigned)f2bf(sv[1]) << 16);
            v.y = (unsigned)f2bf(sv[2]) | ((unsigned)f2bf(sv[3]) << 16);
            v.z = (unsigned)f2bf(sv[4]) | ((unsigned)f2bf(sv[5]) << 16);
            v.w = (unsigned)f2bf(sv[6]) | ((unsigned)f2bf(sv[7]) << 16);
        }
        *(uint4*)(Xs + r * MPITCH + c * 8) = v;
    }

    int lane = tid & 63, wv = tid >> 6;
    int ln31 = lane & 31, half = lane >> 5;
    unsigned abase0 = (unsigned)(wv * 2) * (unsigned)MNS * 1024u + (unsigned)lane * 16u;
    unsigned abase1 = abase0 + (unsigned)MNS * 1024u;
    int bbase = ln31 * MPITCH + half * 8;

    f32x16 acc[2];
#pragma unroll
    for (int ct = 0; ct < 2; ++ct)
#pragma unroll
        for (int r = 0; r < 16; ++r) acc[ct][r] = 0.f;

    __syncthreads();

    uint32x4 ra0[4], ra1[4];
#pragma unroll
    for (int d = 0; d < D; ++d) {
        ra0[d] = gload16(Wbh, abase0 + (unsigned)(d * 1024));
        ra1[d] = gload16(Wbh, abase1 + (unsigned)(d * 1024));
    }

    uint4 bC = *(const uint4*)(Xs + bbase);

#pragma unroll
    for (int s = 0; s < MNS; ++s) {
        int sn = (s + 1 < MNS) ? s + 1 : MNS - 1;
        uint4 bN = *(const uint4*)(Xs + bbase + sn * 16);

        {
            const int rem = MNS - 1 - s;
            const int allow = 2 * ((D - 1) < rem ? (D - 1) : rem);
            asm volatile("s_waitcnt vmcnt(%0)" :: "i"(allow) : "memory");
            __builtin_amdgcn_sched_barrier(0);
        }

        uint32x4 a0 = ra0[s % D];
        uint32x4 a1 = ra1[s % D];
        acc[0] = __builtin_amdgcn_mfma_f32_32x32x16_bf16(
            as_bf16x8v(a0), as_bf16x8(bC), acc[0], 0, 0, 0);
        acc[1] = __builtin_amdgcn_mfma_f32_32x32x16_bf16(
            as_bf16x8v(a1), as_bf16x8(bC), acc[1], 0, 0, 0);

        if (s + D < MNS) {
            ra0[s % D] = gload16(Wbh, abase0 + (unsigned)((s + D) * 1024));
            ra1[s % D] = gload16(Wbh, abase1 + (unsigned)((s + D) * 1024));
        }
        bC = bN;
    }

    int m = m0 + ln31;
    const float* bi = binput + (size_t)m * H;
    float* outp = msgOut + (size_t)m * H;
#pragma unroll
    for (int ct = 0; ct < 2; ++ct) {
        int cbase = (wv * 2 + ct) * 32 + 4 * half;
#pragma unroll
        for (int g = 0; g < 4; ++g) {
            int co = cbase + 8 * g;
            if (co >= H) continue;
            float4 b4 = *(const float4*)(bi + co);
            float4 o;
            o.x = fmaxf(acc[ct][4 * g + 0] + b4.x, 0.f);
            o.y = fmaxf(acc[ct][4 * g + 1] + b4.y, 0.f);
            o.z = fmaxf(acc[ct][4 * g + 2] + b4.z, 0.f);
            o.w = fmaxf(acc[ct][4 * g + 3] + b4.w, 0.f);
            *(float4*)(outp + co) = o;
        }
    }
}

// ---------------- bond input body ----------------
static __device__ __forceinline__ void bond_body(
        int blk, const float* __restrict__ fbonds, const float* __restrict__ Wi,
        float* __restrict__ binput, float* __restrict__ msg, float (*fb)[BFD]) {
    int bond0 = blk * BIPB;
    int tid = threadIdx.x;
    for (int idx = tid; idx < BIPB * BFD; idx += 256)
        fb[idx / BFD][idx % BFD] = fbonds[(size_t)bond0 * BFD + idx];
    __syncthreads();
    if (tid < H) {
        float acc[BIPB];
#pragma unroll
        for (int q = 0; q < BIPB; ++q) acc[q] = 0.f;
#pragma unroll 5
        for (int k = 0; k < BFD; ++k) {
            float w = Wi[k * H + tid];
#pragma unroll
            for (int q = 0; q < BIPB; ++q) acc[q] += fb[q][k] * w;
        }
#pragma unroll
        for (int q = 0; q < BIPB; ++q) {
            size_t o = (size_t)(bond0 + q) * H + tid;
            binput[o] = acc[q];
            msg[o] = fmaxf(acc[q], 0.f);
        }
    }
}

// ---------------- atom head body ----------------
static __device__ __forceinline__ void atom_body(
        int blk, const float* __restrict__ msg, const float* __restrict__ fatoms,
        const int* __restrict__ agraph, const float* __restrict__ Wo,
        const float* __restrict__ Wob, float* __restrict__ x,
        float (*cat)[CATD], int* __restrict__ idxs) {
    const int grpPerMol = NA / APB;
    int b = blk / grpPerMol;
    int grp = blk % grpPerMol;
    int atom0 = grp * APB;
    int tid = threadIdx.x;
    if (tid < APB * 6) idxs[tid] = agraph[((size_t)(b * NA + atom0)) * 6 + tid];
    for (int idx = tid; idx < APB * AFD; idx += 256) {
        int q = idx / AFD, c = idx % AFD;
        cat[q][c] = fatoms[((size_t)(b * NA + atom0 + q)) * AFD + c];
    }
    __syncthreads();
    if (tid < H) {
        const float* base = msg + (size_t)b * NBB * H;
#pragma unroll
        for (int q = 0; q < APB; ++q) {
            float s = 0.f;
#pragma unroll
            for (int j = 0; j < 6; ++j) s += base[(size_t)idxs[q * 6 + j] * H + tid];
            cat[q][AFD + tid] = s;
        }
    }
    __syncthreads();
    if (tid < H) {
        float bb = Wob[tid];
        float acc[APB];
#pragma unroll
        for (int q = 0; q < APB; ++q) acc[q] = bb;
#pragma unroll 4
        for (int k = 0; k < CATD; ++k) {
            float w = Wo[k * H + tid];
#pragma unroll
            for (int q = 0; q < APB; ++q) acc[q] += cat[q][k] * w;
        }
        float s = 0.f;
#pragma unroll
        for (int q = 0; q < APB; ++q) s += fmaxf(acc[q], 0.f);
        atomicAdd(&x[(size_t)b * 400 + tid], s * (1.f / NA));
    }
}

// ================= fused launches (R11): overlap independent MPNN with conv tower =================
// Same-stream kernels serialize; block-range dispatch lets independent chains co-run.
// L0: prep || bond.  L1: conv0 || msg1.  L2: conv1 || msg2.  L3: conv2 || atom.  L4: fc.

__global__ __launch_bounds__(256) void k_l0_prep_bond(
        const float* __restrict__ c0w, const float* __restrict__ c1w,
        const float* __restrict__ c2w, const float* __restrict__ Wh,
        float* __restrict__ x, ushort_t* __restrict__ Wb0,
        ushort_t* __restrict__ Wb1, ushort_t* __restrict__ Wb2,
        ushort_t* __restrict__ Wbh,
        const float* __restrict__ fbonds, const float* __restrict__ Wi,
        float* __restrict__ binput, float* __restrict__ msgA) {
    __shared__ float fb[BIPB][BFD];
    int bid = blockIdx.x;
    if (bid < PREP_BLKS) {
        prep_body(bid * 256 + threadIdx.x, c0w, c1w, c2w, Wh, x, Wb0, Wb1, Wb2, Wbh);
    } else {
        bond_body(bid - PREP_BLKS, fbonds, Wi, binput, msgA, fb);
    }
}

__global__ __launch_bounds__(256, 3) void k_l1_conv0_msg(
        const int* __restrict__ seq, const float* __restrict__ emb,
        const ushort_t* __restrict__ Wb0, const float* __restrict__ c0b,
        ushort_t* __restrict__ act1,
        const float* __restrict__ msgIn, const float* __restrict__ binput,
        const int* __restrict__ bgraph, const ushort_t* __restrict__ Wbh,
        float* __restrict__ msgOut) {
    __shared__ __align__(16) ushort_t Sbuf[(128 + 2) * (64 + 8)];  // 9360 ushorts
    if (blockIdx.x < 8) {
        conv_body<64, 3, 96, 2, 2, false, true>(nullptr, seq, emb, Wb0, c0b, act1, Sbuf);
    } else {
        int blk = (blockIdx.x - 8) * 128 + blockIdx.z;   // 0..383
        msg_body(blk, msgIn, binput, bgraph, Wbh, msgOut, Sbuf,
                 (int*)(Sbuf + 32 * MPITCH));            // idxs after 6912 ushorts
    }
}

__global__ __launch_bounds__(256, 3) void k_l2_conv1_msg(
        const ushort_t* __restrict__ act1, const ushort_t* __restrict__ Wb1,
        const float* __restrict__ c1b, ushort_t* __restrict__ act2,
        const float* __restrict__ msgIn, const float* __restrict__ binput,
        const int* __restrict__ bgraph, const ushort_t* __restrict__ Wbh,
        float* __restrict__ msgOut) {
    __shared__ __align__(16) ushort_t Sbuf[(128 + 4) * (96 + 8)];  // 13728 ushorts
    if (blockIdx.x < 8) {
        conv_body<96, 5, 128, 2, 2, false, false>(act1, nullptr, nullptr, Wb1, c1b, act2, Sbuf);
    } else {
        int blk = (blockIdx.x - 8) * 128 + blockIdx.z;
        msg_body(blk, msgIn, binput, bgraph, Wbh, msgOut, Sbuf,
                 (int*)(Sbuf + 32 * MPITCH));
    }
}

__global__ __launch_bounds__(256, 3) void k_l3_conv2_atom(
        const ushort_t* __restrict__ act2, const ushort_t* __restrict__ Wb2,
        const float* __restrict__ c2b, float* __restrict__ x,
        const float* __restrict__ msg, const float* __restrict__ fatoms,
        const int* __restrict__ agraph, const float* __restrict__ Wo,
        const float* __restrict__ Wob) {
    __shared__ __align__(16) ushort_t Sbuf[(64 + 6) * (128 + 8)];  // 9520 ushorts = 19040 B
    if (blockIdx.x < 16) {
        conv_body<128, 7, 200, 4, 1, true, false>(act2, nullptr, nullptr, Wb2, c2b, x, Sbuf);
    } else {
        int blk = (blockIdx.x - 16) * 128 + blockIdx.z;  // 0..767
        float (*cat)[CATD] = (float (*)[CATD])Sbuf;       // 7648 B
        int* idxs = (int*)((char*)Sbuf + APB * CATD * 4); // +192 B = 7840 <= 19040
        atom_body(blk, msg, fatoms, agraph, Wo, Wob, x, cat, idxs);
    }
}

// ---------------- fused FC head: 400 -> 200 -> 100 -> 1 ----------------
__global__ __launch_bounds__(256) void k_fc(
        const float* __restrict__ x,
        const float* __restrict__ w0, const float* __restrict__ b0,
        const float* __restrict__ w1, const float* __restrict__ b1,
        const float* __restrict__ w2, const float* __restrict__ b2,
        float* __restrict__ out) {
    int b = blockIdx.x, tid = threadIdx.x;
    __shared__ float xr[400];
    __shared__ float h1[200];
    __shared__ float h2[100];
    for (int i = tid; i < 400; i += 256) xr[i] = x[(size_t)b * 400 + i];
    __syncthreads();
    if (tid < 200) {
        float a = b0[tid];
#pragma unroll 4
        for (int k = 0; k < 400; ++k) a += xr[k] * w0[k * 200 + tid];
        h1[tid] = fmaxf(a, 0.f);
    }
    __syncthreads();
    if (tid < 100) {
        float a = b1[tid];
#pragma unroll 4
        for (int k = 0; k < 200; ++k) a += h1[k] * w1[k * 100 + tid];
        h2[tid] = fmaxf(a, 0.f);
    }
    __syncthreads();
    if (tid == 0) {
        float a = b2[0];
#pragma unroll 4
        for (int k = 0; k < 100; ++k) a += h2[k] * w2[k];
        out[b] = a;
    }
}

extern "C" void kernel_launch(void* const* d_in, const int* in_sizes, int n_in,
                              void* d_out, int out_size, void* d_ws, size_t ws_size,
                              hipStream_t stream) {
    const float* fatoms = (const float*)d_in[0];
    const float* fbonds = (const float*)d_in[1];
    const int* agraph = (const int*)d_in[2];
    const int* bgraph = (const int*)d_in[3];
    const int* seq = (const int*)d_in[4];
    const float* Wi = (const float*)d_in[5];
    const float* Wh = (const float*)d_in[6];
    const float* Wo = (const float*)d_in[7];
    const float* Wob = (const float*)d_in[8];
    const float* embp = (const float*)d_in[9];
    const float* c0w = (const float*)d_in[10];
    const float* c0b = (const float*)d_in[11];
    const float* c1w = (const float*)d_in[12];
    const float* c1b = (const float*)d_in[13];
    const float* c2w = (const float*)d_in[14];
    const float* c2b = (const float*)d_in[15];
    const float* fc0w = (const float*)d_in[16];
    const float* fc0b = (const float*)d_in[17];
    const float* fc1w = (const float*)d_in[18];
    const float* fc1b = (const float*)d_in[19];
    const float* fc2w = (const float*)d_in[20];
    const float* fc2b = (const float*)d_in[21];

    float* ws = (float*)d_ws;
    float* binput = ws;                    // 2457600
    float* msgA = binput + 2457600;        // 2457600
    float* msgB = msgA + 2457600;          // 2457600
    float* x = msgB + 2457600;             // 51200
    ushort_t* u = (ushort_t*)(x + 51200);  // bf16 region
    ushort_t* act1 = u;                    // 128000*96  = 12288000
    ushort_t* act2 = act1 + 12288000;      // 128000*128 = 16384000
    ushort_t* Wb0 = act2 + 16384000;       // 4*12*512  = 24576
    ushort_t* Wb1 = Wb0 + 24576;           // 4*30*512  = 61440
    ushort_t* Wb2 = Wb1 + 61440;           // 8*56*512  = 229376
    ushort_t* Wbh = Wb2 + 229376;          // 8*13*512  = 53248

    // L0: prep (weights swizzle + zero x) || bond_input  — both dependency-free
    k_l0_prep_bond<<<PREP_BLKS + BATCH * NBB / BIPB, 256, 0, stream>>>(
        c0w, c1w, c2w, Wh, x, Wb0, Wb1, Wb2, Wbh, fbonds, Wi, binput, msgA);

    // L1: conv0 || msg pass 1 (msgA -> msgB)
    k_l1_conv0_msg<<<dim3(8 + 3, 1, BATCH), 256, 0, stream>>>(
        seq, embp, Wb0, c0b, act1, msgA, binput, bgraph, Wbh, msgB);

    // L2: conv1 || msg pass 2 (msgB -> msgA)
    k_l2_conv1_msg<<<dim3(8 + 3, 1, BATCH), 256, 0, stream>>>(
        act1, Wb1, c1b, act2, msgB, binput, bgraph, Wbh, msgA);

    // L3: conv2 || atom head (disjoint halves of x)
    k_l3_conv2_atom<<<dim3(16 + 6, 1, BATCH), 256, 0, stream>>>(
        act2, Wb2, c2b, x, msgA, fatoms, agraph, Wo, Wob);

    // L4: fc head
    k_fc<<<BATCH, 256, 0, stream>>>(x, fc0w, fc0b, fc1w, fc1b, fc2w, fc2b, (float*)d_out);
}

// Round 10
// 323.642 us; speedup vs baseline: 1.3768x; 1.0226x over previous
//
#include <hip/hip_runtime.h>
#include <hip/hip_bf16.h>
#include <cstddef>

#define H 200
#define NA 48
#define NBB 96
#define BATCH 128
#define AFD 39
#define BFD 50          // 39+11
#define LP 1000
#define CATD (AFD + H)  // 239
#define BIPB 16         // bonds per block in bond-input kernel

typedef unsigned short ushort_t;
typedef __bf16 bf16x8 __attribute__((ext_vector_type(8)));
typedef float f32x16 __attribute__((ext_vector_type(16)));
typedef unsigned uint32x4 __attribute__((ext_vector_type(4)));

union U16B { uint4 u; bf16x8 b; };
static __device__ __forceinline__ bf16x8 as_bf16x8(uint4 u) { U16B x; x.u = u; return x.b; }
union U16B2 { uint32x4 u; bf16x8 b; };
static __device__ __forceinline__ bf16x8 as_bf16x8v(uint32x4 u) { U16B2 x; x.u = u; return x.b; }

// float -> bf16 (RNE)
static __device__ __forceinline__ ushort_t f2bf(float f) {
    union { float f; unsigned u; } a; a.f = f;
    unsigned r = (a.u + 0x7FFFu + ((a.u >> 16) & 1u)) >> 16;
    return (ushort_t)r;
}

// raw asm global load: 16B at sgpr-base + 32-bit voffset. asm volatile pins issue
// order -> counted vmcnt discipline stays valid. "=&v" early-clobber.
static __device__ __forceinline__ uint32x4 gload16(const ushort_t* base, unsigned voff) {
    uint32x4 r;
    asm volatile("global_load_dwordx4 %0, %1, %2"
                 : "=&v"(r) : "v"(voff), "s"(base));
    return r;
}

// ---------------- prep: weight swizzles (32x32x16 A-frag order) ----------------
template <int COUT, int CIN, int CP, int K>
static __device__ __forceinline__ void prep_one(int t, const float* __restrict__ w,
                                                ushort_t* __restrict__ Wb) {
    constexpr int NC = CP / 16;
    constexpr int NS = K * NC;
    int j = t & 7;
    int lane = (t >> 3) & 63;
    int s = (t >> 9) % NS;
    int ct = (t >> 9) / NS;
    int co = ct * 32 + (lane & 31);
    int tt = s / NC, cc = s % NC;
    int ci = cc * 16 + ((lane >> 5) & 1) * 8 + j;
    float v = 0.f;
    if (co < COUT && ci < CIN) v = w[((size_t)co * CIN + ci) * K + tt];
    Wb[t] = f2bf(v);
}

#define MNS 13                            // K-steps for msg GEMM (208/16)
#define ANS 15                            // K-steps for atom GEMM (240/16)
#define PREP_T0 (4 * 12 * 512)            // conv0: 4 tiles x NS=12
#define PREP_T1 (PREP_T0 + 4 * 30 * 512)  // conv1: 4 tiles x NS=30
#define PREP_T2 (PREP_T1 + 8 * 56 * 512)  // conv2: 8 tiles x NS=56
#define PREP_T3 (PREP_T2 + 51200)         // zero x
#define PREP_T4 (PREP_T3 + 8 * MNS * 512) // Wh swizzle: 8 tiles x 13 steps
#define PREP_T5 (PREP_T4 + 8 * ANS * 512) // Wo swizzle (permuted K: nei|fa|pad)
#define PREP_BLKS (PREP_T5 / 256)         // 481280/256 = 1880 exactly

static __device__ __forceinline__ void prep_body(
        int tid, const float* __restrict__ c0w, const float* __restrict__ c1w,
        const float* __restrict__ c2w, const float* __restrict__ Wh,
        const float* __restrict__ Wo, float* __restrict__ x,
        ushort_t* __restrict__ Wb0, ushort_t* __restrict__ Wb1,
        ushort_t* __restrict__ Wb2, ushort_t* __restrict__ Wbh,
        ushort_t* __restrict__ Wbo) {
    if (tid < PREP_T0) prep_one<96, 50, 64, 3>(tid, c0w, Wb0);
    else if (tid < PREP_T1) prep_one<128, 96, 96, 5>(tid - PREP_T0, c1w, Wb1);
    else if (tid < PREP_T2) prep_one<200, 128, 128, 7>(tid - PREP_T1, c2w, Wb2);
    else if (tid < PREP_T3) x[tid - PREP_T2] = 0.f;
    else if (tid < PREP_T4) {
        // Wh stored (in,out): value for (co, ci) = Wh[ci*200 + co]
        int t = tid - PREP_T3;
        int j = t & 7;
        int lane = (t >> 3) & 63;
        int s = (t >> 9) % MNS;
        int tile = (t >> 9) / MNS;
        int co = tile * 32 + (lane & 31);
        int ci = s * 16 + ((lane >> 5) & 1) * 8 + j;
        float v = 0.f;
        if (co < H && ci < H) v = Wh[ci * H + co];
        Wbh[t] = f2bf(v);
    } else if (tid < PREP_T5) {
        // Wo stored (in=239, out=200). Permuted K-axis ci' : [0,200)=nei -> Wo row 39+ci',
        // [200,239)=fa -> Wo row ci'-200, 239 = pad. Lets B staging reuse aligned nei gather.
        int t = tid - PREP_T4;
        int j = t & 7;
        int lane = (t >> 3) & 63;
        int s = (t >> 9) % ANS;
        int tile = (t >> 9) / ANS;
        int co = tile * 32 + (lane & 31);
        int cip = s * 16 + ((lane >> 5) & 1) * 8 + j;
        float v = 0.f;
        if (co < H) {
            if (cip < 200) v = Wo[(size_t)(39 + cip) * H + co];
            else if (cip < CATD) v = Wo[(size_t)(cip - 200) * H + co];
        }
        Wbo[t] = f2bf(v);
    }
}

// ---------------- MFMA conv1d body, 32x32x16 ----------------
// R8 WIN: inline-asm A ring (depth D=4), counted s_waitcnt vmcnt + sched_barrier(0).
// conv2 84.4 -> 72.4 us, MfmaUtil 29 -> 35.6%. Do not touch.
template <int CP, int K, int COUT, int CO_WAVES, int L_WAVES, bool FMAX, bool EMB>
static __device__ __forceinline__ void conv_body(
        const ushort_t* __restrict__ act, const int* __restrict__ seq,
        const float* __restrict__ emb, const ushort_t* __restrict__ Wb,
        const float* __restrict__ bias, void* __restrict__ outv,
        ushort_t* __restrict__ Xs) {
    constexpr int NC = CP / 16;
    constexpr int NS = K * NC;
    constexpr int P = K / 2;
    constexpr int PITCH = CP + 8;
    constexpr int LTILE = 64 * L_WAVES;
    constexpr int ROWS = LTILE + K - 1;
    constexpr int CPR = CP / 8;
    constexpr int D = 4;

    int b = blockIdx.z, lb = blockIdx.x;
    int l0 = lb * LTILE;
    int tid = threadIdx.x;

    if (EMB) {
        const int* seqb = seq + (size_t)b * LP;
        for (int idx = tid; idx < ROWS * CPR; idx += 256) {
            int r = idx / CPR, c = idx % CPR;
            int l = l0 - P + r;
            uint4 v = {0u, 0u, 0u, 0u};
            if ((unsigned)l < (unsigned)LP) {
                int s = seqb[l];
                const float* e = emb + (size_t)s * 50;
                ushort_t h[8];
#pragma unroll
                for (int j = 0; j < 8; ++j) {
                    int cc = c * 8 + j;
                    h[j] = (cc < 50) ? f2bf(e[cc]) : (ushort_t)0;
                }
                v.x = (unsigned)h[0] | ((unsigned)h[1] << 16);
                v.y = (unsigned)h[2] | ((unsigned)h[3] << 16);
                v.z = (unsigned)h[4] | ((unsigned)h[5] << 16);
                v.w = (unsigned)h[6] | ((unsigned)h[7] << 16);
            }
            *(uint4*)(Xs + r * PITCH + c * 8) = v;
        }
    } else {
        const ushort_t* actb = act + (size_t)b * LP * CP;
        for (int idx = tid; idx < ROWS * CPR; idx += 256) {
            int r = idx / CPR, c = idx % CPR;
            int l = l0 - P + r;
            uint4 v = {0u, 0u, 0u, 0u};
            if ((unsigned)l < (unsigned)LP) v = *(const uint4*)(actb + (size_t)l * CP + c * 8);
            *(uint4*)(Xs + r * PITCH + c * 8) = v;
        }
    }

    int lane = tid & 63, wv = tid >> 6;
    int cw = wv % CO_WAVES, lw = wv / CO_WAVES;
    int ln31 = lane & 31, half = lane >> 5;

    unsigned abase0 = (unsigned)(cw * 2) * (unsigned)NS * 1024u + (unsigned)lane * 16u;
    unsigned abase1 = abase0 + (unsigned)NS * 1024u;
    int bbase = (lw * 64 + ln31) * PITCH + half * 8;

    f32x16 acc[2][2];
#pragma unroll
    for (int ct = 0; ct < 2; ++ct)
#pragma unroll
        for (int lt = 0; lt < 2; ++lt)
#pragma unroll
            for (int r = 0; r < 16; ++r) acc[ct][lt][r] = 0.f;

    __syncthreads();   // staging drained -> vmcnt counts ONLY ring loads

    uint32x4 ra0[D], ra1[D];
#pragma unroll
    for (int d = 0; d < D; ++d) {
        ra0[d] = gload16(Wb, abase0 + (unsigned)(d * 1024));
        ra1[d] = gload16(Wb, abase1 + (unsigned)(d * 1024));
    }

    uint4 bC0 = *(const uint4*)(Xs + bbase);
    uint4 bC1 = *(const uint4*)(Xs + bbase + 32 * PITCH);

#pragma unroll
    for (int s = 0; s < NS; ++s) {
        int sn = (s + 1 < NS) ? s + 1 : NS - 1;
        int tn = sn / NC, ccn = sn % NC;
        int off = bbase + tn * PITCH + ccn * 16;
        uint4 bN0 = *(const uint4*)(Xs + off);
        uint4 bN1 = *(const uint4*)(Xs + off + 32 * PITCH);

        {
            const int rem = NS - 1 - s;
            const int allow = 2 * ((D - 1) < rem ? (D - 1) : rem);
            asm volatile("s_waitcnt vmcnt(%0)" :: "i"(allow) : "memory");
            __builtin_amdgcn_sched_barrier(0);
        }

        uint32x4 a0 = ra0[s % D];
        uint32x4 a1 = ra1[s % D];

        acc[0][0] = __builtin_amdgcn_mfma_f32_32x32x16_bf16(
            as_bf16x8v(a0), as_bf16x8(bC0), acc[0][0], 0, 0, 0);
        acc[1][0] = __builtin_amdgcn_mfma_f32_32x32x16_bf16(
            as_bf16x8v(a1), as_bf16x8(bC0), acc[1][0], 0, 0, 0);
        acc[0][1] = __builtin_amdgcn_mfma_f32_32x32x16_bf16(
            as_bf16x8v(a0), as_bf16x8(bC1), acc[0][1], 0, 0, 0);
        acc[1][1] = __builtin_amdgcn_mfma_f32_32x32x16_bf16(
            as_bf16x8v(a1), as_bf16x8(bC1), acc[1][1], 0, 0, 0);

        if (s + D < NS) {
            ra0[s % D] = gload16(Wb, abase0 + (unsigned)((s + D) * 1024));
            ra1[s % D] = gload16(Wb, abase1 + (unsigned)((s + D) * 1024));
        }

        bC0 = bN0; bC1 = bN1;
    }

    if (!FMAX) {
        ushort_t* out = (ushort_t*)outv + (size_t)b * LP * COUT;
#pragma unroll
        for (int ct = 0; ct < 2; ++ct) {
            int cbase = (cw * 2 + ct) * 32 + 4 * half;
#pragma unroll
            for (int g = 0; g < 4; ++g) {
                int co = cbase + 8 * g;
                if (co >= COUT) continue;
                float4 bv = *(const float4*)(bias + co);
#pragma unroll
                for (int lt = 0; lt < 2; ++lt) {
                    int l = l0 + lw * 64 + lt * 32 + ln31;
                    if (l < LP) {
                        ushort_t h0 = f2bf(fmaxf(acc[ct][lt][4 * g + 0] + bv.x, 0.f));
                        ushort_t h1 = f2bf(fmaxf(acc[ct][lt][4 * g + 1] + bv.y, 0.f));
                        ushort_t h2 = f2bf(fmaxf(acc[ct][lt][4 * g + 2] + bv.z, 0.f));
                        ushort_t h3 = f2bf(fmaxf(acc[ct][lt][4 * g + 3] + bv.w, 0.f));
                        uint2 o;
                        o.x = (unsigned)h0 | ((unsigned)h1 << 16);
                        o.y = (unsigned)h2 | ((unsigned)h3 << 16);
                        *(uint2*)(out + (size_t)l * COUT + co) = o;
                    }
                }
            }
        }
    } else {
        float* xout = (float*)outv;
#pragma unroll
        for (int ct = 0; ct < 2; ++ct) {
            float mx[16];
#pragma unroll
            for (int r = 0; r < 16; ++r) mx[r] = -3.0e38f;
#pragma unroll
            for (int lt = 0; lt < 2; ++lt) {
                int l = l0 + lw * 64 + lt * 32 + ln31;
                if (l < LP) {
#pragma unroll
                    for (int r = 0; r < 16; ++r) mx[r] = fmaxf(mx[r], acc[ct][lt][r]);
                }
            }
#pragma unroll
            for (int r = 0; r < 16; ++r) {
#pragma unroll
                for (int off = 1; off < 32; off <<= 1)
                    mx[r] = fmaxf(mx[r], __shfl_xor(mx[r], off, 64));
            }
            if (ln31 == 0) {
                int cbase = (cw * 2 + ct) * 32 + 4 * half;
#pragma unroll
                for (int r = 0; r < 16; ++r) {
                    int co = cbase + (r & 3) + 8 * (r >> 2);
                    if (co < COUT) {
                        float v = fmaxf(mx[r] + bias[co], 0.f);
                        atomicMax((int*)&xout[(size_t)b * 400 + 200 + co], __float_as_int(v));
                    }
                }
            }
        }
    }
}

// ---------------- msg update via MFMA GEMM (R10 WIN, unchanged numerics) ----------------
#define MPITCH 216   // 208 + 8 ushorts
static __device__ __forceinline__ void msg_body(
        int blk, const float* __restrict__ msgIn, const float* __restrict__ binput,
        const int* __restrict__ bgraph, const ushort_t* __restrict__ Wbh,
        float* __restrict__ msgOut, ushort_t* __restrict__ Xs, int* __restrict__ idxs) {
    constexpr int D = 4;
    int m0 = blk * 32;
    int tid = threadIdx.x;

    if (tid < 192) {
        int r = tid / 6, j = tid - r * 6;
        int m = m0 + r;
        int mol = m / NBB;
        idxs[tid] = mol * NBB + bgraph[(size_t)m * 6 + j];
    }
    __syncthreads();

    for (int it = tid; it < 32 * 26; it += 256) {
        int r = it / 26, c = it - r * 26;
        uint4 v = {0u, 0u, 0u, 0u};
        if (c < 25) {
            float sv[8];
#pragma unroll
            for (int k = 0; k < 8; ++k) sv[k] = 0.f;
#pragma unroll
            for (int j = 0; j < 6; ++j) {
                const float* row = msgIn + (size_t)idxs[r * 6 + j] * H + c * 8;
                float4 a = *(const float4*)row;
                float4 b = *(const float4*)(row + 4);
                sv[0] += a.x; sv[1] += a.y; sv[2] += a.z; sv[3] += a.w;
                sv[4] += b.x; sv[5] += b.y; sv[6] += b.z; sv[7] += b.w;
            }
            v.x = (unsigned)f2bf(sv[0]) | ((unsigned)f2bf(sv[1]) << 16);
            v.y = (unsigned)f2bf(sv[2]) | ((unsigned)f2bf(sv[3]) << 16);
            v.z = (unsigned)f2bf(sv[4]) | ((unsigned)f2bf(sv[5]) << 16);
            v.w = (unsigned)f2bf(sv[6]) | ((unsigned)f2bf(sv[7]) << 16);
        }
        *(uint4*)(Xs + r * MPITCH + c * 8) = v;
    }

    int lane = tid & 63, wv = tid >> 6;
    int ln31 = lane & 31, half = lane >> 5;
    unsigned abase0 = (unsigned)(wv * 2) * (unsigned)MNS * 1024u + (unsigned)lane * 16u;
    unsigned abase1 = abase0 + (unsigned)MNS * 1024u;
    int bbase = ln31 * MPITCH + half * 8;

    f32x16 acc[2];
#pragma unroll
    for (int ct = 0; ct < 2; ++ct)
#pragma unroll
        for (int r = 0; r < 16; ++r) acc[ct][r] = 0.f;

    __syncthreads();

    uint32x4 ra0[4], ra1[4];
#pragma unroll
    for (int d = 0; d < D; ++d) {
        ra0[d] = gload16(Wbh, abase0 + (unsigned)(d * 1024));
        ra1[d] = gload16(Wbh, abase1 + (unsigned)(d * 1024));
    }

    uint4 bC = *(const uint4*)(Xs + bbase);

#pragma unroll
    for (int s = 0; s < MNS; ++s) {
        int sn = (s + 1 < MNS) ? s + 1 : MNS - 1;
        uint4 bN = *(const uint4*)(Xs + bbase + sn * 16);

        {
            const int rem = MNS - 1 - s;
            const int allow = 2 * ((D - 1) < rem ? (D - 1) : rem);
            asm volatile("s_waitcnt vmcnt(%0)" :: "i"(allow) : "memory");
            __builtin_amdgcn_sched_barrier(0);
        }

        uint32x4 a0 = ra0[s % D];
        uint32x4 a1 = ra1[s % D];
        acc[0] = __builtin_amdgcn_mfma_f32_32x32x16_bf16(
            as_bf16x8v(a0), as_bf16x8(bC), acc[0], 0, 0, 0);
        acc[1] = __builtin_amdgcn_mfma_f32_32x32x16_bf16(
            as_bf16x8v(a1), as_bf16x8(bC), acc[1], 0, 0, 0);

        if (s + D < MNS) {
            ra0[s % D] = gload16(Wbh, abase0 + (unsigned)((s + D) * 1024));
            ra1[s % D] = gload16(Wbh, abase1 + (unsigned)((s + D) * 1024));
        }
        bC = bN;
    }

    int m = m0 + ln31;
    const float* bi = binput + (size_t)m * H;
    float* outp = msgOut + (size_t)m * H;
#pragma unroll
    for (int ct = 0; ct < 2; ++ct) {
        int cbase = (wv * 2 + ct) * 32 + 4 * half;
#pragma unroll
        for (int g = 0; g < 4; ++g) {
            int co = cbase + 8 * g;
            if (co >= H) continue;
            float4 b4 = *(const float4*)(bi + co);
            float4 o;
            o.x = fmaxf(acc[ct][4 * g + 0] + b4.x, 0.f);
            o.y = fmaxf(acc[ct][4 * g + 1] + b4.y, 0.f);
            o.z = fmaxf(acc[ct][4 * g + 2] + b4.z, 0.f);
            o.w = fmaxf(acc[ct][4 * g + 3] + b4.w, 0.f);
            *(float4*)(outp + co) = o;
        }
    }
}

// ---------------- atom head via MFMA GEMM (R12) ----------------
// relu(cat(fa,nei)@Wo + b) then mean over atoms -> x[:, :200]. 6144x240 @ 240x200.
// K-axis permuted (nei[200] | fa[39] | pad) so nei staging = msg_body's aligned gather.
// Old DS-bound matvec co-resident with conv2 cost L3 ~40us (MfmaUtil 34->22, 5376 bank
// conflicts); MFMA version barely touches DS pipe.
#define APITCH 248   // 240 + 8 ushorts
static __device__ __forceinline__ void atom_mfma_body(
        int blk, const float* __restrict__ msg, const float* __restrict__ fatoms,
        const int* __restrict__ agraph, const ushort_t* __restrict__ Wbo,
        const float* __restrict__ Wob, float* __restrict__ x,
        ushort_t* __restrict__ Xs, int* __restrict__ idxs) {
    constexpr int D = 4;
    int m0 = blk * 32;
    int tid = threadIdx.x;

    if (tid < 192) {
        int r = tid / 6, j = tid - r * 6;
        int m = m0 + r;
        int mol = m / NA;
        idxs[tid] = mol * NBB + agraph[(size_t)m * 6 + j];
    }
    __syncthreads();

    // B tile: rows = atoms, cols = permuted K (0..199 nei gather-sum, 200..238 fa, 239 pad)
    for (int it = tid; it < 32 * 30; it += 256) {
        int r = it / 30, c = it - r * 30;
        uint4 v = {0u, 0u, 0u, 0u};
        if (c < 25) {
            float sv[8];
#pragma unroll
            for (int k = 0; k < 8; ++k) sv[k] = 0.f;
#pragma unroll
            for (int j = 0; j < 6; ++j) {
                const float* row = msg + (size_t)idxs[r * 6 + j] * H + c * 8;
                float4 a = *(const float4*)row;
                float4 b = *(const float4*)(row + 4);
                sv[0] += a.x; sv[1] += a.y; sv[2] += a.z; sv[3] += a.w;
                sv[4] += b.x; sv[5] += b.y; sv[6] += b.z; sv[7] += b.w;
            }
            v.x = (unsigned)f2bf(sv[0]) | ((unsigned)f2bf(sv[1]) << 16);
            v.y = (unsigned)f2bf(sv[2]) | ((unsigned)f2bf(sv[3]) << 16);
            v.z = (unsigned)f2bf(sv[4]) | ((unsigned)f2bf(sv[5]) << 16);
            v.w = (unsigned)f2bf(sv[6]) | ((unsigned)f2bf(sv[7]) << 16);
        } else {
            int m = m0 + r;
            ushort_t h[8];
#pragma unroll
            for (int j = 0; j < 8; ++j) {
                int f = c * 8 + j - 200;
                h[j] = (f < AFD) ? f2bf(fatoms[(size_t)m * AFD + f]) : (ushort_t)0;
            }
            v.x = (unsigned)h[0] | ((unsigned)h[1] << 16);
            v.y = (unsigned)h[2] | ((unsigned)h[3] << 16);
            v.z = (unsigned)h[4] | ((unsigned)h[5] << 16);
            v.w = (unsigned)h[6] | ((unsigned)h[7] << 16);
        }
        *(uint4*)(Xs + r * APITCH + c * 8) = v;
    }

    int lane = tid & 63, wv = tid >> 6;
    int ln31 = lane & 31, half = lane >> 5;
    unsigned abase0 = (unsigned)(wv * 2) * (unsigned)ANS * 1024u + (unsigned)lane * 16u;
    unsigned abase1 = abase0 + (unsigned)ANS * 1024u;
    int bbase = ln31 * APITCH + half * 8;

    f32x16 acc[2];
#pragma unroll
    for (int ct = 0; ct < 2; ++ct)
#pragma unroll
        for (int r = 0; r < 16; ++r) acc[ct][r] = 0.f;

    __syncthreads();

    uint32x4 ra0[4], ra1[4];
#pragma unroll
    for (int d = 0; d < D; ++d) {
        ra0[d] = gload16(Wbo, abase0 + (unsigned)(d * 1024));
        ra1[d] = gload16(Wbo, abase1 + (unsigned)(d * 1024));
    }

    uint4 bC = *(const uint4*)(Xs + bbase);

#pragma unroll
    for (int s = 0; s < ANS; ++s) {
        int sn = (s + 1 < ANS) ? s + 1 : ANS - 1;
        uint4 bN = *(const uint4*)(Xs + bbase + sn * 16);

        {
            const int rem = ANS - 1 - s;
            const int allow = 2 * ((D - 1) < rem ? (D - 1) : rem);
            asm volatile("s_waitcnt vmcnt(%0)" :: "i"(allow) : "memory");
            __builtin_amdgcn_sched_barrier(0);
        }

        uint32x4 a0 = ra0[s % D];
        uint32x4 a1 = ra1[s % D];
        acc[0] = __builtin_amdgcn_mfma_f32_32x32x16_bf16(
            as_bf16x8v(a0), as_bf16x8(bC), acc[0], 0, 0, 0);
        acc[1] = __builtin_amdgcn_mfma_f32_32x32x16_bf16(
            as_bf16x8v(a1), as_bf16x8(bC), acc[1], 0, 0, 0);

        if (s + D < ANS) {
            ra0[s % D] = gload16(Wbo, abase0 + (unsigned)((s + D) * 1024));
            ra1[s % D] = gload16(Wbo, abase1 + (unsigned)((s + D) * 1024));
        }
        bC = bN;
    }

    // Epilogue: relu(+bias)*(1/NA), segmented lane-reduce over atoms, atomicAdd per mol.
    // 48 = 32+16 -> a 32-atom block spans whole 16-lane groups: m0%48==0 or 16 -> all one
    // mol; m0%48==32 -> lanes 0-15 mol q, lanes 16-31 mol q+1.
    int rm = m0 % 48;
    bool split = (rm == 32);
    int molA = m0 / 48;
    const float inv = 1.f / NA;
#pragma unroll
    for (int ct = 0; ct < 2; ++ct) {
        int cbase = (wv * 2 + ct) * 32 + 4 * half;
#pragma unroll
        for (int r = 0; r < 16; ++r) {
            int co = cbase + (r & 3) + 8 * (r >> 2);
            float v = 0.f;
            if (co < H) v = fmaxf(acc[ct][r] + Wob[co], 0.f) * inv;
            v += __shfl_xor(v, 1, 64);
            v += __shfl_xor(v, 2, 64);
            v += __shfl_xor(v, 4, 64);
            v += __shfl_xor(v, 8, 64);
            if (!split) v += __shfl_xor(v, 16, 64);
            if (co < H) {
                if (ln31 == 0) atomicAdd(&x[(size_t)molA * 400 + co], v);
                else if (split && ln31 == 16) atomicAdd(&x[(size_t)(molA + 1) * 400 + co], v);
            }
        }
    }
}

// ---------------- bond input body ----------------
static __device__ __forceinline__ void bond_body(
        int blk, const float* __restrict__ fbonds, const float* __restrict__ Wi,
        float* __restrict__ binput, float* __restrict__ msg, float (*fb)[BFD]) {
    int bond0 = blk * BIPB;
    int tid = threadIdx.x;
    for (int idx = tid; idx < BIPB * BFD; idx += 256)
        fb[idx / BFD][idx % BFD] = fbonds[(size_t)bond0 * BFD + idx];
    __syncthreads();
    if (tid < H) {
        float acc[BIPB];
#pragma unroll
        for (int q = 0; q < BIPB; ++q) acc[q] = 0.f;
#pragma unroll 5
        for (int k = 0; k < BFD; ++k) {
            float w = Wi[k * H + tid];
#pragma unroll
            for (int q = 0; q < BIPB; ++q) acc[q] += fb[q][k] * w;
        }
#pragma unroll
        for (int q = 0; q < BIPB; ++q) {
            size_t o = (size_t)(bond0 + q) * H + tid;
            binput[o] = acc[q];
            msg[o] = fmaxf(acc[q], 0.f);
        }
    }
}

// ================= fused launches: overlap independent MPNN with conv tower =================
// L0: prep || bond.  L1: conv0 || msg1.  L2: conv1 || msg2.  L3: conv2 || atom-MFMA.  L4: fc.

__global__ __launch_bounds__(256) void k_l0_prep_bond(
        const float* __restrict__ c0w, const float* __restrict__ c1w,
        const float* __restrict__ c2w, const float* __restrict__ Wh,
        const float* __restrict__ Wo, float* __restrict__ x,
        ushort_t* __restrict__ Wb0, ushort_t* __restrict__ Wb1,
        ushort_t* __restrict__ Wb2, ushort_t* __restrict__ Wbh,
        ushort_t* __restrict__ Wbo,
        const float* __restrict__ fbonds, const float* __restrict__ Wi,
        float* __restrict__ binput, float* __restrict__ msgA) {
    __shared__ float fb[BIPB][BFD];
    int bid = blockIdx.x;
    if (bid < PREP_BLKS) {
        prep_body(bid * 256 + threadIdx.x, c0w, c1w, c2w, Wh, Wo, x, Wb0, Wb1, Wb2, Wbh, Wbo);
    } else {
        bond_body(bid - PREP_BLKS, fbonds, Wi, binput, msgA, fb);
    }
}

__global__ __launch_bounds__(256, 3) void k_l1_conv0_msg(
        const int* __restrict__ seq, const float* __restrict__ emb,
        const ushort_t* __restrict__ Wb0, const float* __restrict__ c0b,
        ushort_t* __restrict__ act1,
        const float* __restrict__ msgIn, const float* __restrict__ binput,
        const int* __restrict__ bgraph, const ushort_t* __restrict__ Wbh,
        float* __restrict__ msgOut) {
    __shared__ __align__(16) ushort_t Sbuf[(128 + 2) * (64 + 8)];  // 9360 ushorts
    if (blockIdx.x < 8) {
        conv_body<64, 3, 96, 2, 2, false, true>(nullptr, seq, emb, Wb0, c0b, act1, Sbuf);
    } else {
        int blk = (blockIdx.x - 8) * 128 + blockIdx.z;   // 0..383
        msg_body(blk, msgIn, binput, bgraph, Wbh, msgOut, Sbuf,
                 (int*)(Sbuf + 32 * MPITCH));
    }
}

__global__ __launch_bounds__(256, 3) void k_l2_conv1_msg(
        const ushort_t* __restrict__ act1, const ushort_t* __restrict__ Wb1,
        const float* __restrict__ c1b, ushort_t* __restrict__ act2,
        const float* __restrict__ msgIn, const float* __restrict__ binput,
        const int* __restrict__ bgraph, const ushort_t* __restrict__ Wbh,
        float* __restrict__ msgOut) {
    __shared__ __align__(16) ushort_t Sbuf[(128 + 4) * (96 + 8)];  // 13728 ushorts
    if (blockIdx.x < 8) {
        conv_body<96, 5, 128, 2, 2, false, false>(act1, nullptr, nullptr, Wb1, c1b, act2, Sbuf);
    } else {
        int blk = (blockIdx.x - 8) * 128 + blockIdx.z;
        msg_body(blk, msgIn, binput, bgraph, Wbh, msgOut, Sbuf,
                 (int*)(Sbuf + 32 * MPITCH));
    }
}

__global__ __launch_bounds__(256, 3) void k_l3_conv2_atom(
        const ushort_t* __restrict__ act2, const ushort_t* __restrict__ Wb2,
        const float* __restrict__ c2b, float* __restrict__ x,
        const float* __restrict__ msg, const float* __restrict__ fatoms,
        const int* __restrict__ agraph, const ushort_t* __restrict__ Wbo,
        const float* __restrict__ Wob) {
    __shared__ __align__(16) ushort_t Sbuf[(64 + 6) * (128 + 8)];  // 9520 ushorts = 19040 B
    if (blockIdx.x < 16) {
        conv_body<128, 7, 200, 4, 1, true, false>(act2, nullptr, nullptr, Wb2, c2b, x, Sbuf);
    } else {
        int blk = (blockIdx.x - 16) * 128 + blockIdx.z;  // 0..255, need <192
        if (blk < 192) {
            atom_mfma_body(blk, msg, fatoms, agraph, Wbo, Wob, x, Sbuf,
                           (int*)(Sbuf + 32 * APITCH));  // 7936 + 384 ushorts <= 9520
        }
    }
}

// ---------------- fused FC head: 400 -> 200 -> 100 -> 1 ----------------
__global__ __launch_bounds__(256) void k_fc(
        const float* __restrict__ x,
        const float* __restrict__ w0, const float* __restrict__ b0,
        const float* __restrict__ w1, const float* __restrict__ b1,
        const float* __restrict__ w2, const float* __restrict__ b2,
        float* __restrict__ out) {
    int b = blockIdx.x, tid = threadIdx.x;
    __shared__ float xr[400];
    __shared__ float h1[200];
    __shared__ float h2[100];
    for (int i = tid; i < 400; i += 256) xr[i] = x[(size_t)b * 400 + i];
    __syncthreads();
    if (tid < 200) {
        float a = b0[tid];
#pragma unroll 4
        for (int k = 0; k < 400; ++k) a += xr[k] * w0[k * 200 + tid];
        h1[tid] = fmaxf(a, 0.f);
    }
    __syncthreads();
    if (tid < 100) {
        float a = b1[tid];
#pragma unroll 4
        for (int k = 0; k < 200; ++k) a += h1[k] * w1[k * 100 + tid];
        h2[tid] = fmaxf(a, 0.f);
    }
    __syncthreads();
    if (tid == 0) {
        float a = b2[0];
#pragma unroll 4
        for (int k = 0; k < 100; ++k) a += h2[k] * w2[k];
        out[b] = a;
    }
}

extern "C" void kernel_launch(void* const* d_in, const int* in_sizes, int n_in,
                              void* d_out, int out_size, void* d_ws, size_t ws_size,
                              hipStream_t stream) {
    const float* fatoms = (const float*)d_in[0];
    const float* fbonds = (const float*)d_in[1];
    const int* agraph = (const int*)d_in[2];
    const int* bgraph = (const int*)d_in[3];
    const int* seq = (const int*)d_in[4];
    const float* Wi = (const float*)d_in[5];
    const float* Wh = (const float*)d_in[6];
    const float* Wo = (const float*)d_in[7];
    const float* Wob = (const float*)d_in[8];
    const float* embp = (const float*)d_in[9];
    const float* c0w = (const float*)d_in[10];
    const float* c0b = (const float*)d_in[11];
    const float* c1w = (const float*)d_in[12];
    const float* c1b = (const float*)d_in[13];
    const float* c2w = (const float*)d_in[14];
    const float* c2b = (const float*)d_in[15];
    const float* fc0w = (const float*)d_in[16];
    const float* fc0b = (const float*)d_in[17];
    const float* fc1w = (const float*)d_in[18];
    const float* fc1b = (const float*)d_in[19];
    const float* fc2w = (const float*)d_in[20];
    const float* fc2b = (const float*)d_in[21];

    float* ws = (float*)d_ws;
    float* binput = ws;                    // 2457600
    float* msgA = binput + 2457600;        // 2457600
    float* msgB = msgA + 2457600;          // 2457600
    float* x = msgB + 2457600;             // 51200
    ushort_t* u = (ushort_t*)(x + 51200);  // bf16 region
    ushort_t* act1 = u;                    // 128000*96  = 12288000
    ushort_t* act2 = act1 + 12288000;      // 128000*128 = 16384000
    ushort_t* Wb0 = act2 + 16384000;       // 4*12*512  = 24576
    ushort_t* Wb1 = Wb0 + 24576;           // 4*30*512  = 61440
    ushort_t* Wb2 = Wb1 + 61440;           // 8*56*512  = 229376
    ushort_t* Wbh = Wb2 + 229376;          // 8*13*512  = 53248
    ushort_t* Wbo = Wbh + 53248;           // 8*15*512  = 61440

    // L0: prep (weight swizzles incl. Wo + zero x) || bond_input
    k_l0_prep_bond<<<PREP_BLKS + BATCH * NBB / BIPB, 256, 0, stream>>>(
        c0w, c1w, c2w, Wh, Wo, x, Wb0, Wb1, Wb2, Wbh, Wbo, fbonds, Wi, binput, msgA);

    // L1: conv0 || msg pass 1 (msgA -> msgB)
    k_l1_conv0_msg<<<dim3(8 + 3, 1, BATCH), 256, 0, stream>>>(
        seq, embp, Wb0, c0b, act1, msgA, binput, bgraph, Wbh, msgB);

    // L2: conv1 || msg pass 2 (msgB -> msgA)
    k_l2_conv1_msg<<<dim3(8 + 3, 1, BATCH), 256, 0, stream>>>(
        act1, Wb1, c1b, act2, msgB, binput, bgraph, Wbh, msgA);

    // L3: conv2 || atom-MFMA (192 blocks over 2 x-slices; disjoint halves of x)
    k_l3_conv2_atom<<<dim3(16 + 2, 1, BATCH), 256, 0, stream>>>(
        act2, Wb2, c2b, x, msgA, fatoms, agraph, Wbo, Wob);

    // L4: fc head
    k_fc<<<BATCH, 256, 0, stream>>>(x, fc0w, fc0b, fc1w, fc1b, fc2w, fc2b, (float*)d_out);
}

// Round 11
// 321.904 us; speedup vs baseline: 1.3842x; 1.0054x over previous
//
#include <hip/hip_runtime.h>
#include <hip/hip_bf16.h>
#include <cstddef>

#define H 200
#define NA 48
#define NBB 96
#define BATCH 128
#define AFD 39
#define BFD 50          // 39+11
#define LP 1000
#define CATD (AFD + H)  // 239
#define BIPB 16         // bonds per block in bond-input kernel

typedef unsigned short ushort_t;
typedef __bf16 bf16x8 __attribute__((ext_vector_type(8)));
typedef float f32x16 __attribute__((ext_vector_type(16)));
typedef unsigned uint32x4 __attribute__((ext_vector_type(4)));

union U16B { uint4 u; bf16x8 b; };
static __device__ __forceinline__ bf16x8 as_bf16x8(uint4 u) { U16B x; x.u = u; return x.b; }
union U16B2 { uint32x4 u; bf16x8 b; };
static __device__ __forceinline__ bf16x8 as_bf16x8v(uint32x4 u) { U16B2 x; x.u = u; return x.b; }

// float -> bf16 (RNE)
static __device__ __forceinline__ ushort_t f2bf(float f) {
    union { float f; unsigned u; } a; a.f = f;
    unsigned r = (a.u + 0x7FFFu + ((a.u >> 16) & 1u)) >> 16;
    return (ushort_t)r;
}

// raw asm global load: 16B at sgpr-base + 32-bit voffset. asm volatile pins issue
// order -> counted vmcnt discipline stays valid. "=&v" early-clobber.
static __device__ __forceinline__ uint32x4 gload16(const ushort_t* base, unsigned voff) {
    uint32x4 r;
    asm volatile("global_load_dwordx4 %0, %1, %2"
                 : "=&v"(r) : "v"(voff), "s"(base));
    return r;
}

// ---------------- prep: weight swizzles (32x32x16 A-frag order) ----------------
template <int COUT, int CIN, int CP, int K>
static __device__ __forceinline__ void prep_one(int t, const float* __restrict__ w,
                                                ushort_t* __restrict__ Wb) {
    constexpr int NC = CP / 16;
    constexpr int NS = K * NC;
    int j = t & 7;
    int lane = (t >> 3) & 63;
    int s = (t >> 9) % NS;
    int ct = (t >> 9) / NS;
    int co = ct * 32 + (lane & 31);
    int tt = s / NC, cc = s % NC;
    int ci = cc * 16 + ((lane >> 5) & 1) * 8 + j;
    float v = 0.f;
    if (co < COUT && ci < CIN) v = w[((size_t)co * CIN + ci) * K + tt];
    Wb[t] = f2bf(v);
}

#define MNS 13                            // K-steps for msg GEMM (208/16)
#define ANS 15                            // K-steps for atom GEMM (240/16)
#define PREP_T0 (4 * 12 * 512)            // conv0: 4 tiles x NS=12
#define PREP_T1 (PREP_T0 + 4 * 30 * 512)  // conv1: 4 tiles x NS=30
#define PREP_T2 (PREP_T1 + 8 * 56 * 512)  // conv2: 8 tiles x NS=56
#define PREP_T3 (PREP_T2 + 51200)         // zero x
#define PREP_T4 (PREP_T3 + 8 * MNS * 512) // Wh swizzle: 8 tiles x 13 steps
#define PREP_T5 (PREP_T4 + 8 * ANS * 512) // Wo swizzle (permuted K: nei|fa|pad)
#define PREP_BLKS (PREP_T5 / 256)         // 481280/256 = 1880 exactly

static __device__ __forceinline__ void prep_body(
        int tid, const float* __restrict__ c0w, const float* __restrict__ c1w,
        const float* __restrict__ c2w, const float* __restrict__ Wh,
        const float* __restrict__ Wo, float* __restrict__ x,
        ushort_t* __restrict__ Wb0, ushort_t* __restrict__ Wb1,
        ushort_t* __restrict__ Wb2, ushort_t* __restrict__ Wbh,
        ushort_t* __restrict__ Wbo) {
    if (tid < PREP_T0) prep_one<96, 50, 64, 3>(tid, c0w, Wb0);
    else if (tid < PREP_T1) prep_one<128, 96, 96, 5>(tid - PREP_T0, c1w, Wb1);
    else if (tid < PREP_T2) prep_one<200, 128, 128, 7>(tid - PREP_T1, c2w, Wb2);
    else if (tid < PREP_T3) x[tid - PREP_T2] = 0.f;
    else if (tid < PREP_T4) {
        // Wh stored (in,out): value for (co, ci) = Wh[ci*200 + co]
        int t = tid - PREP_T3;
        int j = t & 7;
        int lane = (t >> 3) & 63;
        int s = (t >> 9) % MNS;
        int tile = (t >> 9) / MNS;
        int co = tile * 32 + (lane & 31);
        int ci = s * 16 + ((lane >> 5) & 1) * 8 + j;
        float v = 0.f;
        if (co < H && ci < H) v = Wh[ci * H + co];
        Wbh[t] = f2bf(v);
    } else if (tid < PREP_T5) {
        // Wo stored (in=239, out=200). Permuted K-axis ci' : [0,200)=nei -> Wo row 39+ci',
        // [200,239)=fa -> Wo row ci'-200, 239 = pad. Lets B staging reuse aligned nei gather.
        int t = tid - PREP_T4;
        int j = t & 7;
        int lane = (t >> 3) & 63;
        int s = (t >> 9) % ANS;
        int tile = (t >> 9) / ANS;
        int co = tile * 32 + (lane & 31);
        int cip = s * 16 + ((lane >> 5) & 1) * 8 + j;
        float v = 0.f;
        if (co < H) {
            if (cip < 200) v = Wo[(size_t)(39 + cip) * H + co];
            else if (cip < CATD) v = Wo[(size_t)(cip - 200) * H + co];
        }
        Wbo[t] = f2bf(v);
    }
}

// ---------------- MFMA conv1d body, 32x32x16 ----------------
// R8 WIN: inline-asm A ring (depth D=4), counted s_waitcnt vmcnt + sched_barrier(0).
// R13: launch_bounds (256,3)->(256,4): 64 VGPR + 64 acc = 128/wave fits 4 waves/SIMD;
// latency-bound loop gets +33% TLP for free.
template <int CP, int K, int COUT, int CO_WAVES, int L_WAVES, bool FMAX, bool EMB>
static __device__ __forceinline__ void conv_body(
        const ushort_t* __restrict__ act, const int* __restrict__ seq,
        const float* __restrict__ emb, const ushort_t* __restrict__ Wb,
        const float* __restrict__ bias, void* __restrict__ outv,
        ushort_t* __restrict__ Xs) {
    constexpr int NC = CP / 16;
    constexpr int NS = K * NC;
    constexpr int P = K / 2;
    constexpr int PITCH = CP + 8;
    constexpr int LTILE = 64 * L_WAVES;
    constexpr int ROWS = LTILE + K - 1;
    constexpr int CPR = CP / 8;
    constexpr int D = 4;

    int b = blockIdx.z, lb = blockIdx.x;
    int l0 = lb * LTILE;
    int tid = threadIdx.x;

    if (EMB) {
        const int* seqb = seq + (size_t)b * LP;
        for (int idx = tid; idx < ROWS * CPR; idx += 256) {
            int r = idx / CPR, c = idx % CPR;
            int l = l0 - P + r;
            uint4 v = {0u, 0u, 0u, 0u};
            if ((unsigned)l < (unsigned)LP) {
                int s = seqb[l];
                const float* e = emb + (size_t)s * 50;
                ushort_t h[8];
#pragma unroll
                for (int j = 0; j < 8; ++j) {
                    int cc = c * 8 + j;
                    h[j] = (cc < 50) ? f2bf(e[cc]) : (ushort_t)0;
                }
                v.x = (unsigned)h[0] | ((unsigned)h[1] << 16);
                v.y = (unsigned)h[2] | ((unsigned)h[3] << 16);
                v.z = (unsigned)h[4] | ((unsigned)h[5] << 16);
                v.w = (unsigned)h[6] | ((unsigned)h[7] << 16);
            }
            *(uint4*)(Xs + r * PITCH + c * 8) = v;
        }
    } else {
        const ushort_t* actb = act + (size_t)b * LP * CP;
        for (int idx = tid; idx < ROWS * CPR; idx += 256) {
            int r = idx / CPR, c = idx % CPR;
            int l = l0 - P + r;
            uint4 v = {0u, 0u, 0u, 0u};
            if ((unsigned)l < (unsigned)LP) v = *(const uint4*)(actb + (size_t)l * CP + c * 8);
            *(uint4*)(Xs + r * PITCH + c * 8) = v;
        }
    }

    int lane = tid & 63, wv = tid >> 6;
    int cw = wv % CO_WAVES, lw = wv / CO_WAVES;
    int ln31 = lane & 31, half = lane >> 5;

    unsigned abase0 = (unsigned)(cw * 2) * (unsigned)NS * 1024u + (unsigned)lane * 16u;
    unsigned abase1 = abase0 + (unsigned)NS * 1024u;
    int bbase = (lw * 64 + ln31) * PITCH + half * 8;

    f32x16 acc[2][2];
#pragma unroll
    for (int ct = 0; ct < 2; ++ct)
#pragma unroll
        for (int lt = 0; lt < 2; ++lt)
#pragma unroll
            for (int r = 0; r < 16; ++r) acc[ct][lt][r] = 0.f;

    __syncthreads();   // staging drained -> vmcnt counts ONLY ring loads

    uint32x4 ra0[D], ra1[D];
#pragma unroll
    for (int d = 0; d < D; ++d) {
        ra0[d] = gload16(Wb, abase0 + (unsigned)(d * 1024));
        ra1[d] = gload16(Wb, abase1 + (unsigned)(d * 1024));
    }

    uint4 bC0 = *(const uint4*)(Xs + bbase);
    uint4 bC1 = *(const uint4*)(Xs + bbase + 32 * PITCH);

#pragma unroll
    for (int s = 0; s < NS; ++s) {
        int sn = (s + 1 < NS) ? s + 1 : NS - 1;
        int tn = sn / NC, ccn = sn % NC;
        int off = bbase + tn * PITCH + ccn * 16;
        uint4 bN0 = *(const uint4*)(Xs + off);
        uint4 bN1 = *(const uint4*)(Xs + off + 32 * PITCH);

        {
            const int rem = NS - 1 - s;
            const int allow = 2 * ((D - 1) < rem ? (D - 1) : rem);
            asm volatile("s_waitcnt vmcnt(%0)" :: "i"(allow) : "memory");
            __builtin_amdgcn_sched_barrier(0);
        }

        uint32x4 a0 = ra0[s % D];
        uint32x4 a1 = ra1[s % D];

        acc[0][0] = __builtin_amdgcn_mfma_f32_32x32x16_bf16(
            as_bf16x8v(a0), as_bf16x8(bC0), acc[0][0], 0, 0, 0);
        acc[1][0] = __builtin_amdgcn_mfma_f32_32x32x16_bf16(
            as_bf16x8v(a1), as_bf16x8(bC0), acc[1][0], 0, 0, 0);
        acc[0][1] = __builtin_amdgcn_mfma_f32_32x32x16_bf16(
            as_bf16x8v(a0), as_bf16x8(bC1), acc[0][1], 0, 0, 0);
        acc[1][1] = __builtin_amdgcn_mfma_f32_32x32x16_bf16(
            as_bf16x8v(a1), as_bf16x8(bC1), acc[1][1], 0, 0, 0);

        if (s + D < NS) {
            ra0[s % D] = gload16(Wb, abase0 + (unsigned)((s + D) * 1024));
            ra1[s % D] = gload16(Wb, abase1 + (unsigned)((s + D) * 1024));
        }

        bC0 = bN0; bC1 = bN1;
    }

    if (!FMAX) {
        ushort_t* out = (ushort_t*)outv + (size_t)b * LP * COUT;
#pragma unroll
        for (int ct = 0; ct < 2; ++ct) {
            int cbase = (cw * 2 + ct) * 32 + 4 * half;
#pragma unroll
            for (int g = 0; g < 4; ++g) {
                int co = cbase + 8 * g;
                if (co >= COUT) continue;
                float4 bv = *(const float4*)(bias + co);
#pragma unroll
                for (int lt = 0; lt < 2; ++lt) {
                    int l = l0 + lw * 64 + lt * 32 + ln31;
                    if (l < LP) {
                        ushort_t h0 = f2bf(fmaxf(acc[ct][lt][4 * g + 0] + bv.x, 0.f));
                        ushort_t h1 = f2bf(fmaxf(acc[ct][lt][4 * g + 1] + bv.y, 0.f));
                        ushort_t h2 = f2bf(fmaxf(acc[ct][lt][4 * g + 2] + bv.z, 0.f));
                        ushort_t h3 = f2bf(fmaxf(acc[ct][lt][4 * g + 3] + bv.w, 0.f));
                        uint2 o;
                        o.x = (unsigned)h0 | ((unsigned)h1 << 16);
                        o.y = (unsigned)h2 | ((unsigned)h3 << 16);
                        *(uint2*)(out + (size_t)l * COUT + co) = o;
                    }
                }
            }
        }
    } else {
        float* xout = (float*)outv;
#pragma unroll
        for (int ct = 0; ct < 2; ++ct) {
            float mx[16];
#pragma unroll
            for (int r = 0; r < 16; ++r) mx[r] = -3.0e38f;
#pragma unroll
            for (int lt = 0; lt < 2; ++lt) {
                int l = l0 + lw * 64 + lt * 32 + ln31;
                if (l < LP) {
#pragma unroll
                    for (int r = 0; r < 16; ++r) mx[r] = fmaxf(mx[r], acc[ct][lt][r]);
                }
            }
#pragma unroll
            for (int r = 0; r < 16; ++r) {
#pragma unroll
                for (int off = 1; off < 32; off <<= 1)
                    mx[r] = fmaxf(mx[r], __shfl_xor(mx[r], off, 64));
            }
            if (ln31 == 0) {
                int cbase = (cw * 2 + ct) * 32 + 4 * half;
#pragma unroll
                for (int r = 0; r < 16; ++r) {
                    int co = cbase + (r & 3) + 8 * (r >> 2);
                    if (co < COUT) {
                        float v = fmaxf(mx[r] + bias[co], 0.f);
                        atomicMax((int*)&xout[(size_t)b * 400 + 200 + co], __float_as_int(v));
                    }
                }
            }
        }
    }
}

// ---------------- msg update via MFMA GEMM (R10 WIN, unchanged numerics) ----------------
#define MPITCH 216   // 208 + 8 ushorts
static __device__ __forceinline__ void msg_body(
        int blk, const float* __restrict__ msgIn, const float* __restrict__ binput,
        const int* __restrict__ bgraph, const ushort_t* __restrict__ Wbh,
        float* __restrict__ msgOut, ushort_t* __restrict__ Xs, int* __restrict__ idxs) {
    constexpr int D = 4;
    int m0 = blk * 32;
    int tid = threadIdx.x;

    if (tid < 192) {
        int r = tid / 6, j = tid - r * 6;
        int m = m0 + r;
        int mol = m / NBB;
        idxs[tid] = mol * NBB + bgraph[(size_t)m * 6 + j];
    }
    __syncthreads();

    for (int it = tid; it < 32 * 26; it += 256) {
        int r = it / 26, c = it - r * 26;
        uint4 v = {0u, 0u, 0u, 0u};
        if (c < 25) {
            float sv[8];
#pragma unroll
            for (int k = 0; k < 8; ++k) sv[k] = 0.f;
#pragma unroll
            for (int j = 0; j < 6; ++j) {
                const float* row = msgIn + (size_t)idxs[r * 6 + j] * H + c * 8;
                float4 a = *(const float4*)row;
                float4 b = *(const float4*)(row + 4);
                sv[0] += a.x; sv[1] += a.y; sv[2] += a.z; sv[3] += a.w;
                sv[4] += b.x; sv[5] += b.y; sv[6] += b.z; sv[7] += b.w;
            }
            v.x = (unsigned)f2bf(sv[0]) | ((unsigned)f2bf(sv[1]) << 16);
            v.y = (unsigned)f2bf(sv[2]) | ((unsigned)f2bf(sv[3]) << 16);
            v.z = (unsigned)f2bf(sv[4]) | ((unsigned)f2bf(sv[5]) << 16);
            v.w = (unsigned)f2bf(sv[6]) | ((unsigned)f2bf(sv[7]) << 16);
        }
        *(uint4*)(Xs + r * MPITCH + c * 8) = v;
    }

    int lane = tid & 63, wv = tid >> 6;
    int ln31 = lane & 31, half = lane >> 5;
    unsigned abase0 = (unsigned)(wv * 2) * (unsigned)MNS * 1024u + (unsigned)lane * 16u;
    unsigned abase1 = abase0 + (unsigned)MNS * 1024u;
    int bbase = ln31 * MPITCH + half * 8;

    f32x16 acc[2];
#pragma unroll
    for (int ct = 0; ct < 2; ++ct)
#pragma unroll
        for (int r = 0; r < 16; ++r) acc[ct][r] = 0.f;

    __syncthreads();

    uint32x4 ra0[4], ra1[4];
#pragma unroll
    for (int d = 0; d < D; ++d) {
        ra0[d] = gload16(Wbh, abase0 + (unsigned)(d * 1024));
        ra1[d] = gload16(Wbh, abase1 + (unsigned)(d * 1024));
    }

    uint4 bC = *(const uint4*)(Xs + bbase);

#pragma unroll
    for (int s = 0; s < MNS; ++s) {
        int sn = (s + 1 < MNS) ? s + 1 : MNS - 1;
        uint4 bN = *(const uint4*)(Xs + bbase + sn * 16);

        {
            const int rem = MNS - 1 - s;
            const int allow = 2 * ((D - 1) < rem ? (D - 1) : rem);
            asm volatile("s_waitcnt vmcnt(%0)" :: "i"(allow) : "memory");
            __builtin_amdgcn_sched_barrier(0);
        }

        uint32x4 a0 = ra0[s % D];
        uint32x4 a1 = ra1[s % D];
        acc[0] = __builtin_amdgcn_mfma_f32_32x32x16_bf16(
            as_bf16x8v(a0), as_bf16x8(bC), acc[0], 0, 0, 0);
        acc[1] = __builtin_amdgcn_mfma_f32_32x32x16_bf16(
            as_bf16x8v(a1), as_bf16x8(bC), acc[1], 0, 0, 0);

        if (s + D < MNS) {
            ra0[s % D] = gload16(Wbh, abase0 + (unsigned)((s + D) * 1024));
            ra1[s % D] = gload16(Wbh, abase1 + (unsigned)((s + D) * 1024));
        }
        bC = bN;
    }

    int m = m0 + ln31;
    const float* bi = binput + (size_t)m * H;
    float* outp = msgOut + (size_t)m * H;
#pragma unroll
    for (int ct = 0; ct < 2; ++ct) {
        int cbase = (wv * 2 + ct) * 32 + 4 * half;
#pragma unroll
        for (int g = 0; g < 4; ++g) {
            int co = cbase + 8 * g;
            if (co >= H) continue;
            float4 b4 = *(const float4*)(bi + co);
            float4 o;
            o.x = fmaxf(acc[ct][4 * g + 0] + b4.x, 0.f);
            o.y = fmaxf(acc[ct][4 * g + 1] + b4.y, 0.f);
            o.z = fmaxf(acc[ct][4 * g + 2] + b4.z, 0.f);
            o.w = fmaxf(acc[ct][4 * g + 3] + b4.w, 0.f);
            *(float4*)(outp + co) = o;
        }
    }
}

// ---------------- atom head via MFMA GEMM (R12 WIN; R13: now a solo kernel) ----------------
#define APITCH 248   // 240 + 8 ushorts
static __device__ __forceinline__ void atom_mfma_body(
        int blk, const float* __restrict__ msg, const float* __restrict__ fatoms,
        const int* __restrict__ agraph, const ushort_t* __restrict__ Wbo,
        const float* __restrict__ Wob, float* __restrict__ x,
        ushort_t* __restrict__ Xs, int* __restrict__ idxs) {
    constexpr int D = 4;
    int m0 = blk * 32;
    int tid = threadIdx.x;

    if (tid < 192) {
        int r = tid / 6, j = tid - r * 6;
        int m = m0 + r;
        int mol = m / NA;
        idxs[tid] = mol * NBB + agraph[(size_t)m * 6 + j];
    }
    __syncthreads();

    // B tile: rows = atoms, cols = permuted K (0..199 nei gather-sum, 200..238 fa, 239 pad)
    for (int it = tid; it < 32 * 30; it += 256) {
        int r = it / 30, c = it - r * 30;
        uint4 v = {0u, 0u, 0u, 0u};
        if (c < 25) {
            float sv[8];
#pragma unroll
            for (int k = 0; k < 8; ++k) sv[k] = 0.f;
#pragma unroll
            for (int j = 0; j < 6; ++j) {
                const float* row = msg + (size_t)idxs[r * 6 + j] * H + c * 8;
                float4 a = *(const float4*)row;
                float4 b = *(const float4*)(row + 4);
                sv[0] += a.x; sv[1] += a.y; sv[2] += a.z; sv[3] += a.w;
                sv[4] += b.x; sv[5] += b.y; sv[6] += b.z; sv[7] += b.w;
            }
            v.x = (unsigned)f2bf(sv[0]) | ((unsigned)f2bf(sv[1]) << 16);
            v.y = (unsigned)f2bf(sv[2]) | ((unsigned)f2bf(sv[3]) << 16);
            v.z = (unsigned)f2bf(sv[4]) | ((unsigned)f2bf(sv[5]) << 16);
            v.w = (unsigned)f2bf(sv[6]) | ((unsigned)f2bf(sv[7]) << 16);
        } else {
            int m = m0 + r;
            ushort_t h[8];
#pragma unroll
            for (int j = 0; j < 8; ++j) {
                int f = c * 8 + j - 200;
                h[j] = (f < AFD) ? f2bf(fatoms[(size_t)m * AFD + f]) : (ushort_t)0;
            }
            v.x = (unsigned)h[0] | ((unsigned)h[1] << 16);
            v.y = (unsigned)h[2] | ((unsigned)h[3] << 16);
            v.z = (unsigned)h[4] | ((unsigned)h[5] << 16);
            v.w = (unsigned)h[6] | ((unsigned)h[7] << 16);
        }
        *(uint4*)(Xs + r * APITCH + c * 8) = v;
    }

    int lane = tid & 63, wv = tid >> 6;
    int ln31 = lane & 31, half = lane >> 5;
    unsigned abase0 = (unsigned)(wv * 2) * (unsigned)ANS * 1024u + (unsigned)lane * 16u;
    unsigned abase1 = abase0 + (unsigned)ANS * 1024u;
    int bbase = ln31 * APITCH + half * 8;

    f32x16 acc[2];
#pragma unroll
    for (int ct = 0; ct < 2; ++ct)
#pragma unroll
        for (int r = 0; r < 16; ++r) acc[ct][r] = 0.f;

    __syncthreads();

    uint32x4 ra0[4], ra1[4];
#pragma unroll
    for (int d = 0; d < D; ++d) {
        ra0[d] = gload16(Wbo, abase0 + (unsigned)(d * 1024));
        ra1[d] = gload16(Wbo, abase1 + (unsigned)(d * 1024));
    }

    uint4 bC = *(const uint4*)(Xs + bbase);

#pragma unroll
    for (int s = 0; s < ANS; ++s) {
        int sn = (s + 1 < ANS) ? s + 1 : ANS - 1;
        uint4 bN = *(const uint4*)(Xs + bbase + sn * 16);

        {
            const int rem = ANS - 1 - s;
            const int allow = 2 * ((D - 1) < rem ? (D - 1) : rem);
            asm volatile("s_waitcnt vmcnt(%0)" :: "i"(allow) : "memory");
            __builtin_amdgcn_sched_barrier(0);
        }

        uint32x4 a0 = ra0[s % D];
        uint32x4 a1 = ra1[s % D];
        acc[0] = __builtin_amdgcn_mfma_f32_32x32x16_bf16(
            as_bf16x8v(a0), as_bf16x8(bC), acc[0], 0, 0, 0);
        acc[1] = __builtin_amdgcn_mfma_f32_32x32x16_bf16(
            as_bf16x8v(a1), as_bf16x8(bC), acc[1], 0, 0, 0);

        if (s + D < ANS) {
            ra0[s % D] = gload16(Wbo, abase0 + (unsigned)((s + D) * 1024));
            ra1[s % D] = gload16(Wbo, abase1 + (unsigned)((s + D) * 1024));
        }
        bC = bN;
    }

    // Epilogue: relu(+bias)*(1/NA), segmented lane-reduce over atoms, atomicAdd per mol.
    // 48 = 32+16 -> a 32-atom block spans whole 16-lane groups: m0%48==0 or 16 -> all one
    // mol; m0%48==32 -> lanes 0-15 mol q, lanes 16-31 mol q+1.
    int rm = m0 % 48;
    bool split = (rm == 32);
    int molA = m0 / 48;
    const float inv = 1.f / NA;
#pragma unroll
    for (int ct = 0; ct < 2; ++ct) {
        int cbase = (wv * 2 + ct) * 32 + 4 * half;
#pragma unroll
        for (int r = 0; r < 16; ++r) {
            int co = cbase + (r & 3) + 8 * (r >> 2);
            float v = 0.f;
            if (co < H) v = fmaxf(acc[ct][r] + Wob[co], 0.f) * inv;
            v += __shfl_xor(v, 1, 64);
            v += __shfl_xor(v, 2, 64);
            v += __shfl_xor(v, 4, 64);
            v += __shfl_xor(v, 8, 64);
            if (!split) v += __shfl_xor(v, 16, 64);
            if (co < H) {
                if (ln31 == 0) atomicAdd(&x[(size_t)molA * 400 + co], v);
                else if (split && ln31 == 16) atomicAdd(&x[(size_t)(molA + 1) * 400 + co], v);
            }
        }
    }
}

// ---------------- bond input body ----------------
static __device__ __forceinline__ void bond_body(
        int blk, const float* __restrict__ fbonds, const float* __restrict__ Wi,
        float* __restrict__ binput, float* __restrict__ msg, float (*fb)[BFD]) {
    int bond0 = blk * BIPB;
    int tid = threadIdx.x;
    for (int idx = tid; idx < BIPB * BFD; idx += 256)
        fb[idx / BFD][idx % BFD] = fbonds[(size_t)bond0 * BFD + idx];
    __syncthreads();
    if (tid < H) {
        float acc[BIPB];
#pragma unroll
        for (int q = 0; q < BIPB; ++q) acc[q] = 0.f;
#pragma unroll 5
        for (int k = 0; k < BFD; ++k) {
            float w = Wi[k * H + tid];
#pragma unroll
            for (int q = 0; q < BIPB; ++q) acc[q] += fb[q][k] * w;
        }
#pragma unroll
        for (int q = 0; q < BIPB; ++q) {
            size_t o = (size_t)(bond0 + q) * H + tid;
            binput[o] = acc[q];
            msg[o] = fmaxf(acc[q], 0.f);
        }
    }
}

// ================= launches =================
// L0: prep || bond.  L1: conv0 || msg1.  L2: conv1 || msg2.
// L3a: conv2 SOLO (R13: unfused — atom co-residency cost conv2 ~25us: MfmaUtil 34->26).
// L3b: atom-MFMA solo.  L4: fc.

__global__ __launch_bounds__(256) void k_l0_prep_bond(
        const float* __restrict__ c0w, const float* __restrict__ c1w,
        const float* __restrict__ c2w, const float* __restrict__ Wh,
        const float* __restrict__ Wo, float* __restrict__ x,
        ushort_t* __restrict__ Wb0, ushort_t* __restrict__ Wb1,
        ushort_t* __restrict__ Wb2, ushort_t* __restrict__ Wbh,
        ushort_t* __restrict__ Wbo,
        const float* __restrict__ fbonds, const float* __restrict__ Wi,
        float* __restrict__ binput, float* __restrict__ msgA) {
    __shared__ float fb[BIPB][BFD];
    int bid = blockIdx.x;
    if (bid < PREP_BLKS) {
        prep_body(bid * 256 + threadIdx.x, c0w, c1w, c2w, Wh, Wo, x, Wb0, Wb1, Wb2, Wbh, Wbo);
    } else {
        bond_body(bid - PREP_BLKS, fbonds, Wi, binput, msgA, fb);
    }
}

__global__ __launch_bounds__(256, 4) void k_l1_conv0_msg(
        const int* __restrict__ seq, const float* __restrict__ emb,
        const ushort_t* __restrict__ Wb0, const float* __restrict__ c0b,
        ushort_t* __restrict__ act1,
        const float* __restrict__ msgIn, const float* __restrict__ binput,
        const int* __restrict__ bgraph, const ushort_t* __restrict__ Wbh,
        float* __restrict__ msgOut) {
    __shared__ __align__(16) ushort_t Sbuf[(128 + 2) * (64 + 8)];  // 9360 ushorts
    if (blockIdx.x < 8) {
        conv_body<64, 3, 96, 2, 2, false, true>(nullptr, seq, emb, Wb0, c0b, act1, Sbuf);
    } else {
        int blk = (blockIdx.x - 8) * 128 + blockIdx.z;   // 0..383
        msg_body(blk, msgIn, binput, bgraph, Wbh, msgOut, Sbuf,
                 (int*)(Sbuf + 32 * MPITCH));
    }
}

__global__ __launch_bounds__(256, 4) void k_l2_conv1_msg(
        const ushort_t* __restrict__ act1, const ushort_t* __restrict__ Wb1,
        const float* __restrict__ c1b, ushort_t* __restrict__ act2,
        const float* __restrict__ msgIn, const float* __restrict__ binput,
        const int* __restrict__ bgraph, const ushort_t* __restrict__ Wbh,
        float* __restrict__ msgOut) {
    __shared__ __align__(16) ushort_t Sbuf[(128 + 4) * (96 + 8)];  // 13728 ushorts
    if (blockIdx.x < 8) {
        conv_body<96, 5, 128, 2, 2, false, false>(act1, nullptr, nullptr, Wb1, c1b, act2, Sbuf);
    } else {
        int blk = (blockIdx.x - 8) * 128 + blockIdx.z;
        msg_body(blk, msgIn, binput, bgraph, Wbh, msgOut, Sbuf,
                 (int*)(Sbuf + 32 * MPITCH));
    }
}

__global__ __launch_bounds__(256, 4) void k_conv2(
        const ushort_t* __restrict__ act2, const ushort_t* __restrict__ Wb2,
        const float* __restrict__ c2b, float* __restrict__ x) {
    __shared__ __align__(16) ushort_t Xs[(64 + 6) * (128 + 8)];
    conv_body<128, 7, 200, 4, 1, true, false>(act2, nullptr, nullptr, Wb2, c2b, x, Xs);
}

__global__ __launch_bounds__(256, 4) void k_atom_mfma(
        const float* __restrict__ msg, const float* __restrict__ fatoms,
        const int* __restrict__ agraph, const ushort_t* __restrict__ Wbo,
        const float* __restrict__ Wob, float* __restrict__ x) {
    __shared__ __align__(16) ushort_t Xs[32 * APITCH];
    __shared__ int idxs[192];
    atom_mfma_body(blockIdx.x, msg, fatoms, agraph, Wbo, Wob, x, Xs, idxs);
}

// ---------------- fused FC head: 400 -> 200 -> 100 -> 1 ----------------
__global__ __launch_bounds__(256) void k_fc(
        const float* __restrict__ x,
        const float* __restrict__ w0, const float* __restrict__ b0,
        const float* __restrict__ w1, const float* __restrict__ b1,
        const float* __restrict__ w2, const float* __restrict__ b2,
        float* __restrict__ out) {
    int b = blockIdx.x, tid = threadIdx.x;
    __shared__ float xr[400];
    __shared__ float h1[200];
    __shared__ float h2[100];
    for (int i = tid; i < 400; i += 256) xr[i] = x[(size_t)b * 400 + i];
    __syncthreads();
    if (tid < 200) {
        float a = b0[tid];
#pragma unroll 4
        for (int k = 0; k < 400; ++k) a += xr[k] * w0[k * 200 + tid];
        h1[tid] = fmaxf(a, 0.f);
    }
    __syncthreads();
    if (tid < 100) {
        float a = b1[tid];
#pragma unroll 4
        for (int k = 0; k < 200; ++k) a += h1[k] * w1[k * 100 + tid];
        h2[tid] = fmaxf(a, 0.f);
    }
    __syncthreads();
    if (tid == 0) {
        float a = b2[0];
#pragma unroll 4
        for (int k = 0; k < 100; ++k) a += h2[k] * w2[k];
        out[b] = a;
    }
}

extern "C" void kernel_launch(void* const* d_in, const int* in_sizes, int n_in,
                              void* d_out, int out_size, void* d_ws, size_t ws_size,
                              hipStream_t stream) {
    const float* fatoms = (const float*)d_in[0];
    const float* fbonds = (const float*)d_in[1];
    const int* agraph = (const int*)d_in[2];
    const int* bgraph = (const int*)d_in[3];
    const int* seq = (const int*)d_in[4];
    const float* Wi = (const float*)d_in[5];
    const float* Wh = (const float*)d_in[6];
    const float* Wo = (const float*)d_in[7];
    const float* Wob = (const float*)d_in[8];
    const float* embp = (const float*)d_in[9];
    const float* c0w = (const float*)d_in[10];
    const float* c0b = (const float*)d_in[11];
    const float* c1w = (const float*)d_in[12];
    const float* c1b = (const float*)d_in[13];
    const float* c2w = (const float*)d_in[14];
    const float* c2b = (const float*)d_in[15];
    const float* fc0w = (const float*)d_in[16];
    const float* fc0b = (const float*)d_in[17];
    const float* fc1w = (const float*)d_in[18];
    const float* fc1b = (const float*)d_in[19];
    const float* fc2w = (const float*)d_in[20];
    const float* fc2b = (const float*)d_in[21];

    float* ws = (float*)d_ws;
    float* binput = ws;                    // 2457600
    float* msgA = binput + 2457600;        // 2457600
    float* msgB = msgA + 2457600;          // 2457600
    float* x = msgB + 2457600;             // 51200
    ushort_t* u = (ushort_t*)(x + 51200);  // bf16 region
    ushort_t* act1 = u;                    // 128000*96  = 12288000
    ushort_t* act2 = act1 + 12288000;      // 128000*128 = 16384000
    ushort_t* Wb0 = act2 + 16384000;       // 4*12*512  = 24576
    ushort_t* Wb1 = Wb0 + 24576;           // 4*30*512  = 61440
    ushort_t* Wb2 = Wb1 + 61440;           // 8*56*512  = 229376
    ushort_t* Wbh = Wb2 + 229376;          // 8*13*512  = 53248
    ushort_t* Wbo = Wbh + 53248;           // 8*15*512  = 61440

    // L0: prep (weight swizzles incl. Wo + zero x) || bond_input
    k_l0_prep_bond<<<PREP_BLKS + BATCH * NBB / BIPB, 256, 0, stream>>>(
        c0w, c1w, c2w, Wh, Wo, x, Wb0, Wb1, Wb2, Wbh, Wbo, fbonds, Wi, binput, msgA);

    // L1: conv0 || msg pass 1 (msgA -> msgB)
    k_l1_conv0_msg<<<dim3(8 + 3, 1, BATCH), 256, 0, stream>>>(
        seq, embp, Wb0, c0b, act1, msgA, binput, bgraph, Wbh, msgB);

    // L2: conv1 || msg pass 2 (msgB -> msgA)
    k_l2_conv1_msg<<<dim3(8 + 3, 1, BATCH), 256, 0, stream>>>(
        act1, Wb1, c1b, act2, msgB, binput, bgraph, Wbh, msgA);

    // L3a: conv2 solo (latency-sensitive; keep CUs clean)
    k_conv2<<<dim3(16, 1, BATCH), 256, 0, stream>>>(act2, Wb2, c2b, x);

    // L3b: atom-MFMA solo (192 blocks)
    k_atom_mfma<<<BATCH * NA / 32, 256, 0, stream>>>(msgA, fatoms, agraph, Wbo, Wob, x);

    // L4: fc head
    k_fc<<<BATCH, 256, 0, stream>>>(x, fc0w, fc0b, fc1w, fc1b, fc2w, fc2b, (float*)d_out);
}